// Round 8
// baseline (1765.651 us; speedup 1.0000x reference)
//
#include <hip/hip_runtime.h>
#include <hip/hip_bf16.h>

// ---------------------------------------------------------------------------
#define SEQ   100
#define BATCH 32
#define FLATIN 15873
#define KPAD1  16384
#define ROWS   3200
#define MPAD   3328
#define NOUT3  16000

typedef __attribute__((ext_vector_type(8))) short short8;
typedef __attribute__((ext_vector_type(4))) short short4v;
typedef __attribute__((ext_vector_type(4))) float f32x4;

__device__ __forceinline__ void gload_lds16(const void* g, void* l) {
  __builtin_amdgcn_global_load_lds((const __attribute__((address_space(1))) void*)g,
                                   (__attribute__((address_space(3))) void*)l, 16, 0, 0);
}

// bijective XCD chunk swizzle (m204)
__device__ __forceinline__ int xcd_swizzle(int id, int nwg) {
  const int q = nwg >> 3, r = nwg & 7;
  const int x = id & 7, p = id >> 3;
  return (x < r ? x * (q + 1) : r * (q + 1) + (x - r) * q) + p;
}

// ---------------------------------------------------------------------------
// Shared GEMM body: stage 128x64 A/B tiles (both-sides chunk swizzle), MFMA.
#define GEMM_BODY(KBEG, KEND)                                                   \
  const int tid  = threadIdx.x;                                                 \
  const int lane = tid & 63;                                                    \
  const int wid  = tid >> 6;                                                    \
  const int wr = (wid >> 1) << 6;                                               \
  const int wc = (wid & 1) << 6;                                                \
  f32x4 acc[4][4];                                                              \
  _Pragma("unroll") for (int i = 0; i < 4; ++i)                                 \
  _Pragma("unroll") for (int j = 0; j < 4; ++j)                                 \
      acc[i][j] = (f32x4){0.f, 0.f, 0.f, 0.f};                                  \
  const int srow = (wid << 3) + (lane >> 3);                                    \
  const int scs  = lane & 7;                                                    \
  const int gcol = ((scs ^ (srow & 7)) << 3);                                   \
  const __hip_bfloat16* arow[4];                                                \
  const __hip_bfloat16* brow[4];                                                \
  _Pragma("unroll") for (int j = 0; j < 4; ++j) {                               \
    const int row = (j << 5) + srow;                                            \
    const int gr = GATHER ? idx[m0 + row] : (m0 + row);                         \
    arow[j] = A + (size_t)gr * K + gcol;                                        \
    brow[j] = W + (size_t)(n0 + row) * K + gcol;                                \
  }                                                                             \
  for (int k0 = (KBEG); k0 < (KEND); k0 += 64) {                                \
    __syncthreads();                                                            \
    _Pragma("unroll") for (int j = 0; j < 4; ++j) {                             \
      short* la = As + (((j << 2) + wid) << 9);                                 \
      short* lb = Bs + (((j << 2) + wid) << 9);                                 \
      gload_lds16(arow[j] + k0, la);                                            \
      gload_lds16(brow[j] + k0, lb);                                            \
    }                                                                           \
    __syncthreads();                                                            \
    _Pragma("unroll") for (int kk = 0; kk < 2; ++kk) {                          \
      short8 af[4], bfv[4];                                                     \
      _Pragma("unroll") for (int i = 0; i < 4; ++i) {                           \
        const int mr = wr + (i << 4) + (lane & 15);                             \
        const int cg = (kk << 2) + (lane >> 4);                                 \
        af[i]  = *(const short8*)(As + mr * 64 + ((cg ^ (mr & 7)) << 3));       \
        const int nr = wc + (i << 4) + (lane & 15);                             \
        bfv[i] = *(const short8*)(Bs + nr * 64 + ((cg ^ (nr & 7)) << 3));       \
      }                                                                         \
      _Pragma("unroll") for (int i = 0; i < 4; ++i)                             \
      _Pragma("unroll") for (int j = 0; j < 4; ++j)                             \
          acc[i][j] = __builtin_amdgcn_mfma_f32_16x16x32_bf16(af[i], bfv[j],    \
                                                              acc[i][j], 0,0,0);\
    }                                                                           \
  }

// Split-K partial-output GEMM. mt-minor linearization.
template<int GATHER>
__global__ __launch_bounds__(256)
void gemm_bf16(const __hip_bfloat16* __restrict__ A, const __hip_bfloat16* __restrict__ W,
               const int* __restrict__ idx, const int* __restrict__ cnt,
               float* __restrict__ P,
               int K, int ldc, int mtiles, int ksl, size_t pstride)
{
  __shared__ __align__(16) short lds[16384];
  short* As = lds;
  short* Bs = lds + 8192;
  const int wg = xcd_swizzle(blockIdx.x, gridDim.x);
  const int mt = wg % mtiles;
  const int g  = wg / mtiles;
  const int nt = g / ksl;
  const int ks = g % ksl;
  const int m0 = mt << 7;
  const int n0 = nt << 7;
  if (cnt && m0 >= cnt[0]) return;
  const int Klen = K / ksl;
  const int kbeg = ks * Klen;

  GEMM_BODY(kbeg, kbeg + Klen)

  float* Pout = P + (size_t)ks * pstride;
  const int fr = lane & 15, fq = lane >> 4;
#pragma unroll
  for (int j = 0; j < 4; ++j) {
    const int n = n0 + wc + (j << 4) + fr;
#pragma unroll
    for (int i = 0; i < 4; ++i)
#pragma unroll
      for (int r = 0; r < 4; ++r) {
        const int m = m0 + wr + (i << 4) + (fq << 2) + r;
        Pout[(size_t)m * ldc + n] = acc[i][j][r];
      }
  }
}

// Direct GEMM with fused bias/relu epilogue
template<int RELU, int OF32, int OB16>
__global__ __launch_bounds__(256)
void gemm_direct(const __hip_bfloat16* __restrict__ A, const __hip_bfloat16* __restrict__ W,
                 const float* __restrict__ bias, float* __restrict__ Cf,
                 __hip_bfloat16* __restrict__ Cb, int K, int ldc, int mtiles)
{
  __shared__ __align__(16) short lds[16384];
  short* As = lds;
  short* Bs = lds + 8192;
  const int GATHER = 0;
  const int* idx = nullptr;
  const int wg = xcd_swizzle(blockIdx.x, gridDim.x);
  const int m0 = (wg % mtiles) << 7;
  const int n0 = (wg / mtiles) << 7;

  GEMM_BODY(0, K)

  const int fr = lane & 15, fq = lane >> 4;
#pragma unroll
  for (int j = 0; j < 4; ++j) {
    const int n = n0 + wc + (j << 4) + fr;
    const float bb = bias[n];
#pragma unroll
    for (int i = 0; i < 4; ++i)
#pragma unroll
      for (int r = 0; r < 4; ++r) {
        const int m = m0 + wr + (i << 4) + (fq << 2) + r;
        float v = acc[i][j][r] + bb;
        if (RELU) v = fmaxf(v, 0.f);
        if (OF32) Cf[(size_t)m * ldc + n] = v;
        if (OB16) Cb[(size_t)m * ldc + n] = __float2bfloat16(v);
      }
  }
}

// ---------------------------------------------------------------------------
// Split-K reduce: C = sum_ks P[ks] + bias [, relu]
template<int RELU, int OF32, int OB16>
__global__ __launch_bounds__(256)
void reduce_kernel(const float* __restrict__ P, size_t pstride, int ksl,
                   const float* __restrict__ bias, float* __restrict__ Cf,
                   __hip_bfloat16* __restrict__ Cb, int N,
                   const int* __restrict__ cnt)
{
  const int row = blockIdx.y;
  if (cnt) { const int cp = (cnt[0] + 127) & ~127; if (row >= cp) return; }
  const int n = (blockIdx.x * 256 + threadIdx.x) * 4;
  if (n >= N) return;
  const size_t o = (size_t)row * N + n;
  const float4 b4 = *(const float4*)(bias + n);
  float4 s = *(const float4*)(P + o);
  for (int k = 1; k < ksl; ++k) {
    const float4 p = *(const float4*)(P + (size_t)k * pstride + o);
    s.x += p.x; s.y += p.y; s.z += p.z; s.w += p.w;
  }
  s.x += b4.x; s.y += b4.y; s.z += b4.z; s.w += b4.w;
  if (RELU) {
    s.x = fmaxf(s.x, 0.f); s.y = fmaxf(s.y, 0.f);
    s.z = fmaxf(s.z, 0.f); s.w = fmaxf(s.w, 0.f);
  }
  if (OF32) *(float4*)(Cf + o) = s;
  if (OB16) {
    union { short4v v; __hip_bfloat16 h[4]; } u;
    u.h[0] = __float2bfloat16(s.x);
    u.h[1] = __float2bfloat16(s.y);
    u.h[2] = __float2bfloat16(s.z);
    u.h[3] = __float2bfloat16(s.w);
    *(short4v*)(Cb + o) = u.v;
  }
}

// ---------------------------------------------------------------------------
// x -> xb bf16; skip writes for all-zero rows; block ROWS zeroes canonical row.
__global__ __launch_bounds__(256)
void conv_x_kernel(const float* __restrict__ x, __hip_bfloat16* __restrict__ xb,
                   int* __restrict__ nz)
{
  __shared__ int sred[4];
  const int m = blockIdx.x;               // 0..ROWS
  const int t = threadIdx.x;
  __hip_bfloat16* dst = xb + (size_t)m * KPAD1;
  if (m == ROWS) {
    const __hip_bfloat162 z2 = {__float2bfloat16(0.f), __float2bfloat16(0.f)};
    for (int c = t; c < (KPAD1 >> 1); c += 256) *(__hip_bfloat162*)(dst + 2 * c) = z2;
    return;
  }
  const float* src = x + (size_t)m * FLATIN;
  int any = 0;
  for (int c = t; c < FLATIN; c += 256) any |= (src[c] != 0.f);
  any = __any(any) ? 1 : 0;
  if ((t & 63) == 0) sred[t >> 6] = any;
  __syncthreads();
  const int ba = sred[0] | sred[1] | sred[2] | sred[3];
  if (t == 0) nz[m] = ba;
  if (!ba) return;                         // zero row: gather uses row ROWS
  for (int c = t; c < (KPAD1 >> 1); c += 256) {
    const int c0 = 2 * c;
    const float v0 = (c0 < FLATIN) ? src[c0] : 0.f;
    const float v1 = (c0 + 1 < FLATIN) ? src[c0 + 1] : 0.f;
    __hip_bfloat162 pr;
    pr.x = __float2bfloat16(v0);
    pr.y = __float2bfloat16(v1);
    *(__hip_bfloat162*)(dst + c0) = pr;
  }
}

// Compaction + padding mask (single block)
__global__ __launch_bounds__(256)
void compact_kernel(const int* __restrict__ nz, int* __restrict__ idx,
                    int* __restrict__ pos, int* __restrict__ cnt,
                    int* __restrict__ pad)
{
  __shared__ int wsum[4];
  __shared__ int total;
  const int t = threadIdx.x;
  int loc[13];
  int c = 0;
#pragma unroll
  for (int i = 0; i < 13; ++i) {
    const int m = t * 13 + i;
    loc[i] = (m < ROWS) ? nz[m] : 0;
    c += loc[i];
  }
  int v = c;
#pragma unroll
  for (int o = 1; o < 64; o <<= 1) {
    const int u = __shfl_up(v, o);
    if ((t & 63) >= o) v += u;
  }
  if ((t & 63) == 63) wsum[t >> 6] = v;
  __syncthreads();
  int wbase = 0;
  for (int w = 0; w < (t >> 6); ++w) wbase += wsum[w];
  int p = wbase + v - c;
#pragma unroll
  for (int i = 0; i < 13; ++i) {
    const int m = t * 13 + i;
    if (m < ROWS) {
      if (loc[i]) { idx[p] = m; pos[m] = p; ++p; }
      else pos[m] = -1;
    }
  }
  if (t == 255) total = p;
  __syncthreads();
  const int count = total;
  if (t == 0) cnt[0] = count + 1;
  for (int i = count + t; i < MPAD; i += 256) idx[i] = ROWS;
  for (int m = t; m < ROWS; m += 256) if (pos[m] < 0) pos[m] = count;
  // padding mask
  if (t < 32) {
    int any = 0;
    for (int s = 99; s >= 0; --s) {
      any |= nz[t * 100 + s];
      pad[t * 100 + s] = (s > 0 && !any) ? 1 : 0;
    }
  }
}

// fp32 -> bf16 pairwise with row AND column zero-pad
__global__ __launch_bounds__(256)
void cvt_pad_kernel(const float* __restrict__ in, __hip_bfloat16* __restrict__ out,
                    int rin, int cin, int cout)
{
  const int c = (blockIdx.x * 256 + threadIdx.x) * 2;
  const int r = blockIdx.y;
  if (c >= cout) return;
  const int rv = (r < rin);
  const float v0 = (rv && c < cin) ? in[(size_t)r * cin + c] : 0.f;
  const float v1 = (rv && c + 1 < cin) ? in[(size_t)r * cin + c + 1] : 0.f;
  __hip_bfloat162 pr;
  pr.x = __float2bfloat16(v0);
  pr.y = __float2bfloat16(v1);
  *(__hip_bfloat162*)(out + (size_t)r * cout + c) = pr;
}

// Multi-segment flat fp32->bf16 (counts multiples of 2048)
struct CvtArgs {
  const float* src[8];
  __hip_bfloat16* dst[8];
  int cum[8];
};
__global__ __launch_bounds__(256)
void cvt_multi_kernel(CvtArgs a)
{
  const int bid = blockIdx.x;
  int seg = 0;
#pragma unroll
  for (int i = 1; i < 8; ++i) if (bid >= a.cum[i]) seg = i;
  const size_t e0 = ((size_t)(bid - a.cum[seg]) << 11) + (threadIdx.x << 3);
  const float4 v0 = *(const float4*)(a.src[seg] + e0);
  const float4 v1 = *(const float4*)(a.src[seg] + e0 + 4);
  union { short4v v; __hip_bfloat16 h[4]; } u0, u1;
  u0.h[0] = __float2bfloat16(v0.x); u0.h[1] = __float2bfloat16(v0.y);
  u0.h[2] = __float2bfloat16(v0.z); u0.h[3] = __float2bfloat16(v0.w);
  u1.h[0] = __float2bfloat16(v1.x); u1.h[1] = __float2bfloat16(v1.y);
  u1.h[2] = __float2bfloat16(v1.z); u1.h[3] = __float2bfloat16(v1.w);
  *(short4v*)(a.dst[seg] + e0) = u0.v;
  *(short4v*)(a.dst[seg] + e0 + 4) = u1.v;
}

// bias pad: biasP[i] = i < FLATIN ? out3_b[i] : 0
__global__ void bias_pad_kernel(const float* __restrict__ b, float* __restrict__ bp)
{
  const int i = blockIdx.x * 256 + threadIdx.x;
  if (i < NOUT3) bp[i] = (i < FLATIN) ? b[i] : 0.f;
}

// fc3 reduce + bias + relu + scatter + inline PE
__global__ __launch_bounds__(256)
void scatter_pe_reduce(const float* __restrict__ P, size_t pstride, int ksl,
                       const int* __restrict__ pos, const float* __restrict__ bias,
                       float* __restrict__ hf, __hip_bfloat16* __restrict__ hb)
{
  const int m = blockIdx.x;
  const int s = m % 100, b = m / 100;
  const int src = pos[m];
  const int t = threadIdx.x;
  const size_t sb = (size_t)src * 512;
  const size_t db = (size_t)(s * 32 + b) * 512;
#pragma unroll
  for (int u = 0; u < 2; ++u) {
    const int d = t + u * 256;
    float v = bias[d];
    for (int k = 0; k < ksl; ++k) v += P[(size_t)k * pstride + sb + d];
    const float div = expf((float)(2 * (d >> 1)) * (-9.210340371976184f / 512.f));
    const float arg = (float)s * div;
    const float pe = (d & 1) ? cosf(arg) : sinf(arg);
    v = fmaxf(v, 0.f) + pe;
    hf[db + d] = v;
    hb[db + d] = __float2bfloat16(v);
  }
}

// ---------------------------------------------------------------------------
// LayerNorm over D=512 (+ optional second, final LN fused)
__global__ __launch_bounds__(256)
void ln_kernel(const float* __restrict__ x, const float* __restrict__ res,
               const float* __restrict__ g, const float* __restrict__ bta,
               const float* __restrict__ gf, const float* __restrict__ bf_,
               int dofinal, float* __restrict__ y, __hip_bfloat16* __restrict__ yb)
{
  __shared__ float rs[4], rss[4];
  const int row = blockIdx.x;
  const int t = threadIdx.x;
  const size_t base = (size_t)row * 512;
  float v0 = x[base + t];
  float v1 = x[base + t + 256];
  if (res) { v0 += res[base + t]; v1 += res[base + t + 256]; }
  float o0, o1;
#pragma unroll
  for (int pass = 0; pass < 2; ++pass) {
    float s = v0 + v1, ss = v0 * v0 + v1 * v1;
#pragma unroll
    for (int o = 32; o > 0; o >>= 1) { s += __shfl_xor(s, o); ss += __shfl_xor(ss, o); }
    if ((t & 63) == 0) { rs[t >> 6] = s; rss[t >> 6] = ss; }
    __syncthreads();
    s = rs[0] + rs[1] + rs[2] + rs[3];
    ss = rss[0] + rss[1] + rss[2] + rss[3];
    __syncthreads();
    const float mean = s * (1.f / 512.f);
    const float var = ss * (1.f / 512.f) - mean * mean;
    const float inv = rsqrtf(var + 1e-5f);
    const float* gg = (pass == 0) ? g : gf;
    const float* bb = (pass == 0) ? bta : bf_;
    o0 = (v0 - mean) * inv * gg[t] + bb[t];
    o1 = (v1 - mean) * inv * gg[t + 256] + bb[t + 256];
    if (pass == 1 || !dofinal) break;
    v0 = o0; v1 = o1;
  }
  if (y) {
    y[base + t] = o0;
    y[base + t + 256] = o1;
  }
  if (yb) {
    yb[base + t] = __float2bfloat16(o0);
    yb[base + t + 256] = __float2bfloat16(o1);
  }
}

// ---------------------------------------------------------------------------
// Encoder self-attention (unchanged)
__global__ __launch_bounds__(256)
void enc_attn_kernel(const float* __restrict__ qkv, const int* __restrict__ pad,
                     __hip_bfloat16* __restrict__ ob)
{
  __shared__ float Ks[100][129];
  __shared__ float Qs[128];
  __shared__ float Ps[100];
  __shared__ float red[4];
  const int bh = blockIdx.x;
  const int b = bh >> 2, h = bh & 3;
  const int q0 = blockIdx.y * 25;
  const int t = threadIdx.x;
  for (int i = t; i < 12800; i += 256) {
    const int s = i >> 7, d = i & 127;
    Ks[s][d] = qkv[(size_t)(s * 32 + b) * 1536 + 512 + h * 128 + d];
  }
  const int masked = (t < 100) ? pad[b * 100 + t] : 0;
  const float scale = 0.08838834764831845f;
  for (int qi = 0; qi < 25; ++qi) {
    const int q = q0 + qi;
    __syncthreads();
    if (t < 128) Qs[t] = qkv[(size_t)(q * 32 + b) * 1536 + h * 128 + t];
    __syncthreads();
    float sc = -3e38f;
    if (t < 100) {
      const float* kr = &Ks[t][0];
      float a = 0.f;
#pragma unroll 16
      for (int d = 0; d < 128; ++d) a += Qs[d] * kr[d];
      sc = masked ? -1e9f : (a * scale);
    }
    float mx = sc;
#pragma unroll
    for (int o = 32; o > 0; o >>= 1) mx = fmaxf(mx, __shfl_xor(mx, o));
    if ((t & 63) == 0) red[t >> 6] = mx;
    __syncthreads();
    mx = fmaxf(fmaxf(red[0], red[1]), fmaxf(red[2], red[3]));
    const float e = (t < 100) ? expf(sc - mx) : 0.f;
    float sm = e;
#pragma unroll
    for (int o = 32; o > 0; o >>= 1) sm += __shfl_xor(sm, o);
    __syncthreads();
    if ((t & 63) == 0) red[t >> 6] = sm;
    __syncthreads();
    sm = red[0] + red[1] + red[2] + red[3];
    if (t < 100) Ps[t] = e;
    __syncthreads();
    if (t < 128) {
      float a = 0.f;
      const float* vb = qkv + 1024 + h * 128 + t;
      for (int k = 0; k < 100; ++k) a += Ps[k] * vb[(size_t)(k * 32 + b) * 1536];
      ob[(size_t)(q * 32 + b) * 512 + h * 128 + t] = __float2bfloat16(a / sm);
    }
  }
}

// ---------------------------------------------------------------------------
// Fully fused decoder layer. One block per batch row (grid 32, block 256).
#define BLOCK_LN(V0, V1, G, B, O0, O1)                                          \
  {                                                                             \
    float s_ = (V0) + (V1), ss_ = (V0) * (V0) + (V1) * (V1);                    \
    _Pragma("unroll")                                                           \
    for (int o_ = 32; o_ > 0; o_ >>= 1) {                                       \
      s_ += __shfl_xor(s_, o_); ss_ += __shfl_xor(ss_, o_);                     \
    }                                                                           \
    if ((tid & 63) == 0) { red[tid >> 6] = s_; red[4 + (tid >> 6)] = ss_; }     \
    __syncthreads();                                                            \
    s_ = red[0] + red[1] + red[2] + red[3];                                     \
    ss_ = red[4] + red[5] + red[6] + red[7];                                    \
    const float mean_ = s_ * (1.f / 512.f);                                     \
    const float inv_ = rsqrtf(ss_ * (1.f / 512.f) - mean_ * mean_ + 1e-5f);     \
    O0 = ((V0) - mean_) * inv_ * (G)[tid] + (B)[tid];                           \
    O1 = ((V1) - mean_) * inv_ * (G)[tid + 256] + (B)[tid + 256];               \
    __syncthreads();                                                            \
  }

__device__ __forceinline__ float dot512(const float* __restrict__ v,
                                        const float* __restrict__ wrow)
{
  const float4* wp = (const float4*)wrow;
  float a = 0.f;
#pragma unroll 8
  for (int k = 0; k < 128; ++k) {
    const float4 w = wp[k];
    a += v[4 * k] * w.x + v[4 * k + 1] * w.y + v[4 * k + 2] * w.z + v[4 * k + 3] * w.w;
  }
  return a;
}

__global__ __launch_bounds__(256)
void dec_layer(const float* __restrict__ tin,          // nullptr => ones
               const float* __restrict__ kvb,          // (3200 x 1024) k|v
               const float* __restrict__ Wv, const float* __restrict__ bv,
               const float* __restrict__ Wp, const float* __restrict__ bp,
               const float* __restrict__ g1, const float* __restrict__ b1,
               const float* __restrict__ Wq, const float* __restrict__ bq,
               const float* __restrict__ Wcp, const float* __restrict__ bcp,
               const float* __restrict__ g2, const float* __restrict__ b2,
               const float* __restrict__ W1, const float* __restrict__ b1f,
               const float* __restrict__ W2, const float* __restrict__ b2f,
               const float* __restrict__ g3, const float* __restrict__ b3,
               const float* __restrict__ gf, const float* __restrict__ bf_,
               int dofinal, float* __restrict__ tout)
{
  __shared__ float Ts[512], Bs[512], F1[1024], Ps[4][104];
  __shared__ float red[8];
  const int r = blockIdx.x, tid = threadIdx.x;
  Ts[tid]       = tin ? tin[r * 512 + tid]       : 1.0f;
  Ts[tid + 256] = tin ? tin[r * 512 + tid + 256] : 1.0f;
  __syncthreads();
  // self-attn (Sq=1: softmax over 1 key == 1 -> out = V(t))
  float v0 = dot512(Ts, Wv + (size_t)tid * 512) + bv[tid];
  float v1 = dot512(Ts, Wv + (size_t)(tid + 256) * 512) + bv[tid + 256];
  Bs[tid] = v0; Bs[tid + 256] = v1;
  __syncthreads();
  float r0 = dot512(Bs, Wp + (size_t)tid * 512) + bp[tid] + Ts[tid];
  float r1 = dot512(Bs, Wp + (size_t)(tid + 256) * 512) + bp[tid + 256] + Ts[tid + 256];
  __syncthreads();
  float o0, o1;
  BLOCK_LN(r0, r1, g1, b1, o0, o1)
  Ts[tid] = o0; Ts[tid + 256] = o1;        // t1
  __syncthreads();
  // cross-attn Q
  float q0 = dot512(Ts, Wq + (size_t)tid * 512) + bq[tid];
  float q1 = dot512(Ts, Wq + (size_t)(tid + 256) * 512) + bq[tid + 256];
  Bs[tid] = q0; Bs[tid + 256] = q1;
  __syncthreads();
  // cross-attention: wave h handles head h; 100 keys, 2 per lane
  {
    const int h = tid >> 6, lane = tid & 63;
    const float scale = 0.08838834764831845f;
    const float* Qh = Bs + h * 128;
    float s0, s1 = -3e38f;
    {
      const float* kr = kvb + ((size_t)(lane * 32 + r)) * 1024 + h * 128;
      float a = 0.f;
#pragma unroll 16
      for (int d = 0; d < 128; ++d) a += Qh[d] * kr[d];
      s0 = a * scale;
    }
    if (lane + 64 < 100) {
      const float* kr = kvb + ((size_t)((lane + 64) * 32 + r)) * 1024 + h * 128;
      float a = 0.f;
#pragma unroll 16
      for (int d = 0; d < 128; ++d) a += Qh[d] * kr[d];
      s1 = a * scale;
    }
    float mx = fmaxf(s0, s1);
#pragma unroll
    for (int o = 32; o > 0; o >>= 1) mx = fmaxf(mx, __shfl_xor(mx, o));
    const float e0 = expf(s0 - mx);
    const float e1 = (lane + 64 < 100) ? expf(s1 - mx) : 0.f;
    float sm = e0 + e1;
#pragma unroll
    for (int o = 32; o > 0; o >>= 1) sm += __shfl_xor(sm, o);
    Ps[h][lane] = e0 / sm;
    if (lane + 64 < 100) Ps[h][lane + 64] = e1 / sm;
    __syncthreads();
    // PV: overwrite own Q slice with cav slice
#pragma unroll
    for (int u = 0; u < 2; ++u) {
      const int d = lane + u * 64;
      const float* vb = kvb + 512 + h * 128 + d;
      float a = 0.f;
      for (int k = 0; k < 100; ++k) a += Ps[h][k] * vb[(size_t)(k * 32 + r) * 1024];
      Bs[h * 128 + d] = a;
    }
  }
  __syncthreads();
  // ca proj + residual + LN2
  r0 = dot512(Bs, Wcp + (size_t)tid * 512) + bcp[tid] + Ts[tid];
  r1 = dot512(Bs, Wcp + (size_t)(tid + 256) * 512) + bcp[tid + 256] + Ts[tid + 256];
  __syncthreads();
  float t20, t21;
  BLOCK_LN(r0, r1, g2, b2, t20, t21)
  Ts[tid] = t20; Ts[tid + 256] = t21;      // t2
  __syncthreads();
  // FF1
#pragma unroll
  for (int v = 0; v < 4; ++v) {
    const int n = tid + v * 256;
    F1[n] = fmaxf(dot512(Ts, W1 + (size_t)n * 512) + b1f[n], 0.f);
  }
  __syncthreads();
  // FF2 + residual
  const float4* w2a = (const float4*)(W2 + (size_t)tid * 1024);
  const float4* w2b = (const float4*)(W2 + (size_t)(tid + 256) * 1024);
  float a0 = 0.f, a1 = 0.f;
#pragma unroll 8
  for (int k = 0; k < 256; ++k) {
    const float4 wa = w2a[k], wb = w2b[k];
    const float f0 = F1[4 * k], f1 = F1[4 * k + 1], f2 = F1[4 * k + 2], f3 = F1[4 * k + 3];
    a0 += f0 * wa.x + f1 * wa.y + f2 * wa.z + f3 * wa.w;
    a1 += f0 * wb.x + f1 * wb.y + f2 * wb.z + f3 * wb.w;
  }
  r0 = a0 + b2f[tid] + Ts[tid];
  r1 = a1 + b2f[tid + 256] + Ts[tid + 256];
  __syncthreads();
  BLOCK_LN(r0, r1, g3, b3, o0, o1)
  if (dofinal) {
    float f0, f1;
    BLOCK_LN(o0, o1, gf, bf_, f0, f1)
    o0 = f0; o1 = f1;
  }
  tout[r * 512 + tid] = o0;
  tout[r * 512 + tid + 256] = o1;
}

// ---------------------------------------------------------------------------
// Small fp32 GEMM, M=32, bf16 output into 128-row padded buffer (rows 32+ zeroed)
__global__ __launch_bounds__(256)
void sgemm32b(const float* __restrict__ A, const float* __restrict__ W,
              const float* __restrict__ bias, __hip_bfloat16* __restrict__ Cb, int N, int K)
{
  const int t = threadIdx.x;
  const int n = t & 63;
  const int mg = __builtin_amdgcn_readfirstlane(t >> 6);
  const int gn = blockIdx.x * 64 + n;
  const size_t wrow = (gn < N) ? (size_t)gn : 0;
  const float4* wp = (const float4*)(W + wrow * K);
  const float* Abase = A + (size_t)mg * 8 * K;
  float acc[8] = {0.f, 0.f, 0.f, 0.f, 0.f, 0.f, 0.f, 0.f};
  const int nk4 = K >> 2;
  for (int k4 = 0; k4 < nk4; ++k4) {
    const float4 wv = wp[k4];
#pragma unroll
    for (int i = 0; i < 8; ++i) {
      const float4 av = *(const float4*)(Abase + (size_t)i * K + k4 * 4);
      acc[i] += av.x * wv.x + av.y * wv.y + av.z * wv.z + av.w * wv.w;
    }
  }
  if (gn < N) {
    const float bb = bias[gn];
#pragma unroll
    for (int i = 0; i < 8; ++i)
      Cb[(size_t)(mg * 8 + i) * N + gn] = __float2bfloat16(fmaxf(acc[i] + bb, 0.f));
    const __hip_bfloat16 z = __float2bfloat16(0.f);
    for (int rr = 32 + mg; rr < 128; rr += 4)
      Cb[(size_t)rr * N + gn] = z;
  }
}

// ---------------------------------------------------------------------------
// out3 split-K reduce (+bias+relu) fused with adaptive pool. grid 32 (rows).
__global__ __launch_bounds__(256)
void reduce_pool(const float* __restrict__ P, size_t pstride,
                 const float* __restrict__ bias, float* __restrict__ out)
{
  __shared__ float row[NOUT3];
  const int b = blockIdx.x, t = threadIdx.x;
  for (int n = t * 4; n < NOUT3; n += 1024) {
    const size_t o = (size_t)b * NOUT3 + n;
    float4 s = *(const float4*)(P + o);
#pragma unroll
    for (int k = 1; k < 4; ++k) {
      const float4 p = *(const float4*)(P + (size_t)k * pstride + o);
      s.x += p.x; s.y += p.y; s.z += p.z; s.w += p.w;
    }
    const float4 b4 = *(const float4*)(bias + n);
    row[n]     = fmaxf(s.x + b4.x, 0.f);
    row[n + 1] = fmaxf(s.y + b4.y, 0.f);
    row[n + 2] = fmaxf(s.z + b4.z, 0.f);
    row[n + 3] = fmaxf(s.w + b4.w, 0.f);
  }
  __syncthreads();
  for (int i = t; i < 135 * 103; i += 256) {
    const int j = i % 103, r = i / 103;
    const int rs = (r * 143) / 135, re = ((r + 1) * 143 + 134) / 135;
    const int cs = (j * 111) / 103, ce = ((j + 1) * 111 + 102) / 103;
    float s = 0.f;
    for (int rr = rs; rr < re; ++rr)
      for (int cc = cs; cc < ce; ++cc)
        s += row[rr * 111 + cc];
    out[(size_t)b * (135 * 103) + i] = s / (float)((re - rs) * (ce - cs));
  }
}

// ---------------------------------------------------------------------------
extern "C" void kernel_launch(void* const* d_in, const int* in_sizes, int n_in,
                              void* d_out, int out_size, void* d_ws, size_t ws_size,
                              hipStream_t stream)
{
  (void)in_sizes; (void)n_in; (void)out_size; (void)ws_size;

  const float* x          = (const float*)d_in[0];
  const float* fc1_w      = (const float*)d_in[1];
  const float* fc1_b      = (const float*)d_in[2];
  const float* fc2_w      = (const float*)d_in[3];
  const float* fc2_b      = (const float*)d_in[4];
  const float* fc3_w      = (const float*)d_in[5];
  const float* fc3_b      = (const float*)d_in[6];
  const float* out1_w     = (const float*)d_in[7];
  const float* out1_b     = (const float*)d_in[8];
  const float* out2_w     = (const float*)d_in[9];
  const float* out2_b     = (const float*)d_in[10];
  const float* out3_w     = (const float*)d_in[11];
  const float* out3_b     = (const float*)d_in[12];
  const float* enc_qkv_w  = (const float*)d_in[13];
  const float* enc_qkv_b  = (const float*)d_in[14];
  const float* enc_proj_w = (const float*)d_in[15];
  const float* enc_proj_b = (const float*)d_in[16];
  const float* enc_ff1_w  = (const float*)d_in[17];
  const float* enc_ff1_b  = (const float*)d_in[18];
  const float* enc_ff2_w  = (const float*)d_in[19];
  const float* enc_ff2_b  = (const float*)d_in[20];
  const float* enc_ln1_g  = (const float*)d_in[21];
  const float* enc_ln1_b  = (const float*)d_in[22];
  const float* enc_ln2_g  = (const float*)d_in[23];
  const float* enc_ln2_b  = (const float*)d_in[24];
  const float* enc_lnf_g  = (const float*)d_in[25];
  const float* enc_lnf_b  = (const float*)d_in[26];
  const float* dec_sa_qkv_w  = (const float*)d_in[27];
  const float* dec_sa_qkv_b  = (const float*)d_in[28];
  const float* dec_sa_proj_w = (const float*)d_in[29];
  const float* dec_sa_proj_b = (const float*)d_in[30];
  const float* dec_ca_qkv_w  = (const float*)d_in[31];
  const float* dec_ca_qkv_b  = (const float*)d_in[32];
  const float* dec_ca_proj_w = (const float*)d_in[33];
  const float* dec_ca_proj_b = (const float*)d_in[34];
  const float* dec_ff1_w  = (const float*)d_in[35];
  const float* dec_ff1_b  = (const float*)d_in[36];
  const float* dec_ff2_w  = (const float*)d_in[37];
  const float* dec_ff2_b  = (const float*)d_in[38];
  const float* dec_ln1_g  = (const float*)d_in[39];
  const float* dec_ln1_b  = (const float*)d_in[40];
  const float* dec_ln2_g  = (const float*)d_in[41];
  const float* dec_ln2_b  = (const float*)d_in[42];
  const float* dec_ln3_g  = (const float*)d_in[43];
  const float* dec_ln3_b  = (const float*)d_in[44];
  const float* dec_lnf_g  = (const float*)d_in[45];
  const float* dec_lnf_b  = (const float*)d_in[46];

  char* wsp = (char*)d_ws;
  size_t off = 0;
  auto alloc = [&](size_t nbytes) -> char* {
    char* p = wsp + off;
    off += (nbytes + 255) & ~(size_t)255;
    return p;
  };

  __hip_bfloat16* xb     = (__hip_bfloat16*)alloc((size_t)MPAD * KPAD1 * 2);
  __hip_bfloat16* Wb1    = (__hip_bfloat16*)alloc((size_t)4096 * KPAD1 * 2);
  __hip_bfloat16* Wb2    = (__hip_bfloat16*)alloc((size_t)2048 * 4096 * 2);
  __hip_bfloat16* Wb3    = (__hip_bfloat16*)alloc((size_t)512 * 2048 * 2);
  __hip_bfloat16* Wqkvb  = (__hip_bfloat16*)alloc((size_t)2 * 1536 * 512 * 2);
  __hip_bfloat16* Wprojb = (__hip_bfloat16*)alloc((size_t)2 * 512 * 512 * 2);
  __hip_bfloat16* Wff1b  = (__hip_bfloat16*)alloc((size_t)2 * 1024 * 512 * 2);
  __hip_bfloat16* Wff2b  = (__hip_bfloat16*)alloc((size_t)2 * 512 * 1024 * 2);
  __hip_bfloat16* Wdkvb  = (__hip_bfloat16*)alloc((size_t)2 * 1536 * 512 * 2);
  int*   nz      = (int*)alloc(ROWS * 4);
  int*   padmask = (int*)alloc(ROWS * 4);
  int*   idx     = (int*)alloc(MPAD * 4);
  int*   pos     = (int*)alloc(ROWS * 4);
  int*   cnt     = (int*)alloc(256);
  __hip_bfloat16* h1c = (__hip_bfloat16*)alloc((size_t)MPAD * 4096 * 2);
  __hip_bfloat16* h2c = (__hip_bfloat16*)alloc((size_t)MPAD * 2048 * 2);
  float* hf  = (float*)alloc((size_t)ROWS * 512 * 4);
  __hip_bfloat16* hb = (__hip_bfloat16*)alloc((size_t)ROWS * 512 * 2);
  float* qkvbuf = (float*)alloc((size_t)ROWS * 1536 * 4);
  __hip_bfloat16* attnb = (__hip_bfloat16*)alloc((size_t)ROWS * 512 * 2);
  float* pjf  = (float*)alloc((size_t)ROWS * 512 * 4);
  __hip_bfloat16* f1b = (__hip_bfloat16*)alloc((size_t)ROWS * 1024 * 2);
  float* f2f  = (float*)alloc((size_t)ROWS * 512 * 4);
  float* memf = (float*)alloc((size_t)ROWS * 512 * 4);
  __hip_bfloat16* memb = (__hip_bfloat16*)alloc((size_t)ROWS * 512 * 2);
  float* kvbuf0 = (float*)alloc((size_t)ROWS * 1024 * 4);
  float* kvbuf1 = (float*)alloc((size_t)ROWS * 1024 * 4);
  float* tbuf = (float*)alloc(32 * 512 * 4);
  float* o1   = (float*)alloc(32 * 2048 * 4);
  float* biasP = (float*)alloc(NOUT3 * 4);
  // split-K partial buffers (time-shared)
  float* fcP  = (float*)alloc((size_t)4 * MPAD * 4096 * 4);   // 218 MB
  float* encP = (float*)alloc((size_t)2 * ROWS * 1536 * 4);   // aliases

  // phase-4 aliases (fcP/encP free after decoder)
  float* outP = fcP;
  __hip_bfloat16* Wo3b = (__hip_bfloat16*)((char*)fcP + ((size_t)48 << 20)); // 131 MB
  __hip_bfloat16* Wo2b = (__hip_bfloat16*)encP;                              // 16.8 MB
  __hip_bfloat16* o1b  = (__hip_bfloat16*)((char*)encP + ((size_t)20 << 20));
  __hip_bfloat16* o2b  = (__hip_bfloat16*)((char*)encP + ((size_t)22 << 20));

  const size_t psF1 = (size_t)MPAD * 4096;
  const size_t psF2 = (size_t)MPAD * 2048;
  const size_t psF3 = (size_t)MPAD * 512;

  // ---- phase 0 ----
  conv_x_kernel<<<ROWS + 1, 256, 0, stream>>>(x, xb, nz);
  compact_kernel<<<1, 256, 0, stream>>>(nz, idx, pos, cnt, padmask);
  {
    CvtArgs a;
    const float* srcs[8] = { enc_qkv_w, enc_proj_w, enc_ff1_w, enc_ff2_w,
                             dec_ca_qkv_w, fc2_w, fc3_w, out2_w };
    __hip_bfloat16* dsts[8] = { Wqkvb, Wprojb, Wff1b, Wff2b, Wdkvb, Wb2, Wb3, Wo2b };
    const int counts[8] = { 2*1536*512, 2*512*512, 2*1024*512, 2*512*1024,
                            2*1536*512, 2048*4096, 512*2048, 4096*2048 };
    int c = 0;
    for (int i = 0; i < 8; ++i) { a.src[i] = srcs[i]; a.dst[i] = dsts[i];
                                  a.cum[i] = c; c += counts[i] >> 11; }
    cvt_multi_kernel<<<c, 256, 0, stream>>>(a);
  }
  cvt_pad_kernel<<<dim3(KPAD1 / 512, 4096), 256, 0, stream>>>(fc1_w, Wb1, 4096, FLATIN, KPAD1);

  // ---- phase 1: input MLP (split-K) ----
  gemm_bf16<1><<<26 * 32 * 2, 256, 0, stream>>>(xb, Wb1, idx, cnt, fcP,
      KPAD1, 4096, 26, 2, psF1);
  reduce_kernel<1, 0, 1><<<dim3(4, MPAD), 256, 0, stream>>>(fcP, psF1, 2,
      fc1_b, nullptr, h1c, 4096, cnt);
  gemm_bf16<0><<<26 * 16 * 2, 256, 0, stream>>>(h1c, Wb2, nullptr, cnt, fcP,
      4096, 2048, 26, 2, psF2);
  reduce_kernel<1, 0, 1><<<dim3(2, MPAD), 256, 0, stream>>>(fcP, psF2, 2,
      fc2_b, nullptr, h2c, 2048, cnt);
  gemm_bf16<0><<<26 * 4 * 4, 256, 0, stream>>>(h2c, Wb3, nullptr, cnt, fcP,
      2048, 512, 26, 4, psF3);
  scatter_pe_reduce<<<ROWS, 256, 0, stream>>>(fcP, psF3, 4, pos, fc3_b, hf, hb);

  // ---- phase 2: encoder ----
  for (int L = 0; L < 2; ++L) {
    gemm_direct<0, 1, 0><<<25 * 12, 256, 0, stream>>>(hb, Wqkvb + (size_t)L * 1536 * 512,
        enc_qkv_b + L * 1536, qkvbuf, nullptr, 512, 1536, 25);
    enc_attn_kernel<<<dim3(128, 4), 256, 0, stream>>>(qkvbuf, padmask, attnb);
    gemm_direct<0, 1, 0><<<25 * 4, 256, 0, stream>>>(attnb, Wprojb + (size_t)L * 512 * 512,
        enc_proj_b + L * 512, pjf, nullptr, 512, 512, 25);
    ln_kernel<<<ROWS, 256, 0, stream>>>(hf, pjf, enc_ln1_g + L * 512, enc_ln1_b + L * 512,
        nullptr, nullptr, 0, hf, hb);
    gemm_direct<1, 0, 1><<<25 * 8, 256, 0, stream>>>(hb, Wff1b + (size_t)L * 1024 * 512,
        enc_ff1_b + L * 1024, nullptr, f1b, 512, 1024, 25);
    gemm_direct<0, 1, 0><<<25 * 4, 256, 0, stream>>>(f1b, Wff2b + (size_t)L * 512 * 1024,
        enc_ff2_b + L * 512, f2f, nullptr, 1024, 512, 25);
    if (L == 0) {
      ln_kernel<<<ROWS, 256, 0, stream>>>(hf, f2f, enc_ln2_g, enc_ln2_b,
          nullptr, nullptr, 0, hf, hb);
    } else {
      // ln2(L1) + final encoder LN fused -> memory
      ln_kernel<<<ROWS, 256, 0, stream>>>(hf, f2f, enc_ln2_g + 512, enc_ln2_b + 512,
          enc_lnf_g, enc_lnf_b, 1, memf, memb);
    }
  }

  // ---- decoder KV (depends only on memory) ----
  gemm_direct<0, 1, 0><<<25 * 8, 256, 0, stream>>>(memb, Wdkvb + (size_t)512 * 512,
      dec_ca_qkv_b + 512, kvbuf0, nullptr, 512, 1024, 25);
  gemm_direct<0, 1, 0><<<25 * 8, 256, 0, stream>>>(memb, Wdkvb + ((size_t)1536 + 512) * 512,
      dec_ca_qkv_b + 1536 + 512, kvbuf1, nullptr, 512, 1024, 25);

  // ---- phase 3: fully fused decoder layers ----
  for (int L = 0; L < 2; ++L) {
    dec_layer<<<32, 256, 0, stream>>>(
        (L == 0) ? nullptr : tbuf,
        (L == 0) ? kvbuf0 : kvbuf1,
        dec_sa_qkv_w + (size_t)L * 1536 * 512 + (size_t)1024 * 512,
        dec_sa_qkv_b + L * 1536 + 1024,
        dec_sa_proj_w + (size_t)L * 512 * 512, dec_sa_proj_b + L * 512,
        dec_ln1_g + L * 512, dec_ln1_b + L * 512,
        dec_ca_qkv_w + (size_t)L * 1536 * 512, dec_ca_qkv_b + L * 1536,
        dec_ca_proj_w + (size_t)L * 512 * 512, dec_ca_proj_b + L * 512,
        dec_ln2_g + L * 512, dec_ln2_b + L * 512,
        dec_ff1_w + (size_t)L * 1024 * 512, dec_ff1_b + L * 1024,
        dec_ff2_w + (size_t)L * 512 * 1024, dec_ff2_b + L * 512,
        dec_ln3_g + L * 512, dec_ln3_b + L * 512,
        dec_lnf_g, dec_lnf_b, (L == 1) ? 1 : 0, tbuf);
  }

  // ---- phase 4: output MLP ----
  sgemm32b<<<32, 256, 0, stream>>>(tbuf, out1_w, out1_b, o1b, 2048, 512);
  cvt_pad_kernel<<<dim3(8, NOUT3), 256, 0, stream>>>(out3_w, Wo3b, FLATIN, 4096, 4096);
  bias_pad_kernel<<<(NOUT3 + 255) / 256, 256, 0, stream>>>(out3_b, biasP);

  gemm_bf16<0><<<32 * 4, 256, 0, stream>>>(o1b, Wo2b, nullptr, nullptr, outP,
      2048, 4096, 1, 4, (size_t)128 * 4096);
  reduce_kernel<1, 0, 1><<<dim3(4, 128), 256, 0, stream>>>(outP, (size_t)128 * 4096, 4,
      out2_b, nullptr, o2b, 4096, nullptr);
  gemm_bf16<0><<<125 * 4, 256, 0, stream>>>(o2b, Wo3b, nullptr, nullptr, outP,
      4096, NOUT3, 1, 4, (size_t)128 * NOUT3);
  reduce_pool<<<32, 256, 0, stream>>>(outP, (size_t)128 * NOUT3, biasP, (float*)d_out);

  (void)o1; (void)qkvbuf; (void)pjf; (void)f2f; (void)memf;
}

// Round 9
// 1539.410 us; speedup vs baseline: 1.1470x; 1.1470x over previous
//
#include <hip/hip_runtime.h>
#include <hip/hip_bf16.h>

// ---------------------------------------------------------------------------
#define SEQ   100
#define BATCH 32
#define FLATIN 15873
#define KPAD1  16384
#define ROWS   3200
#define MPAD   3328
#define NOUT3  16000

typedef __attribute__((ext_vector_type(8))) short short8;
typedef __attribute__((ext_vector_type(4))) short short4v;
typedef __attribute__((ext_vector_type(4))) float f32x4;

__device__ __forceinline__ void gload_lds16(const void* g, void* l) {
  __builtin_amdgcn_global_load_lds((const __attribute__((address_space(1))) void*)g,
                                   (__attribute__((address_space(3))) void*)l, 16, 0, 0);
}

// bijective XCD chunk swizzle (m204)
__device__ __forceinline__ int xcd_swizzle(int id, int nwg) {
  const int q = nwg >> 3, r = nwg & 7;
  const int x = id & 7, p = id >> 3;
  return (x < r ? x * (q + 1) : r * (q + 1) + (x - r) * q) + p;
}

// ---------------------------------------------------------------------------
// Shared GEMM body: stage 128x64 A/B tiles (both-sides chunk swizzle), MFMA.
#define GEMM_BODY(KBEG, KEND)                                                   \
  const int tid  = threadIdx.x;                                                 \
  const int lane = tid & 63;                                                    \
  const int wid  = tid >> 6;                                                    \
  const int wr = (wid >> 1) << 6;                                               \
  const int wc = (wid & 1) << 6;                                                \
  f32x4 acc[4][4];                                                              \
  _Pragma("unroll") for (int i = 0; i < 4; ++i)                                 \
  _Pragma("unroll") for (int j = 0; j < 4; ++j)                                 \
      acc[i][j] = (f32x4){0.f, 0.f, 0.f, 0.f};                                  \
  const int srow = (wid << 3) + (lane >> 3);                                    \
  const int scs  = lane & 7;                                                    \
  const int gcol = ((scs ^ (srow & 7)) << 3);                                   \
  const __hip_bfloat16* arow[4];                                                \
  const __hip_bfloat16* brow[4];                                                \
  _Pragma("unroll") for (int j = 0; j < 4; ++j) {                               \
    const int row = (j << 5) + srow;                                            \
    const int gr = GATHER ? idx[m0 + row] : (m0 + row);                         \
    arow[j] = A + (size_t)gr * K + gcol;                                        \
    brow[j] = W + (size_t)(n0 + row) * K + gcol;                                \
  }                                                                             \
  for (int k0 = (KBEG); k0 < (KEND); k0 += 64) {                                \
    __syncthreads();                                                            \
    _Pragma("unroll") for (int j = 0; j < 4; ++j) {                             \
      short* la = As + (((j << 2) + wid) << 9);                                 \
      short* lb = Bs + (((j << 2) + wid) << 9);                                 \
      gload_lds16(arow[j] + k0, la);                                            \
      gload_lds16(brow[j] + k0, lb);                                            \
    }                                                                           \
    __syncthreads();                                                            \
    _Pragma("unroll") for (int kk = 0; kk < 2; ++kk) {                          \
      short8 af[4], bfv[4];                                                     \
      _Pragma("unroll") for (int i = 0; i < 4; ++i) {                           \
        const int mr = wr + (i << 4) + (lane & 15);                             \
        const int cg = (kk << 2) + (lane >> 4);                                 \
        af[i]  = *(const short8*)(As + mr * 64 + ((cg ^ (mr & 7)) << 3));       \
        const int nr = wc + (i << 4) + (lane & 15);                             \
        bfv[i] = *(const short8*)(Bs + nr * 64 + ((cg ^ (nr & 7)) << 3));       \
      }                                                                         \
      _Pragma("unroll") for (int i = 0; i < 4; ++i)                             \
      _Pragma("unroll") for (int j = 0; j < 4; ++j)                             \
          acc[i][j] = __builtin_amdgcn_mfma_f32_16x16x32_bf16(af[i], bfv[j],    \
                                                              acc[i][j], 0,0,0);\
    }                                                                           \
  }

// Split-K partial-output GEMM. mt-minor linearization.
template<int GATHER>
__global__ __launch_bounds__(256)
void gemm_bf16(const __hip_bfloat16* __restrict__ A, const __hip_bfloat16* __restrict__ W,
               const int* __restrict__ idx, const int* __restrict__ cnt,
               float* __restrict__ P,
               int K, int ldc, int mtiles, int ksl, size_t pstride)
{
  __shared__ __align__(16) short lds[16384];
  short* As = lds;
  short* Bs = lds + 8192;
  const int wg = xcd_swizzle(blockIdx.x, gridDim.x);
  const int mt = wg % mtiles;
  const int g  = wg / mtiles;
  const int nt = g / ksl;
  const int ks = g % ksl;
  const int m0 = mt << 7;
  const int n0 = nt << 7;
  if (cnt && m0 >= cnt[0]) return;
  const int Klen = K / ksl;
  const int kbeg = ks * Klen;

  GEMM_BODY(kbeg, kbeg + Klen)

  float* Pout = P + (size_t)ks * pstride;
  const int fr = lane & 15, fq = lane >> 4;
#pragma unroll
  for (int j = 0; j < 4; ++j) {
    const int n = n0 + wc + (j << 4) + fr;
#pragma unroll
    for (int i = 0; i < 4; ++i)
#pragma unroll
      for (int r = 0; r < 4; ++r) {
        const int m = m0 + wr + (i << 4) + (fq << 2) + r;
        Pout[(size_t)m * ldc + n] = acc[i][j][r];
      }
  }
}

// Direct GEMM with fused bias/relu epilogue
template<int RELU, int OF32, int OB16>
__global__ __launch_bounds__(256)
void gemm_direct(const __hip_bfloat16* __restrict__ A, const __hip_bfloat16* __restrict__ W,
                 const float* __restrict__ bias, float* __restrict__ Cf,
                 __hip_bfloat16* __restrict__ Cb, int K, int ldc, int mtiles)
{
  __shared__ __align__(16) short lds[16384];
  short* As = lds;
  short* Bs = lds + 8192;
  const int GATHER = 0;
  const int* idx = nullptr;
  const int wg = xcd_swizzle(blockIdx.x, gridDim.x);
  const int m0 = (wg % mtiles) << 7;
  const int n0 = (wg / mtiles) << 7;

  GEMM_BODY(0, K)

  const int fr = lane & 15, fq = lane >> 4;
#pragma unroll
  for (int j = 0; j < 4; ++j) {
    const int n = n0 + wc + (j << 4) + fr;
    const float bb = bias[n];
#pragma unroll
    for (int i = 0; i < 4; ++i)
#pragma unroll
      for (int r = 0; r < 4; ++r) {
        const int m = m0 + wr + (i << 4) + (fq << 2) + r;
        float v = acc[i][j][r] + bb;
        if (RELU) v = fmaxf(v, 0.f);
        if (OF32) Cf[(size_t)m * ldc + n] = v;
        if (OB16) Cb[(size_t)m * ldc + n] = __float2bfloat16(v);
      }
  }
}

// ---------------------------------------------------------------------------
// Split-K reduce: C = sum_ks P[ks] + bias [, relu]
template<int RELU, int OF32, int OB16>
__global__ __launch_bounds__(256)
void reduce_kernel(const float* __restrict__ P, size_t pstride, int ksl,
                   const float* __restrict__ bias, float* __restrict__ Cf,
                   __hip_bfloat16* __restrict__ Cb, int N,
                   const int* __restrict__ cnt)
{
  const int row = blockIdx.y;
  if (cnt) { const int cp = (cnt[0] + 127) & ~127; if (row >= cp) return; }
  const int n = (blockIdx.x * 256 + threadIdx.x) * 4;
  if (n >= N) return;
  const size_t o = (size_t)row * N + n;
  const float4 b4 = *(const float4*)(bias + n);
  float4 s = *(const float4*)(P + o);
  for (int k = 1; k < ksl; ++k) {
    const float4 p = *(const float4*)(P + (size_t)k * pstride + o);
    s.x += p.x; s.y += p.y; s.z += p.z; s.w += p.w;
  }
  s.x += b4.x; s.y += b4.y; s.z += b4.z; s.w += b4.w;
  if (RELU) {
    s.x = fmaxf(s.x, 0.f); s.y = fmaxf(s.y, 0.f);
    s.z = fmaxf(s.z, 0.f); s.w = fmaxf(s.w, 0.f);
  }
  if (OF32) *(float4*)(Cf + o) = s;
  if (OB16) {
    union { short4v v; __hip_bfloat16 h[4]; } u;
    u.h[0] = __float2bfloat16(s.x);
    u.h[1] = __float2bfloat16(s.y);
    u.h[2] = __float2bfloat16(s.z);
    u.h[3] = __float2bfloat16(s.w);
    *(short4v*)(Cb + o) = u.v;
  }
}

// ---------------------------------------------------------------------------
// x -> xb bf16; skip writes for all-zero rows; block ROWS zeroes canonical row.
__global__ __launch_bounds__(256)
void conv_x_kernel(const float* __restrict__ x, __hip_bfloat16* __restrict__ xb,
                   int* __restrict__ nz)
{
  __shared__ int sred[4];
  const int m = blockIdx.x;               // 0..ROWS
  const int t = threadIdx.x;
  __hip_bfloat16* dst = xb + (size_t)m * KPAD1;
  if (m == ROWS) {
    const __hip_bfloat162 z2 = {__float2bfloat16(0.f), __float2bfloat16(0.f)};
    for (int c = t; c < (KPAD1 >> 1); c += 256) *(__hip_bfloat162*)(dst + 2 * c) = z2;
    return;
  }
  const float* src = x + (size_t)m * FLATIN;
  int any = 0;
  for (int c = t; c < FLATIN; c += 256) any |= (src[c] != 0.f);
  any = __any(any) ? 1 : 0;
  if ((t & 63) == 0) sred[t >> 6] = any;
  __syncthreads();
  const int ba = sred[0] | sred[1] | sred[2] | sred[3];
  if (t == 0) nz[m] = ba;
  if (!ba) return;
  for (int c = t; c < (KPAD1 >> 1); c += 256) {
    const int c0 = 2 * c;
    const float v0 = (c0 < FLATIN) ? src[c0] : 0.f;
    const float v1 = (c0 + 1 < FLATIN) ? src[c0 + 1] : 0.f;
    __hip_bfloat162 pr;
    pr.x = __float2bfloat16(v0);
    pr.y = __float2bfloat16(v1);
    *(__hip_bfloat162*)(dst + c0) = pr;
  }
}

// Compaction + padding mask (single block)
__global__ __launch_bounds__(256)
void compact_kernel(const int* __restrict__ nz, int* __restrict__ idx,
                    int* __restrict__ pos, int* __restrict__ cnt,
                    int* __restrict__ pad)
{
  __shared__ int wsum[4];
  __shared__ int total;
  const int t = threadIdx.x;
  int loc[13];
  int c = 0;
#pragma unroll
  for (int i = 0; i < 13; ++i) {
    const int m = t * 13 + i;
    loc[i] = (m < ROWS) ? nz[m] : 0;
    c += loc[i];
  }
  int v = c;
#pragma unroll
  for (int o = 1; o < 64; o <<= 1) {
    const int u = __shfl_up(v, o);
    if ((t & 63) >= o) v += u;
  }
  if ((t & 63) == 63) wsum[t >> 6] = v;
  __syncthreads();
  int wbase = 0;
  for (int w = 0; w < (t >> 6); ++w) wbase += wsum[w];
  int p = wbase + v - c;
#pragma unroll
  for (int i = 0; i < 13; ++i) {
    const int m = t * 13 + i;
    if (m < ROWS) {
      if (loc[i]) { idx[p] = m; pos[m] = p; ++p; }
      else pos[m] = -1;
    }
  }
  if (t == 255) total = p;
  __syncthreads();
  const int count = total;
  if (t == 0) cnt[0] = count + 1;
  for (int i = count + t; i < MPAD; i += 256) idx[i] = ROWS;
  for (int m = t; m < ROWS; m += 256) if (pos[m] < 0) pos[m] = count;
  if (t < 32) {
    int any = 0;
    for (int s = 99; s >= 0; --s) {
      any |= nz[t * 100 + s];
      pad[t * 100 + s] = (s > 0 && !any) ? 1 : 0;
    }
  }
}

// fp32 -> bf16 pairwise with row AND column zero-pad
__global__ __launch_bounds__(256)
void cvt_pad_kernel(const float* __restrict__ in, __hip_bfloat16* __restrict__ out,
                    int rin, int cin, int cout)
{
  const int c = (blockIdx.x * 256 + threadIdx.x) * 2;
  const int r = blockIdx.y;
  if (c >= cout) return;
  const int rv = (r < rin);
  const float v0 = (rv && c < cin) ? in[(size_t)r * cin + c] : 0.f;
  const float v1 = (rv && c + 1 < cin) ? in[(size_t)r * cin + c + 1] : 0.f;
  __hip_bfloat162 pr;
  pr.x = __float2bfloat16(v0);
  pr.y = __float2bfloat16(v1);
  *(__hip_bfloat162*)(out + (size_t)r * cout + c) = pr;
}

// Multi-segment flat fp32->bf16 (counts multiples of 2048)
struct CvtArgs {
  const float* src[8];
  __hip_bfloat16* dst[8];
  int cum[8];
};
__global__ __launch_bounds__(256)
void cvt_multi_kernel(CvtArgs a)
{
  const int bid = blockIdx.x;
  int seg = 0;
#pragma unroll
  for (int i = 1; i < 8; ++i) if (bid >= a.cum[i]) seg = i;
  const size_t e0 = ((size_t)(bid - a.cum[seg]) << 11) + (threadIdx.x << 3);
  const float4 v0 = *(const float4*)(a.src[seg] + e0);
  const float4 v1 = *(const float4*)(a.src[seg] + e0 + 4);
  union { short4v v; __hip_bfloat16 h[4]; } u0, u1;
  u0.h[0] = __float2bfloat16(v0.x); u0.h[1] = __float2bfloat16(v0.y);
  u0.h[2] = __float2bfloat16(v0.z); u0.h[3] = __float2bfloat16(v0.w);
  u1.h[0] = __float2bfloat16(v1.x); u1.h[1] = __float2bfloat16(v1.y);
  u1.h[2] = __float2bfloat16(v1.z); u1.h[3] = __float2bfloat16(v1.w);
  *(short4v*)(a.dst[seg] + e0) = u0.v;
  *(short4v*)(a.dst[seg] + e0 + 4) = u1.v;
}

// Multi-segment tiled fp32 transpose: dst[C][R] = src[R][C]^T ; 64x64 tiles.
struct TrArgs {
  const float* src[13];
  float* dst[13];
  int R[13], C[13], cum[13];
};
__global__ __launch_bounds__(256)
void transpose_kernel(TrArgs a)
{
  __shared__ float tbuf[64][65];
  const int bid = blockIdx.x;
  int seg = 0;
#pragma unroll
  for (int i = 1; i < 13; ++i) if (bid >= a.cum[i]) seg = i;
  const int local = bid - a.cum[seg];
  const int R = a.R[seg], C = a.C[seg];
  const int tilesC = C >> 6;
  const int r0 = (local / tilesC) << 6;
  const int c0 = (local % tilesC) << 6;
  const int tx = threadIdx.x & 63, ty = threadIdx.x >> 6;
  const float* s = a.src[seg];
  float* d = a.dst[seg];
#pragma unroll
  for (int i = 0; i < 16; ++i) {
    const int rr = (ty << 4) + i;
    tbuf[rr][tx] = s[(size_t)(r0 + rr) * C + c0 + tx];
  }
  __syncthreads();
#pragma unroll
  for (int i = 0; i < 16; ++i) {
    const int cc = (ty << 4) + i;
    d[(size_t)(c0 + cc) * R + r0 + tx] = tbuf[tx][cc];
  }
}

// bias pad
__global__ void bias_pad_kernel(const float* __restrict__ b, float* __restrict__ bp)
{
  const int i = blockIdx.x * 256 + threadIdx.x;
  if (i < NOUT3) bp[i] = (i < FLATIN) ? b[i] : 0.f;
}

// fc3 reduce + bias + relu + scatter + inline PE
__global__ __launch_bounds__(256)
void scatter_pe_reduce(const float* __restrict__ P, size_t pstride, int ksl,
                       const int* __restrict__ pos, const float* __restrict__ bias,
                       float* __restrict__ hf, __hip_bfloat16* __restrict__ hb)
{
  const int m = blockIdx.x;
  const int s = m % 100, b = m / 100;
  const int src = pos[m];
  const int t = threadIdx.x;
  const size_t sb = (size_t)src * 512;
  const size_t db = (size_t)(s * 32 + b) * 512;
#pragma unroll
  for (int u = 0; u < 2; ++u) {
    const int d = t + u * 256;
    float v = bias[d];
    for (int k = 0; k < ksl; ++k) v += P[(size_t)k * pstride + sb + d];
    const float div = expf((float)(2 * (d >> 1)) * (-9.210340371976184f / 512.f));
    const float arg = (float)s * div;
    const float pe = (d & 1) ? cosf(arg) : sinf(arg);
    v = fmaxf(v, 0.f) + pe;
    hf[db + d] = v;
    hb[db + d] = __float2bfloat16(v);
  }
}

// ---------------------------------------------------------------------------
// LayerNorm over D=512 (+ optional second, final LN fused)
__global__ __launch_bounds__(256)
void ln_kernel(const float* __restrict__ x, const float* __restrict__ res,
               const float* __restrict__ g, const float* __restrict__ bta,
               const float* __restrict__ gf, const float* __restrict__ bf_,
               int dofinal, float* __restrict__ y, __hip_bfloat16* __restrict__ yb)
{
  __shared__ float rs[4], rss[4];
  const int row = blockIdx.x;
  const int t = threadIdx.x;
  const size_t base = (size_t)row * 512;
  float v0 = x[base + t];
  float v1 = x[base + t + 256];
  if (res) { v0 += res[base + t]; v1 += res[base + t + 256]; }
  float o0, o1;
#pragma unroll
  for (int pass = 0; pass < 2; ++pass) {
    float s = v0 + v1, ss = v0 * v0 + v1 * v1;
#pragma unroll
    for (int o = 32; o > 0; o >>= 1) { s += __shfl_xor(s, o); ss += __shfl_xor(ss, o); }
    if ((t & 63) == 0) { rs[t >> 6] = s; rss[t >> 6] = ss; }
    __syncthreads();
    s = rs[0] + rs[1] + rs[2] + rs[3];
    ss = rss[0] + rss[1] + rss[2] + rss[3];
    __syncthreads();
    const float mean = s * (1.f / 512.f);
    const float var = ss * (1.f / 512.f) - mean * mean;
    const float inv = rsqrtf(var + 1e-5f);
    const float* gg = (pass == 0) ? g : gf;
    const float* bb = (pass == 0) ? bta : bf_;
    o0 = (v0 - mean) * inv * gg[t] + bb[t];
    o1 = (v1 - mean) * inv * gg[t + 256] + bb[t + 256];
    if (pass == 1 || !dofinal) break;
    v0 = o0; v1 = o1;
  }
  if (y) {
    y[base + t] = o0;
    y[base + t + 256] = o1;
  }
  if (yb) {
    yb[base + t] = __float2bfloat16(o0);
    yb[base + t + 256] = __float2bfloat16(o1);
  }
}

// ---------------------------------------------------------------------------
// Encoder self-attention (unchanged)
__global__ __launch_bounds__(256)
void enc_attn_kernel(const float* __restrict__ qkv, const int* __restrict__ pad,
                     __hip_bfloat16* __restrict__ ob)
{
  __shared__ float Ks[100][129];
  __shared__ float Qs[128];
  __shared__ float Ps[100];
  __shared__ float red[4];
  const int bh = blockIdx.x;
  const int b = bh >> 2, h = bh & 3;
  const int q0 = blockIdx.y * 25;
  const int t = threadIdx.x;
  for (int i = t; i < 12800; i += 256) {
    const int s = i >> 7, d = i & 127;
    Ks[s][d] = qkv[(size_t)(s * 32 + b) * 1536 + 512 + h * 128 + d];
  }
  const int masked = (t < 100) ? pad[b * 100 + t] : 0;
  const float scale = 0.08838834764831845f;
  for (int qi = 0; qi < 25; ++qi) {
    const int q = q0 + qi;
    __syncthreads();
    if (t < 128) Qs[t] = qkv[(size_t)(q * 32 + b) * 1536 + h * 128 + t];
    __syncthreads();
    float sc = -3e38f;
    if (t < 100) {
      const float* kr = &Ks[t][0];
      float a = 0.f;
#pragma unroll 16
      for (int d = 0; d < 128; ++d) a += Qs[d] * kr[d];
      sc = masked ? -1e9f : (a * scale);
    }
    float mx = sc;
#pragma unroll
    for (int o = 32; o > 0; o >>= 1) mx = fmaxf(mx, __shfl_xor(mx, o));
    if ((t & 63) == 0) red[t >> 6] = mx;
    __syncthreads();
    mx = fmaxf(fmaxf(red[0], red[1]), fmaxf(red[2], red[3]));
    const float e = (t < 100) ? expf(sc - mx) : 0.f;
    float sm = e;
#pragma unroll
    for (int o = 32; o > 0; o >>= 1) sm += __shfl_xor(sm, o);
    __syncthreads();
    if ((t & 63) == 0) red[t >> 6] = sm;
    __syncthreads();
    sm = red[0] + red[1] + red[2] + red[3];
    if (t < 100) Ps[t] = e;
    __syncthreads();
    if (t < 128) {
      float a = 0.f;
      const float* vb = qkv + 1024 + h * 128 + t;
      for (int k = 0; k < 100; ++k) a += Ps[k] * vb[(size_t)(k * 32 + b) * 1536];
      ob[(size_t)(q * 32 + b) * 512 + h * 128 + t] = __float2bfloat16(a / sm);
    }
  }
}

// ---------------------------------------------------------------------------
// Fully fused decoder layer v2: transposed-weight coalesced GEMVs.
// 512 threads (8 waves), one block per batch row.
// gemvT<N,K,RELU>: out[n] = relu(bias[n] + sum_k S[k]*WT[k*N+n])
// thread -> (K-group g, output-quad p); S[k] is wave-uniform LDS broadcast,
// WT float4 loads are fully coalesced. Partials combined through LDS.
template<int N, int K, int RELU>
__device__ __forceinline__ void gemvT(int tid, const float* S,
                                      const float* __restrict__ WT,
                                      const float* __restrict__ bias,
                                      float* out, float* part)
{
  constexpr int NQ = N / 4;
  constexpr int G = 512 / NQ;
  constexpr int KP = K / G;
  const int p = tid % NQ;
  const int g = tid / NQ;
  const float4* wp = (const float4*)WT;
  float ax = 0.f, ay = 0.f, az = 0.f, aw = 0.f;
  const int kend = g * KP + KP;
#pragma unroll 8
  for (int k = g * KP; k < kend; ++k) {
    const float s = S[k];
    const float4 w = wp[(size_t)k * NQ + p];
    ax += s * w.x; ay += s * w.y; az += s * w.z; aw += s * w.w;
  }
  float4 a4 = {ax, ay, az, aw};
  *(float4*)(part + g * N + 4 * p) = a4;
  __syncthreads();
#pragma unroll
  for (int n = tid; n < N; n += 512) {
    float v = bias[n];
#pragma unroll
    for (int q = 0; q < G; ++q) v += part[q * N + n];
    if (RELU) v = fmaxf(v, 0.f);
    out[n] = v;
  }
  __syncthreads();
}

#define BLOCK_LN512(V, G, B, O)                                                 \
  {                                                                             \
    float s_ = (V), ss_ = (V) * (V);                                            \
    _Pragma("unroll")                                                           \
    for (int o_ = 32; o_ > 0; o_ >>= 1) {                                       \
      s_ += __shfl_xor(s_, o_); ss_ += __shfl_xor(ss_, o_);                     \
    }                                                                           \
    if ((tid & 63) == 0) { red[tid >> 6] = s_; red2[tid >> 6] = ss_; }          \
    __syncthreads();                                                            \
    s_ = 0.f; ss_ = 0.f;                                                        \
    _Pragma("unroll")                                                           \
    for (int w_ = 0; w_ < 8; ++w_) { s_ += red[w_]; ss_ += red2[w_]; }          \
    const float mean_ = s_ * (1.f / 512.f);                                     \
    const float inv_ = rsqrtf(ss_ * (1.f / 512.f) - mean_ * mean_ + 1e-5f);     \
    O = ((V) - mean_) * inv_ * (G)[tid] + (B)[tid];                             \
    __syncthreads();                                                            \
  }

__global__ __launch_bounds__(512)
void dec_layer(const float* __restrict__ tin,          // nullptr => ones
               const float* __restrict__ kvb,          // (3200 x 1024) k|v
               const float* __restrict__ WvT, const float* __restrict__ bv,
               const float* __restrict__ WpT, const float* __restrict__ bp,
               const float* __restrict__ g1, const float* __restrict__ b1,
               const float* __restrict__ WqT, const float* __restrict__ bq,
               const float* __restrict__ WcpT, const float* __restrict__ bcp,
               const float* __restrict__ g2, const float* __restrict__ b2,
               const float* __restrict__ W1T, const float* __restrict__ b1f,
               const float* __restrict__ W2T, const float* __restrict__ b2f,
               const float* __restrict__ g3, const float* __restrict__ b3,
               const float* __restrict__ gf, const float* __restrict__ bf_,
               int dofinal, float* __restrict__ tout)
{
  __shared__ float Ts[512], Bs[512], Cs[512], F1[1024], part[2048];
  __shared__ float Ps[4][104];
  __shared__ float red[8], red2[8];
  const int r = blockIdx.x, tid = threadIdx.x;
  Ts[tid] = tin ? tin[r * 512 + tid] : 1.0f;
  __syncthreads();

  // self-attn (Sq=1: softmax over one key == 1 -> out = V(t))
  gemvT<512, 512, 0>(tid, Ts, WvT, bv, Bs, part);
  gemvT<512, 512, 0>(tid, Bs, WpT, bp, Cs, part);
  {
    const float rr = Cs[tid] + Ts[tid];
    float o;
    BLOCK_LN512(rr, g1, b1, o)
    Ts[tid] = o;                          // t1
  }
  __syncthreads();

  // cross-attn Q
  gemvT<512, 512, 0>(tid, Ts, WqT, bq, Bs, part);

  // cross-attention: wave h<4 handles head h; 100 keys, 2 per lane
  if (tid < 256) {
    const int h = tid >> 6, lane = tid & 63;
    const float scale = 0.08838834764831845f;
    const float* Qh = Bs + h * 128;
    float s0, s1 = -3e38f;
    {
      const float* kr = kvb + ((size_t)(lane * 32 + r)) * 1024 + h * 128;
      float a = 0.f;
#pragma unroll 16
      for (int d = 0; d < 128; ++d) a += Qh[d] * kr[d];
      s0 = a * scale;
    }
    if (lane + 64 < 100) {
      const float* kr = kvb + ((size_t)((lane + 64) * 32 + r)) * 1024 + h * 128;
      float a = 0.f;
#pragma unroll 16
      for (int d = 0; d < 128; ++d) a += Qh[d] * kr[d];
      s1 = a * scale;
    }
    float mx = fmaxf(s0, s1);
#pragma unroll
    for (int o = 32; o > 0; o >>= 1) mx = fmaxf(mx, __shfl_xor(mx, o));
    const float e0 = expf(s0 - mx);
    const float e1 = (lane + 64 < 100) ? expf(s1 - mx) : 0.f;
    float sm = e0 + e1;
#pragma unroll
    for (int o = 32; o > 0; o >>= 1) sm += __shfl_xor(sm, o);
    Ps[h][lane] = e0 / sm;
    if (lane + 64 < 100) Ps[h][lane + 64] = e1 / sm;
  }
  __syncthreads();
  if (tid < 256) {
    const int h = tid >> 6, lane = tid & 63;
#pragma unroll
    for (int u = 0; u < 2; ++u) {
      const int d = lane + u * 64;
      const float* vb = kvb + 512 + h * 128 + d;
      float a = 0.f;
      for (int k = 0; k < 100; ++k) a += Ps[h][k] * vb[(size_t)(k * 32 + r) * 1024];
      Bs[h * 128 + d] = a;                // cav
    }
  }
  __syncthreads();

  // ca proj + residual + LN2
  gemvT<512, 512, 0>(tid, Bs, WcpT, bcp, Cs, part);
  {
    const float rr = Cs[tid] + Ts[tid];
    float o;
    BLOCK_LN512(rr, g2, b2, o)
    Ts[tid] = o;                          // t2
  }
  __syncthreads();

  // FF
  gemvT<1024, 512, 1>(tid, Ts, W1T, b1f, F1, part);
  gemvT<512, 1024, 0>(tid, F1, W2T, b2f, Cs, part);
  {
    const float rr = Cs[tid] + Ts[tid];
    float o;
    BLOCK_LN512(rr, g3, b3, o)
    if (dofinal) {
      float f;
      BLOCK_LN512(o, gf, bf_, f)
      o = f;
    }
    tout[r * 512 + tid] = o;
  }
}

// ---------------------------------------------------------------------------
// out1: C(32,2048) = A(32,512) @ Wo1T (coalesced, transposed weights),
// bf16 output into 128-row padded buffer. grid 128 (rows), 256 threads.
__global__ __launch_bounds__(256)
void out1_kernel(const float* __restrict__ A, const float* __restrict__ WT, // [512][2048]
                 const float* __restrict__ bias, __hip_bfloat16* __restrict__ Cb)
{
  __shared__ float S[512];
  const int r = blockIdx.x;
  const int tid = threadIdx.x;
  const int n0 = tid * 8;
  if (r >= 32) {
    const short4v z = {0, 0, 0, 0};
    *(short4v*)(Cb + (size_t)r * 2048 + n0) = z;
    *(short4v*)(Cb + (size_t)r * 2048 + n0 + 4) = z;
    return;
  }
  S[tid] = A[r * 512 + tid];
  S[tid + 256] = A[r * 512 + tid + 256];
  __syncthreads();
  float a[8] = {0.f, 0.f, 0.f, 0.f, 0.f, 0.f, 0.f, 0.f};
  const float4* wp = (const float4*)WT;
#pragma unroll 4
  for (int k = 0; k < 512; ++k) {
    const float s = S[k];
    const float4 w0 = wp[(size_t)k * 512 + tid * 2];
    const float4 w1 = wp[(size_t)k * 512 + tid * 2 + 1];
    a[0] += s * w0.x; a[1] += s * w0.y; a[2] += s * w0.z; a[3] += s * w0.w;
    a[4] += s * w1.x; a[5] += s * w1.y; a[6] += s * w1.z; a[7] += s * w1.w;
  }
  union { short4v v; __hip_bfloat16 h[4]; } u0, u1;
#pragma unroll
  for (int i = 0; i < 4; ++i) {
    u0.h[i] = __float2bfloat16(fmaxf(a[i] + bias[n0 + i], 0.f));
    u1.h[i] = __float2bfloat16(fmaxf(a[4 + i] + bias[n0 + 4 + i], 0.f));
  }
  *(short4v*)(Cb + (size_t)r * 2048 + n0) = u0.v;
  *(short4v*)(Cb + (size_t)r * 2048 + n0 + 4) = u1.v;
}

// ---------------------------------------------------------------------------
// out3 split-K reduce (+bias+relu) fused with adaptive pool. grid 32 (rows).
__global__ __launch_bounds__(256)
void reduce_pool(const float* __restrict__ P, size_t pstride,
                 const float* __restrict__ bias, float* __restrict__ out)
{
  __shared__ float row[NOUT3];
  const int b = blockIdx.x, t = threadIdx.x;
  for (int n = t * 4; n < NOUT3; n += 1024) {
    const size_t o = (size_t)b * NOUT3 + n;
    float4 s = *(const float4*)(P + o);
#pragma unroll
    for (int k = 1; k < 4; ++k) {
      const float4 p = *(const float4*)(P + (size_t)k * pstride + o);
      s.x += p.x; s.y += p.y; s.z += p.z; s.w += p.w;
    }
    const float4 b4 = *(const float4*)(bias + n);
    row[n]     = fmaxf(s.x + b4.x, 0.f);
    row[n + 1] = fmaxf(s.y + b4.y, 0.f);
    row[n + 2] = fmaxf(s.z + b4.z, 0.f);
    row[n + 3] = fmaxf(s.w + b4.w, 0.f);
  }
  __syncthreads();
  for (int i = t; i < 135 * 103; i += 256) {
    const int j = i % 103, r = i / 103;
    const int rs = (r * 143) / 135, re = ((r + 1) * 143 + 134) / 135;
    const int cs = (j * 111) / 103, ce = ((j + 1) * 111 + 102) / 103;
    float s = 0.f;
    for (int rr = rs; rr < re; ++rr)
      for (int cc = cs; cc < ce; ++cc)
        s += row[rr * 111 + cc];
    out[(size_t)b * (135 * 103) + i] = s / (float)((re - rs) * (ce - cs));
  }
}

// ---------------------------------------------------------------------------
extern "C" void kernel_launch(void* const* d_in, const int* in_sizes, int n_in,
                              void* d_out, int out_size, void* d_ws, size_t ws_size,
                              hipStream_t stream)
{
  (void)in_sizes; (void)n_in; (void)out_size; (void)ws_size;

  const float* x          = (const float*)d_in[0];
  const float* fc1_w      = (const float*)d_in[1];
  const float* fc1_b      = (const float*)d_in[2];
  const float* fc2_w      = (const float*)d_in[3];
  const float* fc2_b      = (const float*)d_in[4];
  const float* fc3_w      = (const float*)d_in[5];
  const float* fc3_b      = (const float*)d_in[6];
  const float* out1_w     = (const float*)d_in[7];
  const float* out1_b     = (const float*)d_in[8];
  const float* out2_w     = (const float*)d_in[9];
  const float* out2_b     = (const float*)d_in[10];
  const float* out3_w     = (const float*)d_in[11];
  const float* out3_b     = (const float*)d_in[12];
  const float* enc_qkv_w  = (const float*)d_in[13];
  const float* enc_qkv_b  = (const float*)d_in[14];
  const float* enc_proj_w = (const float*)d_in[15];
  const float* enc_proj_b = (const float*)d_in[16];
  const float* enc_ff1_w  = (const float*)d_in[17];
  const float* enc_ff1_b  = (const float*)d_in[18];
  const float* enc_ff2_w  = (const float*)d_in[19];
  const float* enc_ff2_b  = (const float*)d_in[20];
  const float* enc_ln1_g  = (const float*)d_in[21];
  const float* enc_ln1_b  = (const float*)d_in[22];
  const float* enc_ln2_g  = (const float*)d_in[23];
  const float* enc_ln2_b  = (const float*)d_in[24];
  const float* enc_lnf_g  = (const float*)d_in[25];
  const float* enc_lnf_b  = (const float*)d_in[26];
  const float* dec_sa_qkv_w  = (const float*)d_in[27];
  const float* dec_sa_qkv_b  = (const float*)d_in[28];
  const float* dec_sa_proj_w = (const float*)d_in[29];
  const float* dec_sa_proj_b = (const float*)d_in[30];
  const float* dec_ca_qkv_w  = (const float*)d_in[31];
  const float* dec_ca_qkv_b  = (const float*)d_in[32];
  const float* dec_ca_proj_w = (const float*)d_in[33];
  const float* dec_ca_proj_b = (const float*)d_in[34];
  const float* dec_ff1_w  = (const float*)d_in[35];
  const float* dec_ff1_b  = (const float*)d_in[36];
  const float* dec_ff2_w  = (const float*)d_in[37];
  const float* dec_ff2_b  = (const float*)d_in[38];
  const float* dec_ln1_g  = (const float*)d_in[39];
  const float* dec_ln1_b  = (const float*)d_in[40];
  const float* dec_ln2_g  = (const float*)d_in[41];
  const float* dec_ln2_b  = (const float*)d_in[42];
  const float* dec_ln3_g  = (const float*)d_in[43];
  const float* dec_ln3_b  = (const float*)d_in[44];
  const float* dec_lnf_g  = (const float*)d_in[45];
  const float* dec_lnf_b  = (const float*)d_in[46];

  char* wsp = (char*)d_ws;
  size_t off = 0;
  auto alloc = [&](size_t nbytes) -> char* {
    char* p = wsp + off;
    off += (nbytes + 255) & ~(size_t)255;
    return p;
  };

  __hip_bfloat16* xb     = (__hip_bfloat16*)alloc((size_t)MPAD * KPAD1 * 2);
  __hip_bfloat16* Wb1    = (__hip_bfloat16*)alloc((size_t)4096 * KPAD1 * 2);
  __hip_bfloat16* Wb2    = (__hip_bfloat16*)alloc((size_t)2048 * 4096 * 2);
  __hip_bfloat16* Wb3    = (__hip_bfloat16*)alloc((size_t)512 * 2048 * 2);
  __hip_bfloat16* Wqkvb  = (__hip_bfloat16*)alloc((size_t)2 * 1536 * 512 * 2);
  __hip_bfloat16* Wprojb = (__hip_bfloat16*)alloc((size_t)2 * 512 * 512 * 2);
  __hip_bfloat16* Wff1b  = (__hip_bfloat16*)alloc((size_t)2 * 1024 * 512 * 2);
  __hip_bfloat16* Wff2b  = (__hip_bfloat16*)alloc((size_t)2 * 512 * 1024 * 2);
  __hip_bfloat16* Wdkvb  = (__hip_bfloat16*)alloc((size_t)2 * 1536 * 512 * 2);
  int*   nz      = (int*)alloc(ROWS * 4);
  int*   padmask = (int*)alloc(ROWS * 4);
  int*   idx     = (int*)alloc(MPAD * 4);
  int*   pos     = (int*)alloc(ROWS * 4);
  int*   cnt     = (int*)alloc(256);
  __hip_bfloat16* h1c = (__hip_bfloat16*)alloc((size_t)MPAD * 4096 * 2);
  __hip_bfloat16* h2c = (__hip_bfloat16*)alloc((size_t)MPAD * 2048 * 2);
  float* hf  = (float*)alloc((size_t)ROWS * 512 * 4);
  __hip_bfloat16* hb = (__hip_bfloat16*)alloc((size_t)ROWS * 512 * 2);
  float* qkvbuf = (float*)alloc((size_t)ROWS * 1536 * 4);
  __hip_bfloat16* attnb = (__hip_bfloat16*)alloc((size_t)ROWS * 512 * 2);
  float* pjf  = (float*)alloc((size_t)ROWS * 512 * 4);
  __hip_bfloat16* f1b = (__hip_bfloat16*)alloc((size_t)ROWS * 1024 * 2);
  float* f2f  = (float*)alloc((size_t)ROWS * 512 * 4);
  float* memf = (float*)alloc((size_t)ROWS * 512 * 4);
  __hip_bfloat16* memb = (__hip_bfloat16*)alloc((size_t)ROWS * 512 * 2);
  float* kvbuf0 = (float*)alloc((size_t)ROWS * 1024 * 4);
  float* kvbuf1 = (float*)alloc((size_t)ROWS * 1024 * 4);
  float* tbuf = (float*)alloc(32 * 512 * 4);
  float* biasP = (float*)alloc(NOUT3 * 4);
  // transposed fp32 weights (decoder + out1)
  float* WvT[2]  = { (float*)alloc(512 * 512 * 4), (float*)alloc(512 * 512 * 4) };
  float* WpT[2]  = { (float*)alloc(512 * 512 * 4), (float*)alloc(512 * 512 * 4) };
  float* WqT[2]  = { (float*)alloc(512 * 512 * 4), (float*)alloc(512 * 512 * 4) };
  float* WcpT[2] = { (float*)alloc(512 * 512 * 4), (float*)alloc(512 * 512 * 4) };
  float* W1T[2]  = { (float*)alloc(512 * 1024 * 4), (float*)alloc(512 * 1024 * 4) };
  float* W2T[2]  = { (float*)alloc(1024 * 512 * 4), (float*)alloc(1024 * 512 * 4) };
  float* Wo1T    = (float*)alloc((size_t)512 * 2048 * 4);
  // split-K partial buffers (time-shared)
  float* fcP  = (float*)alloc((size_t)4 * MPAD * 4096 * 4);   // 218 MB
  float* encP = (float*)alloc((size_t)2 * ROWS * 1536 * 4);   // aliases

  // phase-4 aliases (fcP/encP free after decoder)
  float* outP = fcP;
  __hip_bfloat16* Wo3b = (__hip_bfloat16*)((char*)fcP + ((size_t)48 << 20)); // 131 MB
  __hip_bfloat16* Wo2b = (__hip_bfloat16*)encP;                              // 16.8 MB
  __hip_bfloat16* o1b  = (__hip_bfloat16*)((char*)encP + ((size_t)20 << 20));
  __hip_bfloat16* o2b  = (__hip_bfloat16*)((char*)encP + ((size_t)22 << 20));

  const size_t psF1 = (size_t)MPAD * 4096;
  const size_t psF2 = (size_t)MPAD * 2048;
  const size_t psF3 = (size_t)MPAD * 512;

  // ---- phase 0 ----
  conv_x_kernel<<<ROWS + 1, 256, 0, stream>>>(x, xb, nz);
  compact_kernel<<<1, 256, 0, stream>>>(nz, idx, pos, cnt, padmask);
  {
    CvtArgs a;
    const float* srcs[8] = { enc_qkv_w, enc_proj_w, enc_ff1_w, enc_ff2_w,
                             dec_ca_qkv_w, fc2_w, fc3_w, out2_w };
    __hip_bfloat16* dsts[8] = { Wqkvb, Wprojb, Wff1b, Wff2b, Wdkvb, Wb2, Wb3, Wo2b };
    const int counts[8] = { 2*1536*512, 2*512*512, 2*1024*512, 2*512*1024,
                            2*1536*512, 2048*4096, 512*2048, 4096*2048 };
    int c = 0;
    for (int i = 0; i < 8; ++i) { a.src[i] = srcs[i]; a.dst[i] = dsts[i];
                                  a.cum[i] = c; c += counts[i] >> 11; }
    cvt_multi_kernel<<<c, 256, 0, stream>>>(a);
  }
  cvt_pad_kernel<<<dim3(KPAD1 / 512, 4096), 256, 0, stream>>>(fc1_w, Wb1, 4096, FLATIN, KPAD1);
  {
    TrArgs a;
    const float* srcs[13];
    float* dsts[13];
    int R[13], C[13];
    int n = 0;
    for (int L = 0; L < 2; ++L) {
      srcs[n] = dec_sa_qkv_w + (size_t)L * 1536 * 512 + (size_t)1024 * 512;
      dsts[n] = WvT[L]; R[n] = 512; C[n] = 512; ++n;
      srcs[n] = dec_sa_proj_w + (size_t)L * 512 * 512;
      dsts[n] = WpT[L]; R[n] = 512; C[n] = 512; ++n;
      srcs[n] = dec_ca_qkv_w + (size_t)L * 1536 * 512;
      dsts[n] = WqT[L]; R[n] = 512; C[n] = 512; ++n;
      srcs[n] = dec_ca_proj_w + (size_t)L * 512 * 512;
      dsts[n] = WcpT[L]; R[n] = 512; C[n] = 512; ++n;
      srcs[n] = dec_ff1_w + (size_t)L * 1024 * 512;
      dsts[n] = W1T[L]; R[n] = 1024; C[n] = 512; ++n;
      srcs[n] = dec_ff2_w + (size_t)L * 512 * 1024;
      dsts[n] = W2T[L]; R[n] = 512; C[n] = 1024; ++n;
    }
    srcs[n] = out1_w; dsts[n] = Wo1T; R[n] = 2048; C[n] = 512; ++n;
    int c = 0;
    for (int i = 0; i < 13; ++i) {
      a.src[i] = srcs[i]; a.dst[i] = dsts[i]; a.R[i] = R[i]; a.C[i] = C[i];
      a.cum[i] = c; c += (R[i] >> 6) * (C[i] >> 6);
    }
    transpose_kernel<<<c, 256, 0, stream>>>(a);
  }

  // ---- phase 1: input MLP (split-K) ----
  gemm_bf16<1><<<26 * 32 * 2, 256, 0, stream>>>(xb, Wb1, idx, cnt, fcP,
      KPAD1, 4096, 26, 2, psF1);
  reduce_kernel<1, 0, 1><<<dim3(4, MPAD), 256, 0, stream>>>(fcP, psF1, 2,
      fc1_b, nullptr, h1c, 4096, cnt);
  gemm_bf16<0><<<26 * 16 * 2, 256, 0, stream>>>(h1c, Wb2, nullptr, cnt, fcP,
      4096, 2048, 26, 2, psF2);
  reduce_kernel<1, 0, 1><<<dim3(2, MPAD), 256, 0, stream>>>(fcP, psF2, 2,
      fc2_b, nullptr, h2c, 2048, cnt);
  gemm_bf16<0><<<26 * 4 * 4, 256, 0, stream>>>(h2c, Wb3, nullptr, cnt, fcP,
      2048, 512, 26, 4, psF3);
  scatter_pe_reduce<<<ROWS, 256, 0, stream>>>(fcP, psF3, 4, pos, fc3_b, hf, hb);

  // ---- phase 2: encoder ----
  for (int L = 0; L < 2; ++L) {
    gemm_direct<0, 1, 0><<<25 * 12, 256, 0, stream>>>(hb, Wqkvb + (size_t)L * 1536 * 512,
        enc_qkv_b + L * 1536, qkvbuf, nullptr, 512, 1536, 25);
    enc_attn_kernel<<<dim3(128, 4), 256, 0, stream>>>(qkvbuf, padmask, attnb);
    gemm_direct<0, 1, 0><<<25 * 4, 256, 0, stream>>>(attnb, Wprojb + (size_t)L * 512 * 512,
        enc_proj_b + L * 512, pjf, nullptr, 512, 512, 25);
    ln_kernel<<<ROWS, 256, 0, stream>>>(hf, pjf, enc_ln1_g + L * 512, enc_ln1_b + L * 512,
        nullptr, nullptr, 0, hf, hb);
    gemm_direct<1, 0, 1><<<25 * 8, 256, 0, stream>>>(hb, Wff1b + (size_t)L * 1024 * 512,
        enc_ff1_b + L * 1024, nullptr, f1b, 512, 1024, 25);
    gemm_direct<0, 1, 0><<<25 * 4, 256, 0, stream>>>(f1b, Wff2b + (size_t)L * 512 * 1024,
        enc_ff2_b + L * 512, f2f, nullptr, 1024, 512, 25);
    if (L == 0) {
      ln_kernel<<<ROWS, 256, 0, stream>>>(hf, f2f, enc_ln2_g, enc_ln2_b,
          nullptr, nullptr, 0, hf, hb);
    } else {
      ln_kernel<<<ROWS, 256, 0, stream>>>(hf, f2f, enc_ln2_g + 512, enc_ln2_b + 512,
          enc_lnf_g, enc_lnf_b, 1, memf, memb);
    }
  }

  // ---- decoder KV ----
  gemm_direct<0, 1, 0><<<25 * 8, 256, 0, stream>>>(memb, Wdkvb + (size_t)512 * 512,
      dec_ca_qkv_b + 512, kvbuf0, nullptr, 512, 1024, 25);
  gemm_direct<0, 1, 0><<<25 * 8, 256, 0, stream>>>(memb, Wdkvb + ((size_t)1536 + 512) * 512,
      dec_ca_qkv_b + 1536 + 512, kvbuf1, nullptr, 512, 1024, 25);

  // ---- phase 3: fused decoder layers (transposed-weight GEMVs) ----
  for (int L = 0; L < 2; ++L) {
    dec_layer<<<32, 512, 0, stream>>>(
        (L == 0) ? nullptr : tbuf,
        (L == 0) ? kvbuf0 : kvbuf1,
        WvT[L], dec_sa_qkv_b + L * 1536 + 1024,
        WpT[L], dec_sa_proj_b + L * 512,
        dec_ln1_g + L * 512, dec_ln1_b + L * 512,
        WqT[L], dec_ca_qkv_b + L * 1536,
        WcpT[L], dec_ca_proj_b + L * 512,
        dec_ln2_g + L * 512, dec_ln2_b + L * 512,
        W1T[L], dec_ff1_b + L * 1024,
        W2T[L], dec_ff2_b + L * 512,
        dec_ln3_g + L * 512, dec_ln3_b + L * 512,
        dec_lnf_g, dec_lnf_b, (L == 1) ? 1 : 0, tbuf);
  }

  // ---- phase 4: output MLP ----
  out1_kernel<<<128, 256, 0, stream>>>(tbuf, Wo1T, out1_b, o1b);
  cvt_pad_kernel<<<dim3(8, NOUT3), 256, 0, stream>>>(out3_w, Wo3b, FLATIN, 4096, 4096);
  bias_pad_kernel<<<(NOUT3 + 255) / 256, 256, 0, stream>>>(out3_b, biasP);

  gemm_bf16<0><<<32 * 4, 256, 0, stream>>>(o1b, Wo2b, nullptr, nullptr, outP,
      2048, 4096, 1, 4, (size_t)128 * 4096);
  reduce_kernel<1, 0, 1><<<dim3(4, 128), 256, 0, stream>>>(outP, (size_t)128 * 4096, 4,
      out2_b, nullptr, o2b, 4096, nullptr);
  gemm_bf16<0><<<125 * 4, 256, 0, stream>>>(o2b, Wo3b, nullptr, nullptr, outP,
      4096, NOUT3, 1, 4, (size_t)128 * NOUT3);
  reduce_pool<<<32, 256, 0, stream>>>(outP, (size_t)128 * NOUT3, biasP, (float*)d_out);

  (void)qkvbuf; (void)pjf; (void)f2f; (void)memf;
}

// Round 10
// 1498.358 us; speedup vs baseline: 1.1784x; 1.0274x over previous
//
#include <hip/hip_runtime.h>
#include <hip/hip_bf16.h>

// ---------------------------------------------------------------------------
#define SEQ   100
#define BATCH 32
#define FLATIN 15873
#define KPAD1  16384
#define ROWS   3200
#define MPAD   3328
#define NOUT3  16000

typedef __attribute__((ext_vector_type(8))) short short8;
typedef __attribute__((ext_vector_type(4))) short short4v;
typedef __attribute__((ext_vector_type(4))) float f32x4;

__device__ __forceinline__ void gload_lds16(const void* g, void* l) {
  __builtin_amdgcn_global_load_lds((const __attribute__((address_space(1))) void*)g,
                                   (__attribute__((address_space(3))) void*)l, 16, 0, 0);
}

// bijective XCD chunk swizzle (m204)
__device__ __forceinline__ int xcd_swizzle(int id, int nwg) {
  const int q = nwg >> 3, r = nwg & 7;
  const int x = id & 7, p = id >> 3;
  return (x < r ? x * (q + 1) : r * (q + 1) + (x - r) * q) + p;
}

// ---------------------------------------------------------------------------
// Shared GEMM body: stage 128x64 A/B tiles (both-sides chunk swizzle), MFMA.
#define GEMM_BODY(KBEG, KEND)                                                   \
  const int tid  = threadIdx.x;                                                 \
  const int lane = tid & 63;                                                    \
  const int wid  = tid >> 6;                                                    \
  const int wr = (wid >> 1) << 6;                                               \
  const int wc = (wid & 1) << 6;                                                \
  f32x4 acc[4][4];                                                              \
  _Pragma("unroll") for (int i = 0; i < 4; ++i)                                 \
  _Pragma("unroll") for (int j = 0; j < 4; ++j)                                 \
      acc[i][j] = (f32x4){0.f, 0.f, 0.f, 0.f};                                  \
  const int srow = (wid << 3) + (lane >> 3);                                    \
  const int scs  = lane & 7;                                                    \
  const int gcol = ((scs ^ (srow & 7)) << 3);                                   \
  const __hip_bfloat16* arow[4];                                                \
  const __hip_bfloat16* brow[4];                                                \
  _Pragma("unroll") for (int j = 0; j < 4; ++j) {                               \
    const int row = (j << 5) + srow;                                            \
    const int gr = GATHER ? idx[m0 + row] : (m0 + row);                         \
    arow[j] = A + (size_t)gr * K + gcol;                                        \
    brow[j] = W + (size_t)(n0 + row) * K + gcol;                                \
  }                                                                             \
  for (int k0 = (KBEG); k0 < (KEND); k0 += 64) {                                \
    __syncthreads();                                                            \
    _Pragma("unroll") for (int j = 0; j < 4; ++j) {                             \
      short* la = As + (((j << 2) + wid) << 9);                                 \
      short* lb = Bs + (((j << 2) + wid) << 9);                                 \
      gload_lds16(arow[j] + k0, la);                                            \
      gload_lds16(brow[j] + k0, lb);                                            \
    }                                                                           \
    __syncthreads();                                                            \
    _Pragma("unroll") for (int kk = 0; kk < 2; ++kk) {                          \
      short8 af[4], bfv[4];                                                     \
      _Pragma("unroll") for (int i = 0; i < 4; ++i) {                           \
        const int mr = wr + (i << 4) + (lane & 15);                             \
        const int cg = (kk << 2) + (lane >> 4);                                 \
        af[i]  = *(const short8*)(As + mr * 64 + ((cg ^ (mr & 7)) << 3));       \
        const int nr = wc + (i << 4) + (lane & 15);                             \
        bfv[i] = *(const short8*)(Bs + nr * 64 + ((cg ^ (nr & 7)) << 3));       \
      }                                                                         \
      _Pragma("unroll") for (int i = 0; i < 4; ++i)                             \
      _Pragma("unroll") for (int j = 0; j < 4; ++j)                             \
          acc[i][j] = __builtin_amdgcn_mfma_f32_16x16x32_bf16(af[i], bfv[j],    \
                                                              acc[i][j], 0,0,0);\
    }                                                                           \
  }

// Split-K partial-output GEMM. mt-minor linearization.
template<int GATHER>
__global__ __launch_bounds__(256)
void gemm_bf16(const __hip_bfloat16* __restrict__ A, const __hip_bfloat16* __restrict__ W,
               const int* __restrict__ idx, const int* __restrict__ cnt,
               float* __restrict__ P,
               int K, int ldc, int mtiles, int ksl, size_t pstride)
{
  __shared__ __align__(16) short lds[16384];
  short* As = lds;
  short* Bs = lds + 8192;
  const int wg = xcd_swizzle(blockIdx.x, gridDim.x);
  const int mt = wg % mtiles;
  const int g  = wg / mtiles;
  const int nt = g / ksl;
  const int ks = g % ksl;
  const int m0 = mt << 7;
  const int n0 = nt << 7;
  if (cnt && m0 >= cnt[0]) return;
  const int Klen = K / ksl;
  const int kbeg = ks * Klen;

  GEMM_BODY(kbeg, kbeg + Klen)

  float* Pout = P + (size_t)ks * pstride;
  const int fr = lane & 15, fq = lane >> 4;
#pragma unroll
  for (int j = 0; j < 4; ++j) {
    const int n = n0 + wc + (j << 4) + fr;
#pragma unroll
    for (int i = 0; i < 4; ++i)
#pragma unroll
      for (int r = 0; r < 4; ++r) {
        const int m = m0 + wr + (i << 4) + (fq << 2) + r;
        Pout[(size_t)m * ldc + n] = acc[i][j][r];
      }
  }
}

// Direct GEMM with fused bias/relu epilogue
template<int RELU, int OF32, int OB16>
__global__ __launch_bounds__(256)
void gemm_direct(const __hip_bfloat16* __restrict__ A, const __hip_bfloat16* __restrict__ W,
                 const float* __restrict__ bias, float* __restrict__ Cf,
                 __hip_bfloat16* __restrict__ Cb, int K, int ldc, int mtiles)
{
  __shared__ __align__(16) short lds[16384];
  short* As = lds;
  short* Bs = lds + 8192;
  const int GATHER = 0;
  const int* idx = nullptr;
  const int wg = xcd_swizzle(blockIdx.x, gridDim.x);
  const int m0 = (wg % mtiles) << 7;
  const int n0 = (wg / mtiles) << 7;

  GEMM_BODY(0, K)

  const int fr = lane & 15, fq = lane >> 4;
#pragma unroll
  for (int j = 0; j < 4; ++j) {
    const int n = n0 + wc + (j << 4) + fr;
    const float bb = bias[n];
#pragma unroll
    for (int i = 0; i < 4; ++i)
#pragma unroll
      for (int r = 0; r < 4; ++r) {
        const int m = m0 + wr + (i << 4) + (fq << 2) + r;
        float v = acc[i][j][r] + bb;
        if (RELU) v = fmaxf(v, 0.f);
        if (OF32) Cf[(size_t)m * ldc + n] = v;
        if (OB16) Cb[(size_t)m * ldc + n] = __float2bfloat16(v);
      }
  }
}

// ---------------------------------------------------------------------------
// Split-K reduce: C = sum_ks P[ks] + bias [, relu]
template<int RELU, int OF32, int OB16>
__global__ __launch_bounds__(256)
void reduce_kernel(const float* __restrict__ P, size_t pstride, int ksl,
                   const float* __restrict__ bias, float* __restrict__ Cf,
                   __hip_bfloat16* __restrict__ Cb, int N,
                   const int* __restrict__ cnt)
{
  const int row = blockIdx.y;
  if (cnt) { const int cp = (cnt[0] + 127) & ~127; if (row >= cp) return; }
  const int n = (blockIdx.x * 256 + threadIdx.x) * 4;
  if (n >= N) return;
  const size_t o = (size_t)row * N + n;
  const float4 b4 = *(const float4*)(bias + n);
  float4 s = *(const float4*)(P + o);
  for (int k = 1; k < ksl; ++k) {
    const float4 p = *(const float4*)(P + (size_t)k * pstride + o);
    s.x += p.x; s.y += p.y; s.z += p.z; s.w += p.w;
  }
  s.x += b4.x; s.y += b4.y; s.z += b4.z; s.w += b4.w;
  if (RELU) {
    s.x = fmaxf(s.x, 0.f); s.y = fmaxf(s.y, 0.f);
    s.z = fmaxf(s.z, 0.f); s.w = fmaxf(s.w, 0.f);
  }
  if (OF32) *(float4*)(Cf + o) = s;
  if (OB16) {
    union { short4v v; __hip_bfloat16 h[4]; } u;
    u.h[0] = __float2bfloat16(s.x);
    u.h[1] = __float2bfloat16(s.y);
    u.h[2] = __float2bfloat16(s.z);
    u.h[3] = __float2bfloat16(s.w);
    *(short4v*)(Cb + o) = u.v;
  }
}

// ---------------------------------------------------------------------------
// x -> xb bf16 single pass (convert + any-check together; always write)
__global__ __launch_bounds__(256)
void conv_x_kernel(const float* __restrict__ x, __hip_bfloat16* __restrict__ xb,
                   int* __restrict__ nz)
{
  __shared__ int sred[4];
  const int m = blockIdx.x;               // 0..ROWS
  const int t = threadIdx.x;
  __hip_bfloat16* dst = xb + (size_t)m * KPAD1;
  if (m == ROWS) {
    const __hip_bfloat162 z2 = {__float2bfloat16(0.f), __float2bfloat16(0.f)};
    for (int c = t; c < (KPAD1 >> 1); c += 256) *(__hip_bfloat162*)(dst + 2 * c) = z2;
    return;
  }
  const float* src = x + (size_t)m * FLATIN;
  int any = 0;
  for (int c = t; c < (KPAD1 >> 1); c += 256) {
    const int c0 = 2 * c;
    const float v0 = (c0 < FLATIN) ? src[c0] : 0.f;
    const float v1 = (c0 + 1 < FLATIN) ? src[c0 + 1] : 0.f;
    any |= (v0 != 0.f) | (v1 != 0.f);
    __hip_bfloat162 pr;
    pr.x = __float2bfloat16(v0);
    pr.y = __float2bfloat16(v1);
    *(__hip_bfloat162*)(dst + c0) = pr;
  }
  any = __any(any) ? 1 : 0;
  if ((t & 63) == 0) sred[t >> 6] = any;
  __syncthreads();
  if (t == 0) nz[m] = sred[0] | sred[1] | sred[2] | sred[3];
}

// Compaction + padding mask + decoder-KV bias concat (single block)
__global__ __launch_bounds__(256)
void compact_kernel(const int* __restrict__ nz, int* __restrict__ idx,
                    int* __restrict__ pos, int* __restrict__ cnt,
                    int* __restrict__ pad,
                    const float* __restrict__ dkvb, float* __restrict__ kvbias)
{
  __shared__ int wsum[4];
  __shared__ int total;
  const int t = threadIdx.x;
  int loc[13];
  int c = 0;
#pragma unroll
  for (int i = 0; i < 13; ++i) {
    const int m = t * 13 + i;
    loc[i] = (m < ROWS) ? nz[m] : 0;
    c += loc[i];
  }
  int v = c;
#pragma unroll
  for (int o = 1; o < 64; o <<= 1) {
    const int u = __shfl_up(v, o);
    if ((t & 63) >= o) v += u;
  }
  if ((t & 63) == 63) wsum[t >> 6] = v;
  __syncthreads();
  int wbase = 0;
  for (int w = 0; w < (t >> 6); ++w) wbase += wsum[w];
  int p = wbase + v - c;
#pragma unroll
  for (int i = 0; i < 13; ++i) {
    const int m = t * 13 + i;
    if (m < ROWS) {
      if (loc[i]) { idx[p] = m; pos[m] = p; ++p; }
      else pos[m] = -1;
    }
  }
  if (t == 255) total = p;
  __syncthreads();
  const int count = total;
  if (t == 0) cnt[0] = count + 1;
  for (int i = count + t; i < MPAD; i += 256) idx[i] = ROWS;
  for (int m = t; m < ROWS; m += 256) if (pos[m] < 0) pos[m] = count;
  if (t < 32) {
    int any = 0;
    for (int s = 99; s >= 0; --s) {
      any |= nz[t * 100 + s];
      pad[t * 100 + s] = (s > 0 && !any) ? 1 : 0;
    }
  }
  // kvbias[L*1024 + j] = dec_ca_qkv_b[L*1536 + 512 + j]
#pragma unroll
  for (int i = t; i < 2048; i += 256) {
    const int L = i >> 10, j = i & 1023;
    kvbias[i] = dkvb[L * 1536 + 512 + j];
  }
}

// fp32 -> bf16 pairwise with row AND column zero-pad
__global__ __launch_bounds__(256)
void cvt_pad_kernel(const float* __restrict__ in, __hip_bfloat16* __restrict__ out,
                    int rin, int cin, int cout)
{
  const int c = (blockIdx.x * 256 + threadIdx.x) * 2;
  const int r = blockIdx.y;
  if (c >= cout) return;
  const int rv = (r < rin);
  const float v0 = (rv && c < cin) ? in[(size_t)r * cin + c] : 0.f;
  const float v1 = (rv && c + 1 < cin) ? in[(size_t)r * cin + c + 1] : 0.f;
  __hip_bfloat162 pr;
  pr.x = __float2bfloat16(v0);
  pr.y = __float2bfloat16(v1);
  *(__hip_bfloat162*)(out + (size_t)r * cout + c) = pr;
}

// Multi-segment flat fp32->bf16 (counts multiples of 2048)
struct CvtArgs {
  const float* src[9];
  __hip_bfloat16* dst[9];
  int cum[9];
};
__global__ __launch_bounds__(256)
void cvt_multi_kernel(CvtArgs a)
{
  const int bid = blockIdx.x;
  int seg = 0;
#pragma unroll
  for (int i = 1; i < 9; ++i) if (bid >= a.cum[i]) seg = i;
  const size_t e0 = ((size_t)(bid - a.cum[seg]) << 11) + (threadIdx.x << 3);
  const float4 v0 = *(const float4*)(a.src[seg] + e0);
  const float4 v1 = *(const float4*)(a.src[seg] + e0 + 4);
  union { short4v v; __hip_bfloat16 h[4]; } u0, u1;
  u0.h[0] = __float2bfloat16(v0.x); u0.h[1] = __float2bfloat16(v0.y);
  u0.h[2] = __float2bfloat16(v0.z); u0.h[3] = __float2bfloat16(v0.w);
  u1.h[0] = __float2bfloat16(v1.x); u1.h[1] = __float2bfloat16(v1.y);
  u1.h[2] = __float2bfloat16(v1.z); u1.h[3] = __float2bfloat16(v1.w);
  *(short4v*)(a.dst[seg] + e0) = u0.v;
  *(short4v*)(a.dst[seg] + e0 + 4) = u1.v;
}

// Multi-segment tiled fp32 transpose: dst[C][R] = src[R][C]^T ; 64x64 tiles.
struct TrArgs {
  const float* src[13];
  float* dst[13];
  int R[13], C[13], cum[13];
};
__global__ __launch_bounds__(256)
void transpose_kernel(TrArgs a)
{
  __shared__ float tbuf[64][65];
  const int bid = blockIdx.x;
  int seg = 0;
#pragma unroll
  for (int i = 1; i < 13; ++i) if (bid >= a.cum[i]) seg = i;
  const int local = bid - a.cum[seg];
  const int R = a.R[seg], C = a.C[seg];
  const int tilesC = C >> 6;
  const int r0 = (local / tilesC) << 6;
  const int c0 = (local % tilesC) << 6;
  const int tx = threadIdx.x & 63, ty = threadIdx.x >> 6;
  const float* s = a.src[seg];
  float* d = a.dst[seg];
#pragma unroll
  for (int i = 0; i < 16; ++i) {
    const int rr = (ty << 4) + i;
    tbuf[rr][tx] = s[(size_t)(r0 + rr) * C + c0 + tx];
  }
  __syncthreads();
#pragma unroll
  for (int i = 0; i < 16; ++i) {
    const int cc = (ty << 4) + i;
    d[(size_t)(c0 + cc) * R + r0 + tx] = tbuf[tx][cc];
  }
}

// fc3 reduce + bias + relu + scatter + inline PE
__global__ __launch_bounds__(256)
void scatter_pe_reduce(const float* __restrict__ P, size_t pstride, int ksl,
                       const int* __restrict__ pos, const float* __restrict__ bias,
                       float* __restrict__ hf, __hip_bfloat16* __restrict__ hb)
{
  const int m = blockIdx.x;
  const int s = m % 100, b = m / 100;
  const int src = pos[m];
  const int t = threadIdx.x;
  const size_t sb = (size_t)src * 512;
  const size_t db = (size_t)(s * 32 + b) * 512;
#pragma unroll
  for (int u = 0; u < 2; ++u) {
    const int d = t + u * 256;
    float v = bias[d];
    for (int k = 0; k < ksl; ++k) v += P[(size_t)k * pstride + sb + d];
    const float div = expf((float)(2 * (d >> 1)) * (-9.210340371976184f / 512.f));
    const float arg = (float)s * div;
    const float pe = (d & 1) ? cosf(arg) : sinf(arg);
    v = fmaxf(v, 0.f) + pe;
    hf[db + d] = v;
    hb[db + d] = __float2bfloat16(v);
  }
}

// ---------------------------------------------------------------------------
// LayerNorm over D=512 (+ optional second, final LN fused)
__global__ __launch_bounds__(256)
void ln_kernel(const float* __restrict__ x, const float* __restrict__ res,
               const float* __restrict__ g, const float* __restrict__ bta,
               const float* __restrict__ gf, const float* __restrict__ bf_,
               int dofinal, float* __restrict__ y, __hip_bfloat16* __restrict__ yb)
{
  __shared__ float rs[4], rss[4];
  const int row = blockIdx.x;
  const int t = threadIdx.x;
  const size_t base = (size_t)row * 512;
  float v0 = x[base + t];
  float v1 = x[base + t + 256];
  if (res) { v0 += res[base + t]; v1 += res[base + t + 256]; }
  float o0, o1;
#pragma unroll
  for (int pass = 0; pass < 2; ++pass) {
    float s = v0 + v1, ss = v0 * v0 + v1 * v1;
#pragma unroll
    for (int o = 32; o > 0; o >>= 1) { s += __shfl_xor(s, o); ss += __shfl_xor(ss, o); }
    if ((t & 63) == 0) { rs[t >> 6] = s; rss[t >> 6] = ss; }
    __syncthreads();
    s = rs[0] + rs[1] + rs[2] + rs[3];
    ss = rss[0] + rss[1] + rss[2] + rss[3];
    __syncthreads();
    const float mean = s * (1.f / 512.f);
    const float var = ss * (1.f / 512.f) - mean * mean;
    const float inv = rsqrtf(var + 1e-5f);
    const float* gg = (pass == 0) ? g : gf;
    const float* bb = (pass == 0) ? bta : bf_;
    o0 = (v0 - mean) * inv * gg[t] + bb[t];
    o1 = (v1 - mean) * inv * gg[t + 256] + bb[t + 256];
    if (pass == 1 || !dofinal) break;
    v0 = o0; v1 = o1;
  }
  if (y) {
    y[base + t] = o0;
    y[base + t + 256] = o1;
  }
  if (yb) {
    yb[base + t] = __float2bfloat16(o0);
    yb[base + t + 256] = __float2bfloat16(o1);
  }
}

// ---------------------------------------------------------------------------
// Encoder self-attention (unchanged)
__global__ __launch_bounds__(256)
void enc_attn_kernel(const float* __restrict__ qkv, const int* __restrict__ pad,
                     __hip_bfloat16* __restrict__ ob)
{
  __shared__ float Ks[100][129];
  __shared__ float Qs[128];
  __shared__ float Ps[100];
  __shared__ float red[4];
  const int bh = blockIdx.x;
  const int b = bh >> 2, h = bh & 3;
  const int q0 = blockIdx.y * 25;
  const int t = threadIdx.x;
  for (int i = t; i < 12800; i += 256) {
    const int s = i >> 7, d = i & 127;
    Ks[s][d] = qkv[(size_t)(s * 32 + b) * 1536 + 512 + h * 128 + d];
  }
  const int masked = (t < 100) ? pad[b * 100 + t] : 0;
  const float scale = 0.08838834764831845f;
  for (int qi = 0; qi < 25; ++qi) {
    const int q = q0 + qi;
    __syncthreads();
    if (t < 128) Qs[t] = qkv[(size_t)(q * 32 + b) * 1536 + h * 128 + t];
    __syncthreads();
    float sc = -3e38f;
    if (t < 100) {
      const float* kr = &Ks[t][0];
      float a = 0.f;
#pragma unroll 16
      for (int d = 0; d < 128; ++d) a += Qs[d] * kr[d];
      sc = masked ? -1e9f : (a * scale);
    }
    float mx = sc;
#pragma unroll
    for (int o = 32; o > 0; o >>= 1) mx = fmaxf(mx, __shfl_xor(mx, o));
    if ((t & 63) == 0) red[t >> 6] = mx;
    __syncthreads();
    mx = fmaxf(fmaxf(red[0], red[1]), fmaxf(red[2], red[3]));
    const float e = (t < 100) ? expf(sc - mx) : 0.f;
    float sm = e;
#pragma unroll
    for (int o = 32; o > 0; o >>= 1) sm += __shfl_xor(sm, o);
    __syncthreads();
    if ((t & 63) == 0) red[t >> 6] = sm;
    __syncthreads();
    sm = red[0] + red[1] + red[2] + red[3];
    if (t < 100) Ps[t] = e;
    __syncthreads();
    if (t < 128) {
      float a = 0.f;
      const float* vb = qkv + 1024 + h * 128 + t;
      for (int k = 0; k < 100; ++k) a += Ps[k] * vb[(size_t)(k * 32 + b) * 1536];
      ob[(size_t)(q * 32 + b) * 512 + h * 128 + t] = __float2bfloat16(a / sm);
    }
  }
}

// ---------------------------------------------------------------------------
// Fused decoder layer: transposed-weight coalesced GEMVs. 512 thr, grid 32.
template<int N, int K, int RELU>
__device__ __forceinline__ void gemvT(int tid, const float* S,
                                      const float* __restrict__ WT,
                                      const float* __restrict__ bias,
                                      float* out, float* part)
{
  constexpr int NQ = N / 4;
  constexpr int G = 512 / NQ;
  constexpr int KP = K / G;
  const int p = tid % NQ;
  const int g = tid / NQ;
  const float4* wp = (const float4*)WT;
  float ax = 0.f, ay = 0.f, az = 0.f, aw = 0.f;
  const int kend = g * KP + KP;
#pragma unroll 8
  for (int k = g * KP; k < kend; ++k) {
    const float s = S[k];
    const float4 w = wp[(size_t)k * NQ + p];
    ax += s * w.x; ay += s * w.y; az += s * w.z; aw += s * w.w;
  }
  float4 a4 = {ax, ay, az, aw};
  *(float4*)(part + g * N + 4 * p) = a4;
  __syncthreads();
#pragma unroll
  for (int n = tid; n < N; n += 512) {
    float v = bias[n];
#pragma unroll
    for (int q = 0; q < G; ++q) v += part[q * N + n];
    if (RELU) v = fmaxf(v, 0.f);
    out[n] = v;
  }
  __syncthreads();
}

#define BLOCK_LN512(V, G, B, O)                                                 \
  {                                                                             \
    float s_ = (V), ss_ = (V) * (V);                                            \
    _Pragma("unroll")                                                           \
    for (int o_ = 32; o_ > 0; o_ >>= 1) {                                       \
      s_ += __shfl_xor(s_, o_); ss_ += __shfl_xor(ss_, o_);                     \
    }                                                                           \
    if ((tid & 63) == 0) { red[tid >> 6] = s_; red2[tid >> 6] = ss_; }          \
    __syncthreads();                                                            \
    s_ = 0.f; ss_ = 0.f;                                                        \
    _Pragma("unroll")                                                           \
    for (int w_ = 0; w_ < 8; ++w_) { s_ += red[w_]; ss_ += red2[w_]; }          \
    const float mean_ = s_ * (1.f / 512.f);                                     \
    const float inv_ = rsqrtf(ss_ * (1.f / 512.f) - mean_ * mean_ + 1e-5f);     \
    O = ((V) - mean_) * inv_ * (G)[tid] + (B)[tid];                             \
    __syncthreads();                                                            \
  }

__global__ __launch_bounds__(512)
void dec_layer(const float* __restrict__ tin,          // nullptr => ones
               const float* __restrict__ kvb,          // K at +0, V at +512
               int kvstride,
               const float* __restrict__ WvT, const float* __restrict__ bv,
               const float* __restrict__ WpT, const float* __restrict__ bp,
               const float* __restrict__ g1, const float* __restrict__ b1,
               const float* __restrict__ WqT, const float* __restrict__ bq,
               const float* __restrict__ WcpT, const float* __restrict__ bcp,
               const float* __restrict__ g2, const float* __restrict__ b2,
               const float* __restrict__ W1T, const float* __restrict__ b1f,
               const float* __restrict__ W2T, const float* __restrict__ b2f,
               const float* __restrict__ g3, const float* __restrict__ b3,
               const float* __restrict__ gf, const float* __restrict__ bf_,
               int dofinal, float* __restrict__ tout,
               const float* __restrict__ Wo1T, const float* __restrict__ ob1,
               __hip_bfloat16* __restrict__ o1b)
{
  __shared__ float Ts[512], Bs[512], Cs[512], F1[1024], part[2048];
  __shared__ float Ps[4][104];
  __shared__ float red[8], red2[8];
  const int r = blockIdx.x, tid = threadIdx.x;
  Ts[tid] = tin ? tin[r * 512 + tid] : 1.0f;
  __syncthreads();

  // self-attn (Sq=1: softmax over one key == 1 -> out = V(t))
  gemvT<512, 512, 0>(tid, Ts, WvT, bv, Bs, part);
  gemvT<512, 512, 0>(tid, Bs, WpT, bp, Cs, part);
  {
    const float rr = Cs[tid] + Ts[tid];
    float o;
    BLOCK_LN512(rr, g1, b1, o)
    Ts[tid] = o;                          // t1
  }
  __syncthreads();

  // cross-attn Q
  gemvT<512, 512, 0>(tid, Ts, WqT, bq, Bs, part);

  // cross-attention: wave h<4 handles head h; 100 keys, 2 per lane
  if (tid < 256) {
    const int h = tid >> 6, lane = tid & 63;
    const float scale = 0.08838834764831845f;
    const float* Qh = Bs + h * 128;
    float s0, s1 = -3e38f;
    {
      const float* kr = kvb + (size_t)(lane * 32 + r) * kvstride + h * 128;
      float a = 0.f;
#pragma unroll 16
      for (int d = 0; d < 128; ++d) a += Qh[d] * kr[d];
      s0 = a * scale;
    }
    if (lane + 64 < 100) {
      const float* kr = kvb + (size_t)((lane + 64) * 32 + r) * kvstride + h * 128;
      float a = 0.f;
#pragma unroll 16
      for (int d = 0; d < 128; ++d) a += Qh[d] * kr[d];
      s1 = a * scale;
    }
    float mx = fmaxf(s0, s1);
#pragma unroll
    for (int o = 32; o > 0; o >>= 1) mx = fmaxf(mx, __shfl_xor(mx, o));
    const float e0 = expf(s0 - mx);
    const float e1 = (lane + 64 < 100) ? expf(s1 - mx) : 0.f;
    float sm = e0 + e1;
#pragma unroll
    for (int o = 32; o > 0; o >>= 1) sm += __shfl_xor(sm, o);
    Ps[h][lane] = e0 / sm;
    if (lane + 64 < 100) Ps[h][lane + 64] = e1 / sm;
  }
  __syncthreads();
  if (tid < 256) {
    const int h = tid >> 6, lane = tid & 63;
#pragma unroll
    for (int u = 0; u < 2; ++u) {
      const int d = lane + u * 64;
      const float* vb = kvb + 512 + h * 128 + d;
      float a = 0.f;
      for (int k = 0; k < 100; ++k) a += Ps[h][k] * vb[(size_t)(k * 32 + r) * kvstride];
      Bs[h * 128 + d] = a;                // cav
    }
  }
  __syncthreads();

  // ca proj + residual + LN2
  gemvT<512, 512, 0>(tid, Bs, WcpT, bcp, Cs, part);
  {
    const float rr = Cs[tid] + Ts[tid];
    float o;
    BLOCK_LN512(rr, g2, b2, o)
    Ts[tid] = o;                          // t2
  }
  __syncthreads();

  // FF
  gemvT<1024, 512, 1>(tid, Ts, W1T, b1f, F1, part);
  gemvT<512, 1024, 0>(tid, F1, W2T, b2f, Cs, part);
  {
    const float rr = Cs[tid] + Ts[tid];
    float o;
    BLOCK_LN512(rr, g3, b3, o)
    if (dofinal) {
      float f;
      BLOCK_LN512(o, gf, bf_, f)
      o = f;
    }
    tout[r * 512 + tid] = o;
    if (dofinal) {
      Ts[tid] = o;
      __syncthreads();
      // fused out1: row r of C(32,2048) = relu(t @ Wo1T + b); 4 outputs/thread
      const float4* wp = (const float4*)Wo1T;   // [512][512 quads]
      float ax = 0.f, ay = 0.f, az = 0.f, aw = 0.f;
#pragma unroll 8
      for (int k = 0; k < 512; ++k) {
        const float s = Ts[k];
        const float4 w = wp[(size_t)k * 512 + tid];
        ax += s * w.x; ay += s * w.y; az += s * w.z; aw += s * w.w;
      }
      union { short4v v; __hip_bfloat16 h[4]; } u;
      u.h[0] = __float2bfloat16(fmaxf(ax + ob1[4 * tid], 0.f));
      u.h[1] = __float2bfloat16(fmaxf(ay + ob1[4 * tid + 1], 0.f));
      u.h[2] = __float2bfloat16(fmaxf(az + ob1[4 * tid + 2], 0.f));
      u.h[3] = __float2bfloat16(fmaxf(aw + ob1[4 * tid + 3], 0.f));
      *(short4v*)(o1b + (size_t)r * 2048 + 4 * tid) = u.v;
      const short4v z = {0, 0, 0, 0};
#pragma unroll
      for (int rr = r + 32; rr < 128; rr += 32)
        *(short4v*)(o1b + (size_t)rr * 2048 + 4 * tid) = z;
    }
  }
}

// ---------------------------------------------------------------------------
// out3 split-K reduce (+bias(+guard)+relu) fused with adaptive pool. grid 32.
__global__ __launch_bounds__(256)
void reduce_pool(const float* __restrict__ P, size_t pstride,
                 const float* __restrict__ bias, float* __restrict__ out)
{
  __shared__ float row[NOUT3];
  const int b = blockIdx.x, t = threadIdx.x;
  for (int n = t * 4; n < NOUT3; n += 1024) {
    const size_t o = (size_t)b * NOUT3 + n;
    float4 s = *(const float4*)(P + o);
#pragma unroll
    for (int k = 1; k < 4; ++k) {
      const float4 p = *(const float4*)(P + (size_t)k * pstride + o);
      s.x += p.x; s.y += p.y; s.z += p.z; s.w += p.w;
    }
    row[n]     = fmaxf(s.x + ((n     < FLATIN) ? bias[n]     : 0.f), 0.f);
    row[n + 1] = fmaxf(s.y + ((n + 1 < FLATIN) ? bias[n + 1] : 0.f), 0.f);
    row[n + 2] = fmaxf(s.z + ((n + 2 < FLATIN) ? bias[n + 2] : 0.f), 0.f);
    row[n + 3] = fmaxf(s.w + ((n + 3 < FLATIN) ? bias[n + 3] : 0.f), 0.f);
  }
  __syncthreads();
  for (int i = t; i < 135 * 103; i += 256) {
    const int j = i % 103, r = i / 103;
    const int rs = (r * 143) / 135, re = ((r + 1) * 143 + 134) / 135;
    const int cs = (j * 111) / 103, ce = ((j + 1) * 111 + 102) / 103;
    float s = 0.f;
    for (int rr = rs; rr < re; ++rr)
      for (int cc = cs; cc < ce; ++cc)
        s += row[rr * 111 + cc];
    out[(size_t)b * (135 * 103) + i] = s / (float)((re - rs) * (ce - cs));
  }
}

// ---------------------------------------------------------------------------
extern "C" void kernel_launch(void* const* d_in, const int* in_sizes, int n_in,
                              void* d_out, int out_size, void* d_ws, size_t ws_size,
                              hipStream_t stream)
{
  (void)in_sizes; (void)n_in; (void)out_size; (void)ws_size;

  const float* x          = (const float*)d_in[0];
  const float* fc1_w      = (const float*)d_in[1];
  const float* fc1_b      = (const float*)d_in[2];
  const float* fc2_w      = (const float*)d_in[3];
  const float* fc2_b      = (const float*)d_in[4];
  const float* fc3_w      = (const float*)d_in[5];
  const float* fc3_b      = (const float*)d_in[6];
  const float* out1_w     = (const float*)d_in[7];
  const float* out1_b     = (const float*)d_in[8];
  const float* out2_w     = (const float*)d_in[9];
  const float* out2_b     = (const float*)d_in[10];
  const float* out3_w     = (const float*)d_in[11];
  const float* out3_b     = (const float*)d_in[12];
  const float* enc_qkv_w  = (const float*)d_in[13];
  const float* enc_qkv_b  = (const float*)d_in[14];
  const float* enc_proj_w = (const float*)d_in[15];
  const float* enc_proj_b = (const float*)d_in[16];
  const float* enc_ff1_w  = (const float*)d_in[17];
  const float* enc_ff1_b  = (const float*)d_in[18];
  const float* enc_ff2_w  = (const float*)d_in[19];
  const float* enc_ff2_b  = (const float*)d_in[20];
  const float* enc_ln1_g  = (const float*)d_in[21];
  const float* enc_ln1_b  = (const float*)d_in[22];
  const float* enc_ln2_g  = (const float*)d_in[23];
  const float* enc_ln2_b  = (const float*)d_in[24];
  const float* enc_lnf_g  = (const float*)d_in[25];
  const float* enc_lnf_b  = (const float*)d_in[26];
  const float* dec_sa_qkv_w  = (const float*)d_in[27];
  const float* dec_sa_qkv_b  = (const float*)d_in[28];
  const float* dec_sa_proj_w = (const float*)d_in[29];
  const float* dec_sa_proj_b = (const float*)d_in[30];
  const float* dec_ca_qkv_w  = (const float*)d_in[31];
  const float* dec_ca_qkv_b  = (const float*)d_in[32];
  const float* dec_ca_proj_w = (const float*)d_in[33];
  const float* dec_ca_proj_b = (const float*)d_in[34];
  const float* dec_ff1_w  = (const float*)d_in[35];
  const float* dec_ff1_b  = (const float*)d_in[36];
  const float* dec_ff2_w  = (const float*)d_in[37];
  const float* dec_ff2_b  = (const float*)d_in[38];
  const float* dec_ln1_g  = (const float*)d_in[39];
  const float* dec_ln1_b  = (const float*)d_in[40];
  const float* dec_ln2_g  = (const float*)d_in[41];
  const float* dec_ln2_b  = (const float*)d_in[42];
  const float* dec_ln3_g  = (const float*)d_in[43];
  const float* dec_ln3_b  = (const float*)d_in[44];
  const float* dec_lnf_g  = (const float*)d_in[45];
  const float* dec_lnf_b  = (const float*)d_in[46];

  char* wsp = (char*)d_ws;
  size_t off = 0;
  auto alloc = [&](size_t nbytes) -> char* {
    char* p = wsp + off;
    off += (nbytes + 255) & ~(size_t)255;
    return p;
  };

  __hip_bfloat16* xb     = (__hip_bfloat16*)alloc((size_t)MPAD * KPAD1 * 2);
  __hip_bfloat16* Wb1    = (__hip_bfloat16*)alloc((size_t)4096 * KPAD1 * 2);
  __hip_bfloat16* Wb2    = (__hip_bfloat16*)alloc((size_t)2048 * 4096 * 2);
  __hip_bfloat16* Wb3    = (__hip_bfloat16*)alloc((size_t)512 * 2048 * 2);
  __hip_bfloat16* Wqkvb  = (__hip_bfloat16*)alloc((size_t)2 * 1536 * 512 * 2);
  __hip_bfloat16* Wprojb = (__hip_bfloat16*)alloc((size_t)2 * 512 * 512 * 2);
  __hip_bfloat16* Wff1b  = (__hip_bfloat16*)alloc((size_t)2 * 1024 * 512 * 2);
  __hip_bfloat16* Wff2b  = (__hip_bfloat16*)alloc((size_t)2 * 512 * 1024 * 2);
  __hip_bfloat16* Wkv2b  = (__hip_bfloat16*)alloc((size_t)2048 * 512 * 2);
  int*   nz      = (int*)alloc(ROWS * 4);
  int*   padmask = (int*)alloc(ROWS * 4);
  int*   idx     = (int*)alloc(MPAD * 4);
  int*   pos     = (int*)alloc(ROWS * 4);
  int*   cnt     = (int*)alloc(256);
  float* kvbias  = (float*)alloc(2048 * 4);
  __hip_bfloat16* h1c = (__hip_bfloat16*)alloc((size_t)MPAD * 4096 * 2);
  __hip_bfloat16* h2c = (__hip_bfloat16*)alloc((size_t)MPAD * 2048 * 2);
  float* hf  = (float*)alloc((size_t)ROWS * 512 * 4);
  __hip_bfloat16* hb = (__hip_bfloat16*)alloc((size_t)ROWS * 512 * 2);
  float* qkvbuf = (float*)alloc((size_t)ROWS * 1536 * 4);
  __hip_bfloat16* attnb = (__hip_bfloat16*)alloc((size_t)ROWS * 512 * 2);
  float* pjf  = (float*)alloc((size_t)ROWS * 512 * 4);
  __hip_bfloat16* f1b = (__hip_bfloat16*)alloc((size_t)ROWS * 1024 * 2);
  float* f2f  = (float*)alloc((size_t)ROWS * 512 * 4);
  __hip_bfloat16* memb = (__hip_bfloat16*)alloc((size_t)ROWS * 512 * 2);
  float* kv01 = (float*)alloc((size_t)ROWS * 2048 * 4);
  float* tbuf = (float*)alloc(32 * 512 * 4);
  // transposed fp32 weights (decoder + out1)
  float* WvT[2]  = { (float*)alloc(512 * 512 * 4), (float*)alloc(512 * 512 * 4) };
  float* WpT[2]  = { (float*)alloc(512 * 512 * 4), (float*)alloc(512 * 512 * 4) };
  float* WqT[2]  = { (float*)alloc(512 * 512 * 4), (float*)alloc(512 * 512 * 4) };
  float* WcpT[2] = { (float*)alloc(512 * 512 * 4), (float*)alloc(512 * 512 * 4) };
  float* W1T[2]  = { (float*)alloc(512 * 1024 * 4), (float*)alloc(512 * 1024 * 4) };
  float* W2T[2]  = { (float*)alloc(1024 * 512 * 4), (float*)alloc(1024 * 512 * 4) };
  float* Wo1T    = (float*)alloc((size_t)512 * 2048 * 4);
  // split-K partial buffers (time-shared)
  float* fcP  = (float*)alloc((size_t)4 * MPAD * 4096 * 4);   // 218 MB
  float* encP = (float*)alloc((size_t)2 * ROWS * 1536 * 4);   // aliases

  // phase-4 aliases (fcP/encP free after decoder)
  float* outP = fcP;
  __hip_bfloat16* Wo3b = (__hip_bfloat16*)((char*)fcP + ((size_t)48 << 20)); // 131 MB
  __hip_bfloat16* Wo2b = (__hip_bfloat16*)encP;                              // 16.8 MB
  __hip_bfloat16* o1b  = (__hip_bfloat16*)((char*)encP + ((size_t)20 << 20));
  __hip_bfloat16* o2b  = (__hip_bfloat16*)((char*)encP + ((size_t)22 << 20));

  const size_t psF1 = (size_t)MPAD * 4096;
  const size_t psF2 = (size_t)MPAD * 2048;
  const size_t psF3 = (size_t)MPAD * 512;

  // ---- phase 0 ----
  conv_x_kernel<<<ROWS + 1, 256, 0, stream>>>(x, xb, nz);
  compact_kernel<<<1, 256, 0, stream>>>(nz, idx, pos, cnt, padmask,
                                        dec_ca_qkv_b, kvbias);
  {
    CvtArgs a;
    const float* srcs[9] = { enc_qkv_w, enc_proj_w, enc_ff1_w, enc_ff2_w,
                             dec_ca_qkv_w + (size_t)512 * 512,
                             dec_ca_qkv_w + (size_t)(1536 + 512) * 512,
                             fc2_w, fc3_w, out2_w };
    __hip_bfloat16* dsts[9] = { Wqkvb, Wprojb, Wff1b, Wff2b,
                                Wkv2b, Wkv2b + (size_t)1024 * 512,
                                Wb2, Wb3, Wo2b };
    const int counts[9] = { 2*1536*512, 2*512*512, 2*1024*512, 2*512*1024,
                            1024*512, 1024*512, 2048*4096, 512*2048, 4096*2048 };
    int c = 0;
    for (int i = 0; i < 9; ++i) { a.src[i] = srcs[i]; a.dst[i] = dsts[i];
                                  a.cum[i] = c; c += counts[i] >> 11; }
    cvt_multi_kernel<<<c, 256, 0, stream>>>(a);
  }
  cvt_pad_kernel<<<dim3(KPAD1 / 512, 4096), 256, 0, stream>>>(fc1_w, Wb1, 4096, FLATIN, KPAD1);
  {
    TrArgs a;
    const float* srcs[13];
    float* dsts[13];
    int R[13], C[13];
    int n = 0;
    for (int L = 0; L < 2; ++L) {
      srcs[n] = dec_sa_qkv_w + (size_t)L * 1536 * 512 + (size_t)1024 * 512;
      dsts[n] = WvT[L]; R[n] = 512; C[n] = 512; ++n;
      srcs[n] = dec_sa_proj_w + (size_t)L * 512 * 512;
      dsts[n] = WpT[L]; R[n] = 512; C[n] = 512; ++n;
      srcs[n] = dec_ca_qkv_w + (size_t)L * 1536 * 512;
      dsts[n] = WqT[L]; R[n] = 512; C[n] = 512; ++n;
      srcs[n] = dec_ca_proj_w + (size_t)L * 512 * 512;
      dsts[n] = WcpT[L]; R[n] = 512; C[n] = 512; ++n;
      srcs[n] = dec_ff1_w + (size_t)L * 1024 * 512;
      dsts[n] = W1T[L]; R[n] = 1024; C[n] = 512; ++n;
      srcs[n] = dec_ff2_w + (size_t)L * 512 * 1024;
      dsts[n] = W2T[L]; R[n] = 512; C[n] = 1024; ++n;
    }
    srcs[n] = out1_w; dsts[n] = Wo1T; R[n] = 2048; C[n] = 512; ++n;
    int c = 0;
    for (int i = 0; i < 13; ++i) {
      a.src[i] = srcs[i]; a.dst[i] = dsts[i]; a.R[i] = R[i]; a.C[i] = C[i];
      a.cum[i] = c; c += (R[i] >> 6) * (C[i] >> 6);
    }
    transpose_kernel<<<c, 256, 0, stream>>>(a);
  }

  // ---- phase 1: input MLP (split-K) ----
  gemm_bf16<1><<<26 * 32 * 2, 256, 0, stream>>>(xb, Wb1, idx, cnt, fcP,
      KPAD1, 4096, 26, 2, psF1);
  reduce_kernel<1, 0, 1><<<dim3(4, MPAD), 256, 0, stream>>>(fcP, psF1, 2,
      fc1_b, nullptr, h1c, 4096, cnt);
  gemm_bf16<0><<<26 * 16 * 4, 256, 0, stream>>>(h1c, Wb2, nullptr, cnt, fcP,
      4096, 2048, 26, 4, psF2);
  reduce_kernel<1, 0, 1><<<dim3(2, MPAD), 256, 0, stream>>>(fcP, psF2, 4,
      fc2_b, nullptr, h2c, 2048, cnt);
  gemm_bf16<0><<<26 * 4 * 4, 256, 0, stream>>>(h2c, Wb3, nullptr, cnt, fcP,
      2048, 512, 26, 4, psF3);
  scatter_pe_reduce<<<ROWS, 256, 0, stream>>>(fcP, psF3, 4, pos, fc3_b, hf, hb);

  // ---- phase 2: encoder ----
  for (int L = 0; L < 2; ++L) {
    gemm_direct<0, 1, 0><<<25 * 12, 256, 0, stream>>>(hb, Wqkvb + (size_t)L * 1536 * 512,
        enc_qkv_b + L * 1536, qkvbuf, nullptr, 512, 1536, 25);
    enc_attn_kernel<<<dim3(128, 4), 256, 0, stream>>>(qkvbuf, padmask, attnb);
    gemm_direct<0, 1, 0><<<25 * 4, 256, 0, stream>>>(attnb, Wprojb + (size_t)L * 512 * 512,
        enc_proj_b + L * 512, pjf, nullptr, 512, 512, 25);
    ln_kernel<<<ROWS, 256, 0, stream>>>(hf, pjf, enc_ln1_g + L * 512, enc_ln1_b + L * 512,
        nullptr, nullptr, 0, hf, hb);
    gemm_direct<1, 0, 1><<<25 * 8, 256, 0, stream>>>(hb, Wff1b + (size_t)L * 1024 * 512,
        enc_ff1_b + L * 1024, nullptr, f1b, 512, 1024, 25);
    gemm_direct<0, 1, 0><<<25 * 4, 256, 0, stream>>>(f1b, Wff2b + (size_t)L * 512 * 1024,
        enc_ff2_b + L * 512, f2f, nullptr, 1024, 512, 25);
    if (L == 0) {
      ln_kernel<<<ROWS, 256, 0, stream>>>(hf, f2f, enc_ln2_g, enc_ln2_b,
          nullptr, nullptr, 0, hf, hb);
    } else {
      ln_kernel<<<ROWS, 256, 0, stream>>>(hf, f2f, enc_ln2_g + 512, enc_ln2_b + 512,
          enc_lnf_g, enc_lnf_b, 1, nullptr, memb);
    }
  }

  // ---- decoder KV (both layers, one GEMM) ----
  gemm_direct<0, 1, 0><<<25 * 16, 256, 0, stream>>>(memb, Wkv2b, kvbias,
      kv01, nullptr, 512, 2048, 25);

  // ---- phase 3: fused decoder layers (+ out1 fused into L1) ----
  for (int L = 0; L < 2; ++L) {
    dec_layer<<<32, 512, 0, stream>>>(
        (L == 0) ? nullptr : tbuf,
        kv01 + (size_t)L * 1024, 2048,
        WvT[L], dec_sa_qkv_b + L * 1536 + 1024,
        WpT[L], dec_sa_proj_b + L * 512,
        dec_ln1_g + L * 512, dec_ln1_b + L * 512,
        WqT[L], dec_ca_qkv_b + L * 1536,
        WcpT[L], dec_ca_proj_b + L * 512,
        dec_ln2_g + L * 512, dec_ln2_b + L * 512,
        W1T[L], dec_ff1_b + L * 1024,
        W2T[L], dec_ff2_b + L * 512,
        dec_ln3_g + L * 512, dec_ln3_b + L * 512,
        dec_lnf_g, dec_lnf_b, (L == 1) ? 1 : 0, tbuf,
        Wo1T, out1_b, o1b);
  }

  // ---- phase 4: output MLP ----
  cvt_pad_kernel<<<dim3(8, NOUT3), 256, 0, stream>>>(out3_w, Wo3b, FLATIN, 4096, 4096);

  gemm_bf16<0><<<32 * 4, 256, 0, stream>>>(o1b, Wo2b, nullptr, nullptr, outP,
      2048, 4096, 1, 4, (size_t)128 * 4096);
  reduce_kernel<1, 0, 1><<<dim3(4, 128), 256, 0, stream>>>(outP, (size_t)128 * 4096, 4,
      out2_b, nullptr, o2b, 4096, nullptr);
  gemm_bf16<0><<<125 * 4, 256, 0, stream>>>(o2b, Wo3b, nullptr, nullptr, outP,
      4096, NOUT3, 1, 4, (size_t)128 * NOUT3);
  reduce_pool<<<32, 256, 0, stream>>>(outP, (size_t)128 * NOUT3, out3_b, (float*)d_out);

  (void)qkvbuf; (void)pjf; (void)f2f;
}

// Round 12
// 1428.615 us; speedup vs baseline: 1.2359x; 1.0488x over previous
//
#include <hip/hip_runtime.h>
#include <hip/hip_bf16.h>

// ---------------------------------------------------------------------------
#define SEQ   100
#define BATCH 32
#define FLATIN 15873
#define KPAD1  16384
#define ROWS   3200
#define MPAD   3328
#define NOUT3  16000

typedef __attribute__((ext_vector_type(8))) short short8;
typedef __attribute__((ext_vector_type(4))) short short4v;
typedef __attribute__((ext_vector_type(4))) float f32x4;

__device__ __forceinline__ void gload_lds16(const void* g, void* l) {
  __builtin_amdgcn_global_load_lds((const __attribute__((address_space(1))) void*)g,
                                   (__attribute__((address_space(3))) void*)l, 16, 0, 0);
}

// bijective XCD chunk swizzle (m204)
__device__ __forceinline__ int xcd_swizzle(int id, int nwg) {
  const int q = nwg >> 3, r = nwg & 7;
  const int x = id & 7, p = id >> 3;
  return (x < r ? x * (q + 1) : r * (q + 1) + (x - r) * q) + p;
}

// ---------------------------------------------------------------------------
// Shared GEMM body: stage 128x64 A/B tiles (both-sides chunk swizzle), MFMA.
#define GEMM_BODY(KBEG, KEND)                                                   \
  const int tid  = threadIdx.x;                                                 \
  const int lane = tid & 63;                                                    \
  const int wid  = tid >> 6;                                                    \
  const int wr = (wid >> 1) << 6;                                               \
  const int wc = (wid & 1) << 6;                                                \
  f32x4 acc[4][4];                                                              \
  _Pragma("unroll") for (int i = 0; i < 4; ++i)                                 \
  _Pragma("unroll") for (int j = 0; j < 4; ++j)                                 \
      acc[i][j] = (f32x4){0.f, 0.f, 0.f, 0.f};                                  \
  const int srow = (wid << 3) + (lane >> 3);                                    \
  const int scs  = lane & 7;                                                    \
  const int gcol = ((scs ^ (srow & 7)) << 3);                                   \
  const __hip_bfloat16* arow[4];                                                \
  const __hip_bfloat16* brow[4];                                                \
  _Pragma("unroll") for (int j = 0; j < 4; ++j) {                               \
    const int row = (j << 5) + srow;                                            \
    const int gr = GATHER ? idx[m0 + row] : (m0 + row);                         \
    arow[j] = A + (size_t)gr * K + gcol;                                        \
    brow[j] = W + (size_t)(n0 + row) * K + gcol;                                \
  }                                                                             \
  for (int k0 = (KBEG); k0 < (KEND); k0 += 64) {                                \
    __syncthreads();                                                            \
    _Pragma("unroll") for (int j = 0; j < 4; ++j) {                             \
      short* la = As + (((j << 2) + wid) << 9);                                 \
      short* lb = Bs + (((j << 2) + wid) << 9);                                 \
      gload_lds16(arow[j] + k0, la);                                            \
      gload_lds16(brow[j] + k0, lb);                                            \
    }                                                                           \
    __syncthreads();                                                            \
    _Pragma("unroll") for (int kk = 0; kk < 2; ++kk) {                          \
      short8 af[4], bfv[4];                                                     \
      _Pragma("unroll") for (int i = 0; i < 4; ++i) {                           \
        const int mr = wr + (i << 4) + (lane & 15);                             \
        const int cg = (kk << 2) + (lane >> 4);                                 \
        af[i]  = *(const short8*)(As + mr * 64 + ((cg ^ (mr & 7)) << 3));       \
        const int nr = wc + (i << 4) + (lane & 15);                             \
        bfv[i] = *(const short8*)(Bs + nr * 64 + ((cg ^ (nr & 7)) << 3));       \
      }                                                                         \
      _Pragma("unroll") for (int i = 0; i < 4; ++i)                             \
      _Pragma("unroll") for (int j = 0; j < 4; ++j)                             \
          acc[i][j] = __builtin_amdgcn_mfma_f32_16x16x32_bf16(af[i], bfv[j],    \
                                                              acc[i][j], 0,0,0);\
    }                                                                           \
  }

// Split-K partial-output GEMM. mt-minor linearization.
template<int GATHER>
__global__ __launch_bounds__(256)
void gemm_bf16(const __hip_bfloat16* __restrict__ A, const __hip_bfloat16* __restrict__ W,
               const int* __restrict__ idx, const int* __restrict__ cnt,
               float* __restrict__ P,
               int K, int ldc, int mtiles, int ksl, size_t pstride)
{
  __shared__ __align__(16) short lds[16384];
  short* As = lds;
  short* Bs = lds + 8192;
  const int wg = xcd_swizzle(blockIdx.x, gridDim.x);
  const int mt = wg % mtiles;
  const int g  = wg / mtiles;
  const int nt = g / ksl;
  const int ks = g % ksl;
  const int m0 = mt << 7;
  const int n0 = nt << 7;
  if (cnt && m0 >= cnt[0]) return;
  const int Klen = K / ksl;
  const int kbeg = ks * Klen;

  GEMM_BODY(kbeg, kbeg + Klen)

  float* Pout = P + (size_t)ks * pstride;
  const int fr = lane & 15, fq = lane >> 4;
#pragma unroll
  for (int j = 0; j < 4; ++j) {
    const int n = n0 + wc + (j << 4) + fr;
#pragma unroll
    for (int i = 0; i < 4; ++i)
#pragma unroll
      for (int r = 0; r < 4; ++r) {
        const int m = m0 + wr + (i << 4) + (fq << 2) + r;
        Pout[(size_t)m * ldc + n] = acc[i][j][r];
      }
  }
}

// Direct GEMM with fused bias/relu epilogue
template<int RELU, int OF32, int OB16>
__global__ __launch_bounds__(256)
void gemm_direct(const __hip_bfloat16* __restrict__ A, const __hip_bfloat16* __restrict__ W,
                 const float* __restrict__ bias, float* __restrict__ Cf,
                 __hip_bfloat16* __restrict__ Cb, int K, int ldc, int mtiles)
{
  __shared__ __align__(16) short lds[16384];
  short* As = lds;
  short* Bs = lds + 8192;
  const int GATHER = 0;
  const int* idx = nullptr;
  const int wg = xcd_swizzle(blockIdx.x, gridDim.x);
  const int m0 = (wg % mtiles) << 7;
  const int n0 = (wg / mtiles) << 7;

  GEMM_BODY(0, K)

  const int fr = lane & 15, fq = lane >> 4;
#pragma unroll
  for (int j = 0; j < 4; ++j) {
    const int n = n0 + wc + (j << 4) + fr;
    const float bb = bias[n];
#pragma unroll
    for (int i = 0; i < 4; ++i)
#pragma unroll
      for (int r = 0; r < 4; ++r) {
        const int m = m0 + wr + (i << 4) + (fq << 2) + r;
        float v = acc[i][j][r] + bb;
        if (RELU) v = fmaxf(v, 0.f);
        if (OF32) Cf[(size_t)m * ldc + n] = v;
        if (OB16) Cb[(size_t)m * ldc + n] = __float2bfloat16(v);
      }
  }
}

// ---------------------------------------------------------------------------
// Split-K reduce: C = sum_ks P[ks] + bias [, relu]
template<int RELU, int OF32, int OB16>
__global__ __launch_bounds__(256)
void reduce_kernel(const float* __restrict__ P, size_t pstride, int ksl,
                   const float* __restrict__ bias, float* __restrict__ Cf,
                   __hip_bfloat16* __restrict__ Cb, int N,
                   const int* __restrict__ cnt)
{
  const int row = blockIdx.y;
  if (cnt) { const int cp = (cnt[0] + 127) & ~127; if (row >= cp) return; }
  const int n = (blockIdx.x * 256 + threadIdx.x) * 4;
  if (n >= N) return;
  const size_t o = (size_t)row * N + n;
  const float4 b4 = *(const float4*)(bias + n);
  float4 s = *(const float4*)(P + o);
  for (int k = 1; k < ksl; ++k) {
    const float4 p = *(const float4*)(P + (size_t)k * pstride + o);
    s.x += p.x; s.y += p.y; s.z += p.z; s.w += p.w;
  }
  s.x += b4.x; s.y += b4.y; s.z += b4.z; s.w += b4.w;
  if (RELU) {
    s.x = fmaxf(s.x, 0.f); s.y = fmaxf(s.y, 0.f);
    s.z = fmaxf(s.z, 0.f); s.w = fmaxf(s.w, 0.f);
  }
  if (OF32) *(float4*)(Cf + o) = s;
  if (OB16) {
    union { short4v v; __hip_bfloat16 h[4]; } u;
    u.h[0] = __float2bfloat16(s.x);
    u.h[1] = __float2bfloat16(s.y);
    u.h[2] = __float2bfloat16(s.z);
    u.h[3] = __float2bfloat16(s.w);
    *(short4v*)(Cb + o) = u.v;
  }
}

// ---------------------------------------------------------------------------
// x -> xb bf16 single pass (convert + any-check together; always write)
__global__ __launch_bounds__(256)
void conv_x_kernel(const float* __restrict__ x, __hip_bfloat16* __restrict__ xb,
                   int* __restrict__ nz)
{
  __shared__ int sred[4];
  const int m = blockIdx.x;               // 0..ROWS
  const int t = threadIdx.x;
  __hip_bfloat16* dst = xb + (size_t)m * KPAD1;
  if (m == ROWS) {
    const __hip_bfloat162 z2 = {__float2bfloat16(0.f), __float2bfloat16(0.f)};
    for (int c = t; c < (KPAD1 >> 1); c += 256) *(__hip_bfloat162*)(dst + 2 * c) = z2;
    return;
  }
  const float* src = x + (size_t)m * FLATIN;
  int any = 0;
  for (int c = t; c < (KPAD1 >> 1); c += 256) {
    const int c0 = 2 * c;
    const float v0 = (c0 < FLATIN) ? src[c0] : 0.f;
    const float v1 = (c0 + 1 < FLATIN) ? src[c0 + 1] : 0.f;
    any |= (v0 != 0.f) | (v1 != 0.f);
    __hip_bfloat162 pr;
    pr.x = __float2bfloat16(v0);
    pr.y = __float2bfloat16(v1);
    *(__hip_bfloat162*)(dst + c0) = pr;
  }
  any = __any(any) ? 1 : 0;
  if ((t & 63) == 0) sred[t >> 6] = any;
  __syncthreads();
  if (t == 0) nz[m] = sred[0] | sred[1] | sred[2] | sred[3];
}

// Compaction + padding mask + decoder-KV bias concat (single block)
__global__ __launch_bounds__(256)
void compact_kernel(const int* __restrict__ nz, int* __restrict__ idx,
                    int* __restrict__ pos, int* __restrict__ cnt,
                    int* __restrict__ pad,
                    const float* __restrict__ dkvb, float* __restrict__ kvbias)
{
  __shared__ int wsum[4];
  __shared__ int total;
  const int t = threadIdx.x;
  int loc[13];
  int c = 0;
#pragma unroll
  for (int i = 0; i < 13; ++i) {
    const int m = t * 13 + i;
    loc[i] = (m < ROWS) ? nz[m] : 0;
    c += loc[i];
  }
  int v = c;
#pragma unroll
  for (int o = 1; o < 64; o <<= 1) {
    const int u = __shfl_up(v, o);
    if ((t & 63) >= o) v += u;
  }
  if ((t & 63) == 63) wsum[t >> 6] = v;
  __syncthreads();
  int wbase = 0;
  for (int w = 0; w < (t >> 6); ++w) wbase += wsum[w];
  int p = wbase + v - c;
#pragma unroll
  for (int i = 0; i < 13; ++i) {
    const int m = t * 13 + i;
    if (m < ROWS) {
      if (loc[i]) { idx[p] = m; pos[m] = p; ++p; }
      else pos[m] = -1;
    }
  }
  if (t == 255) total = p;
  __syncthreads();
  const int count = total;
  if (t == 0) cnt[0] = count + 1;
  for (int i = count + t; i < MPAD; i += 256) idx[i] = ROWS;
  for (int m = t; m < ROWS; m += 256) if (pos[m] < 0) pos[m] = count;
  if (t < 32) {
    int any = 0;
    for (int s = 99; s >= 0; --s) {
      any |= nz[t * 100 + s];
      pad[t * 100 + s] = (s > 0 && !any) ? 1 : 0;
    }
  }
#pragma unroll
  for (int i = t; i < 2048; i += 256) {
    const int L = i >> 10, j = i & 1023;
    kvbias[i] = dkvb[L * 1536 + 512 + j];
  }
}

// fc1 weight fp32 -> bf16 with column pad; one block per row, 8 elems/thread
__global__ __launch_bounds__(256)
void cvt_fc1_kernel(const float* __restrict__ in, __hip_bfloat16* __restrict__ out)
{
  const int r = blockIdx.x;               // 4096 rows
  const float* src = in + (size_t)r * FLATIN;
  __hip_bfloat16* dst = out + (size_t)r * KPAD1;
#pragma unroll
  for (int u = 0; u < KPAD1 / 2048; ++u) {
    const int c0 = u * 2048 + threadIdx.x * 8;
    union { short8 v; __hip_bfloat16 h[8]; } pk;
    if (c0 + 8 <= FLATIN) {
      const float4 a = *(const float4*)(src + c0);
      const float4 b = *(const float4*)(src + c0 + 4);
      pk.h[0] = __float2bfloat16(a.x); pk.h[1] = __float2bfloat16(a.y);
      pk.h[2] = __float2bfloat16(a.z); pk.h[3] = __float2bfloat16(a.w);
      pk.h[4] = __float2bfloat16(b.x); pk.h[5] = __float2bfloat16(b.y);
      pk.h[6] = __float2bfloat16(b.z); pk.h[7] = __float2bfloat16(b.w);
    } else {
#pragma unroll
      for (int i = 0; i < 8; ++i)
        pk.h[i] = __float2bfloat16((c0 + i < FLATIN) ? src[c0 + i] : 0.f);
    }
    *(short8*)(dst + c0) = pk.v;
  }
}

// Flat fp32 -> bf16 (count multiple of 2048); used for out3_w late conversion
__global__ __launch_bounds__(256)
void cvt_flat_kernel(const float* __restrict__ src, __hip_bfloat16* __restrict__ dst)
{
  const size_t e0 = ((size_t)blockIdx.x << 11) + (threadIdx.x << 3);
  const float4 v0 = *(const float4*)(src + e0);
  const float4 v1 = *(const float4*)(src + e0 + 4);
  union { short8 v; __hip_bfloat16 h[8]; } pk;
  pk.h[0] = __float2bfloat16(v0.x); pk.h[1] = __float2bfloat16(v0.y);
  pk.h[2] = __float2bfloat16(v0.z); pk.h[3] = __float2bfloat16(v0.w);
  pk.h[4] = __float2bfloat16(v1.x); pk.h[5] = __float2bfloat16(v1.y);
  pk.h[6] = __float2bfloat16(v1.z); pk.h[7] = __float2bfloat16(v1.w);
  *(short8*)(dst + e0) = pk.v;
}

// Multi-segment flat fp32->bf16 (counts multiples of 2048)
struct CvtArgs {
  const float* src[9];
  __hip_bfloat16* dst[9];
  int cum[9];
};
__global__ __launch_bounds__(256)
void cvt_multi_kernel(CvtArgs a)
{
  const int bid = blockIdx.x;
  int seg = 0;
#pragma unroll
  for (int i = 1; i < 9; ++i) if (bid >= a.cum[i]) seg = i;
  const size_t e0 = ((size_t)(bid - a.cum[seg]) << 11) + (threadIdx.x << 3);
  const float4 v0 = *(const float4*)(a.src[seg] + e0);
  const float4 v1 = *(const float4*)(a.src[seg] + e0 + 4);
  union { short4v v; __hip_bfloat16 h[4]; } u0, u1;
  u0.h[0] = __float2bfloat16(v0.x); u0.h[1] = __float2bfloat16(v0.y);
  u0.h[2] = __float2bfloat16(v0.z); u0.h[3] = __float2bfloat16(v0.w);
  u1.h[0] = __float2bfloat16(v1.x); u1.h[1] = __float2bfloat16(v1.y);
  u1.h[2] = __float2bfloat16(v1.z); u1.h[3] = __float2bfloat16(v1.w);
  *(short4v*)(a.dst[seg] + e0) = u0.v;
  *(short4v*)(a.dst[seg] + e0 + 4) = u1.v;
}

// Multi-segment tiled fp32 transpose: dst[C][R] = src[R][C]^T ; 64x64 tiles.
struct TrArgs {
  const float* src[13];
  float* dst[13];
  int R[13], C[13], cum[13];
};
__global__ __launch_bounds__(256)
void transpose_kernel(TrArgs a)
{
  __shared__ float tbuf[64][65];
  const int bid = blockIdx.x;
  int seg = 0;
#pragma unroll
  for (int i = 1; i < 13; ++i) if (bid >= a.cum[i]) seg = i;
  const int local = bid - a.cum[seg];
  const int R = a.R[seg], C = a.C[seg];
  const int tilesC = C >> 6;
  const int r0 = (local / tilesC) << 6;
  const int c0 = (local % tilesC) << 6;
  const int tx = threadIdx.x & 63, ty = threadIdx.x >> 6;
  const float* s = a.src[seg];
  float* d = a.dst[seg];
#pragma unroll
  for (int i = 0; i < 16; ++i) {
    const int rr = (ty << 4) + i;
    tbuf[rr][tx] = s[(size_t)(r0 + rr) * C + c0 + tx];
  }
  __syncthreads();
#pragma unroll
  for (int i = 0; i < 16; ++i) {
    const int cc = (ty << 4) + i;
    d[(size_t)(c0 + cc) * R + r0 + tx] = tbuf[tx][cc];
  }
}

// fc3 reduce + bias + relu + scatter + inline PE
__global__ __launch_bounds__(256)
void scatter_pe_reduce(const float* __restrict__ P, size_t pstride, int ksl,
                       const int* __restrict__ pos, const float* __restrict__ bias,
                       float* __restrict__ hf, __hip_bfloat16* __restrict__ hb)
{
  const int m = blockIdx.x;
  const int s = m % 100, b = m / 100;
  const int src = pos[m];
  const int t = threadIdx.x;
  const size_t sb = (size_t)src * 512;
  const size_t db = (size_t)(s * 32 + b) * 512;
#pragma unroll
  for (int u = 0; u < 2; ++u) {
    const int d = t + u * 256;
    float v = bias[d];
    for (int k = 0; k < ksl; ++k) v += P[(size_t)k * pstride + sb + d];
    const float div = expf((float)(2 * (d >> 1)) * (-9.210340371976184f / 512.f));
    const float arg = (float)s * div;
    const float pe = (d & 1) ? cosf(arg) : sinf(arg);
    v = fmaxf(v, 0.f) + pe;
    hf[db + d] = v;
    hb[db + d] = __float2bfloat16(v);
  }
}

// ---------------------------------------------------------------------------
// LayerNorm over D=512 (+ optional second, final LN fused)
__global__ __launch_bounds__(256)
void ln_kernel(const float* __restrict__ x, const float* __restrict__ res,
               const float* __restrict__ g, const float* __restrict__ bta,
               const float* __restrict__ gf, const float* __restrict__ bf_,
               int dofinal, float* __restrict__ y, __hip_bfloat16* __restrict__ yb)
{
  __shared__ float rs[4], rss[4];
  const int row = blockIdx.x;
  const int t = threadIdx.x;
  const size_t base = (size_t)row * 512;
  float v0 = x[base + t];
  float v1 = x[base + t + 256];
  if (res) { v0 += res[base + t]; v1 += res[base + t + 256]; }
  float o0, o1;
#pragma unroll
  for (int pass = 0; pass < 2; ++pass) {
    float s = v0 + v1, ss = v0 * v0 + v1 * v1;
#pragma unroll
    for (int o = 32; o > 0; o >>= 1) { s += __shfl_xor(s, o); ss += __shfl_xor(ss, o); }
    if ((t & 63) == 0) { rs[t >> 6] = s; rss[t >> 6] = ss; }
    __syncthreads();
    s = rs[0] + rs[1] + rs[2] + rs[3];
    ss = rss[0] + rss[1] + rss[2] + rss[3];
    __syncthreads();
    const float mean = s * (1.f / 512.f);
    const float var = ss * (1.f / 512.f) - mean * mean;
    const float inv = rsqrtf(var + 1e-5f);
    const float* gg = (pass == 0) ? g : gf;
    const float* bb = (pass == 0) ? bta : bf_;
    o0 = (v0 - mean) * inv * gg[t] + bb[t];
    o1 = (v1 - mean) * inv * gg[t + 256] + bb[t + 256];
    if (pass == 1 || !dofinal) break;
    v0 = o0; v1 = o1;
  }
  if (y) {
    y[base + t] = o0;
    y[base + t + 256] = o1;
  }
  if (yb) {
    yb[base + t] = __float2bfloat16(o0);
    yb[base + t + 256] = __float2bfloat16(o1);
  }
}

// ---------------------------------------------------------------------------
// Encoder self-attention. grid (128 bh, 25 qg): 4 q's per block.
__global__ __launch_bounds__(256)
void enc_attn_kernel(const float* __restrict__ qkv, const int* __restrict__ pad,
                     __hip_bfloat16* __restrict__ ob)
{
  __shared__ float Ks[100][129];
  __shared__ float Qs[128];
  __shared__ float Ps[100];
  __shared__ float red[4];
  const int bh = blockIdx.x;
  const int b = bh >> 2, h = bh & 3;
  const int q0 = blockIdx.y * 4;
  const int t = threadIdx.x;
  for (int i = t; i < 12800; i += 256) {
    const int s = i >> 7, d = i & 127;
    Ks[s][d] = qkv[(size_t)(s * 32 + b) * 1536 + 512 + h * 128 + d];
  }
  const int masked = (t < 100) ? pad[b * 100 + t] : 0;
  const float scale = 0.08838834764831845f;
  for (int qi = 0; qi < 4; ++qi) {
    const int q = q0 + qi;
    __syncthreads();
    if (t < 128) Qs[t] = qkv[(size_t)(q * 32 + b) * 1536 + h * 128 + t];
    __syncthreads();
    float sc = -3e38f;
    if (t < 100) {
      const float* kr = &Ks[t][0];
      float a = 0.f;
#pragma unroll 16
      for (int d = 0; d < 128; ++d) a += Qs[d] * kr[d];
      sc = masked ? -1e9f : (a * scale);
    }
    float mx = sc;
#pragma unroll
    for (int o = 32; o > 0; o >>= 1) mx = fmaxf(mx, __shfl_xor(mx, o));
    if ((t & 63) == 0) red[t >> 6] = mx;
    __syncthreads();
    mx = fmaxf(fmaxf(red[0], red[1]), fmaxf(red[2], red[3]));
    const float e = (t < 100) ? expf(sc - mx) : 0.f;
    float sm = e;
#pragma unroll
    for (int o = 32; o > 0; o >>= 1) sm += __shfl_xor(sm, o);
    __syncthreads();
    if ((t & 63) == 0) red[t >> 6] = sm;
    __syncthreads();
    sm = red[0] + red[1] + red[2] + red[3];
    if (t < 100) Ps[t] = e;
    __syncthreads();
    if (t < 128) {
      float a = 0.f;
      const float* vb = qkv + 1024 + h * 128 + t;
      for (int k = 0; k < 100; ++k) a += Ps[k] * vb[(size_t)(k * 32 + b) * 1536];
      ob[(size_t)(q * 32 + b) * 512 + h * 128 + t] = __float2bfloat16(a / sm);
    }
  }
}

// ---------------------------------------------------------------------------
// Fused decoder layer: transposed-weight coalesced GEMVs. 512 thr, grid 32.
template<int N, int K, int RELU>
__device__ __forceinline__ void gemvT(int tid, const float* S,
                                      const float* __restrict__ WT,
                                      const float* __restrict__ bias,
                                      float* out, float* part)
{
  constexpr int NQ = N / 4;
  constexpr int G = 512 / NQ;
  constexpr int KP = K / G;
  const int p = tid % NQ;
  const int g = tid / NQ;
  const float4* wp = (const float4*)WT;
  float ax = 0.f, ay = 0.f, az = 0.f, aw = 0.f;
  const int kend = g * KP + KP;
#pragma unroll 8
  for (int k = g * KP; k < kend; ++k) {
    const float s = S[k];
    const float4 w = wp[(size_t)k * NQ + p];
    ax += s * w.x; ay += s * w.y; az += s * w.z; aw += s * w.w;
  }
  float4 a4 = {ax, ay, az, aw};
  *(float4*)(part + g * N + 4 * p) = a4;
  __syncthreads();
#pragma unroll
  for (int n = tid; n < N; n += 512) {
    float v = bias[n];
#pragma unroll
    for (int q = 0; q < G; ++q) v += part[q * N + n];
    if (RELU) v = fmaxf(v, 0.f);
    out[n] = v;
  }
  __syncthreads();
}

#define BLOCK_LN512(V, G, B, O)                                                 \
  {                                                                             \
    float s_ = (V), ss_ = (V) * (V);                                            \
    _Pragma("unroll")                                                           \
    for (int o_ = 32; o_ > 0; o_ >>= 1) {                                       \
      s_ += __shfl_xor(s_, o_); ss_ += __shfl_xor(ss_, o_);                     \
    }                                                                           \
    if ((tid & 63) == 0) { red[tid >> 6] = s_; red2[tid >> 6] = ss_; }          \
    __syncthreads();                                                            \
    s_ = 0.f; ss_ = 0.f;                                                        \
    _Pragma("unroll")                                                           \
    for (int w_ = 0; w_ < 8; ++w_) { s_ += red[w_]; ss_ += red2[w_]; }          \
    const float mean_ = s_ * (1.f / 512.f);                                     \
    const float inv_ = rsqrtf(ss_ * (1.f / 512.f) - mean_ * mean_ + 1e-5f);     \
    O = ((V) - mean_) * inv_ * (G)[tid] + (B)[tid];                             \
    __syncthreads();                                                            \
  }

__global__ __launch_bounds__(512)
void dec_layer(const float* __restrict__ tin,          // nullptr => ones
               const float* __restrict__ kvb,          // K at +0, V at +512
               int kvstride,
               const float* __restrict__ WvT, const float* __restrict__ bv,
               const float* __restrict__ WpT, const float* __restrict__ bp,
               const float* __restrict__ g1, const float* __restrict__ b1,
               const float* __restrict__ WqT, const float* __restrict__ bq,
               const float* __restrict__ WcpT, const float* __restrict__ bcp,
               const float* __restrict__ g2, const float* __restrict__ b2,
               const float* __restrict__ W1T, const float* __restrict__ b1f,
               const float* __restrict__ W2T, const float* __restrict__ b2f,
               const float* __restrict__ g3, const float* __restrict__ b3,
               const float* __restrict__ gf, const float* __restrict__ bf_,
               int dofinal, float* __restrict__ tout,
               const float* __restrict__ Wo1T, const float* __restrict__ ob1,
               __hip_bfloat16* __restrict__ o1b)
{
  __shared__ float Ts[512], Bs[512], Cs[512], F1[1024], part[2048];
  __shared__ float Ps[4][104];
  __shared__ float red[8], red2[8];
  const int r = blockIdx.x, tid = threadIdx.x;
  Ts[tid] = tin ? tin[r * 512 + tid] : 1.0f;
  __syncthreads();

  // self-attn (Sq=1: softmax over one key == 1 -> out = V(t))
  gemvT<512, 512, 0>(tid, Ts, WvT, bv, Bs, part);
  gemvT<512, 512, 0>(tid, Bs, WpT, bp, Cs, part);
  {
    const float rr = Cs[tid] + Ts[tid];
    float o;
    BLOCK_LN512(rr, g1, b1, o)
    Ts[tid] = o;                          // t1
  }
  __syncthreads();

  // cross-attn Q
  gemvT<512, 512, 0>(tid, Ts, WqT, bq, Bs, part);

  // cross-attention: wave h<4 handles head h; 100 keys, 2 per lane
  if (tid < 256) {
    const int h = tid >> 6, lane = tid & 63;
    const float scale = 0.08838834764831845f;
    const float* Qh = Bs + h * 128;
    float s0, s1 = -3e38f;
    {
      const float* kr = kvb + (size_t)(lane * 32 + r) * kvstride + h * 128;
      float a = 0.f;
#pragma unroll 16
      for (int d = 0; d < 128; ++d) a += Qh[d] * kr[d];
      s0 = a * scale;
    }
    if (lane + 64 < 100) {
      const float* kr = kvb + (size_t)((lane + 64) * 32 + r) * kvstride + h * 128;
      float a = 0.f;
#pragma unroll 16
      for (int d = 0; d < 128; ++d) a += Qh[d] * kr[d];
      s1 = a * scale;
    }
    float mx = fmaxf(s0, s1);
#pragma unroll
    for (int o = 32; o > 0; o >>= 1) mx = fmaxf(mx, __shfl_xor(mx, o));
    const float e0 = expf(s0 - mx);
    const float e1 = (lane + 64 < 100) ? expf(s1 - mx) : 0.f;
    float sm = e0 + e1;
#pragma unroll
    for (int o = 32; o > 0; o >>= 1) sm += __shfl_xor(sm, o);
    Ps[h][lane] = e0 / sm;
    if (lane + 64 < 100) Ps[h][lane + 64] = e1 / sm;
  }
  __syncthreads();
  if (tid < 256) {
    const int h = tid >> 6, lane = tid & 63;
#pragma unroll
    for (int u = 0; u < 2; ++u) {
      const int d = lane + u * 64;
      const float* vb = kvb + 512 + h * 128 + d;
      float a = 0.f;
      for (int k = 0; k < 100; ++k) a += Ps[h][k] * vb[(size_t)(k * 32 + r) * kvstride];
      Bs[h * 128 + d] = a;                // cav
    }
  }
  __syncthreads();

  // ca proj + residual + LN2
  gemvT<512, 512, 0>(tid, Bs, WcpT, bcp, Cs, part);
  {
    const float rr = Cs[tid] + Ts[tid];
    float o;
    BLOCK_LN512(rr, g2, b2, o)
    Ts[tid] = o;                          // t2
  }
  __syncthreads();

  // FF
  gemvT<1024, 512, 1>(tid, Ts, W1T, b1f, F1, part);
  gemvT<512, 1024, 0>(tid, F1, W2T, b2f, Cs, part);
  {
    const float rr = Cs[tid] + Ts[tid];
    float o;
    BLOCK_LN512(rr, g3, b3, o)
    if (dofinal) {
      float f;
      BLOCK_LN512(o, gf, bf_, f)
      o = f;
    }
    tout[r * 512 + tid] = o;
    if (dofinal) {
      Ts[tid] = o;
      __syncthreads();
      // fused out1: row r of C(32,2048) = relu(t @ Wo1T + b); 4 outputs/thread
      const float4* wp = (const float4*)Wo1T;   // [512][512 quads]
      float ax = 0.f, ay = 0.f, az = 0.f, aw = 0.f;
#pragma unroll 8
      for (int k = 0; k < 512; ++k) {
        const float s = Ts[k];
        const float4 w = wp[(size_t)k * 512 + tid];
        ax += s * w.x; ay += s * w.y; az += s * w.z; aw += s * w.w;
      }
      union { short4v v; __hip_bfloat16 h[4]; } u;
      u.h[0] = __float2bfloat16(fmaxf(ax + ob1[4 * tid], 0.f));
      u.h[1] = __float2bfloat16(fmaxf(ay + ob1[4 * tid + 1], 0.f));
      u.h[2] = __float2bfloat16(fmaxf(az + ob1[4 * tid + 2], 0.f));
      u.h[3] = __float2bfloat16(fmaxf(aw + ob1[4 * tid + 3], 0.f));
      *(short4v*)(o1b + (size_t)r * 2048 + 4 * tid) = u.v;
      const short4v z = {0, 0, 0, 0};
#pragma unroll
      for (int rr = r + 32; rr < 128; rr += 32)
        *(short4v*)(o1b + (size_t)rr * 2048 + 4 * tid) = z;
    }
  }
}

// ---------------------------------------------------------------------------
// out3 split-K reduce (+bias(+guard)+relu) fused with adaptive pool. grid 32.
__global__ __launch_bounds__(256)
void reduce_pool(const float* __restrict__ P, size_t pstride,
                 const float* __restrict__ bias, float* __restrict__ out)
{
  __shared__ float row[NOUT3];
  const int b = blockIdx.x, t = threadIdx.x;
  for (int n = t * 4; n < NOUT3; n += 1024) {
    const size_t o = (size_t)b * NOUT3 + n;
    float4 s = *(const float4*)(P + o);
#pragma unroll
    for (int k = 1; k < 4; ++k) {
      const float4 p = *(const float4*)(P + (size_t)k * pstride + o);
      s.x += p.x; s.y += p.y; s.z += p.z; s.w += p.w;
    }
    row[n]     = fmaxf(s.x + ((n     < FLATIN) ? bias[n]     : 0.f), 0.f);
    row[n + 1] = fmaxf(s.y + ((n + 1 < FLATIN) ? bias[n + 1] : 0.f), 0.f);
    row[n + 2] = fmaxf(s.z + ((n + 2 < FLATIN) ? bias[n + 2] : 0.f), 0.f);
    row[n + 3] = fmaxf(s.w + ((n + 3 < FLATIN) ? bias[n + 3] : 0.f), 0.f);
  }
  __syncthreads();
  for (int i = t; i < 135 * 103; i += 256) {
    const int j = i % 103, r = i / 103;
    const int rs = (r * 143) / 135, re = ((r + 1) * 143 + 134) / 135;
    const int cs = (j * 111) / 103, ce = ((j + 1) * 111 + 102) / 103;
    float s = 0.f;
    for (int rr = rs; rr < re; ++rr)
      for (int cc = cs; cc < ce; ++cc)
        s += row[rr * 111 + cc];
    out[(size_t)b * (135 * 103) + i] = s / (float)((re - rs) * (ce - cs));
  }
}

// ---------------------------------------------------------------------------
extern "C" void kernel_launch(void* const* d_in, const int* in_sizes, int n_in,
                              void* d_out, int out_size, void* d_ws, size_t ws_size,
                              hipStream_t stream)
{
  (void)in_sizes; (void)n_in; (void)out_size; (void)ws_size;

  const float* x          = (const float*)d_in[0];
  const float* fc1_w      = (const float*)d_in[1];
  const float* fc1_b      = (const float*)d_in[2];
  const float* fc2_w      = (const float*)d_in[3];
  const float* fc2_b      = (const float*)d_in[4];
  const float* fc3_w      = (const float*)d_in[5];
  const float* fc3_b      = (const float*)d_in[6];
  const float* out1_w     = (const float*)d_in[7];
  const float* out1_b     = (const float*)d_in[8];
  const float* out2_w     = (const float*)d_in[9];
  const float* out2_b     = (const float*)d_in[10];
  const float* out3_w     = (const float*)d_in[11];
  const float* out3_b     = (const float*)d_in[12];
  const float* enc_qkv_w  = (const float*)d_in[13];
  const float* enc_qkv_b  = (const float*)d_in[14];
  const float* enc_proj_w = (const float*)d_in[15];
  const float* enc_proj_b = (const float*)d_in[16];
  const float* enc_ff1_w  = (const float*)d_in[17];
  const float* enc_ff1_b  = (const float*)d_in[18];
  const float* enc_ff2_w  = (const float*)d_in[19];
  const float* enc_ff2_b  = (const float*)d_in[20];
  const float* enc_ln1_g  = (const float*)d_in[21];
  const float* enc_ln1_b  = (const float*)d_in[22];
  const float* enc_ln2_g  = (const float*)d_in[23];
  const float* enc_ln2_b  = (const float*)d_in[24];
  const float* enc_lnf_g  = (const float*)d_in[25];
  const float* enc_lnf_b  = (const float*)d_in[26];
  const float* dec_sa_qkv_w  = (const float*)d_in[27];
  const float* dec_sa_qkv_b  = (const float*)d_in[28];
  const float* dec_sa_proj_w = (const float*)d_in[29];
  const float* dec_sa_proj_b = (const float*)d_in[30];
  const float* dec_ca_qkv_w  = (const float*)d_in[31];
  const float* dec_ca_qkv_b  = (const float*)d_in[32];
  const float* dec_ca_proj_w = (const float*)d_in[33];
  const float* dec_ca_proj_b = (const float*)d_in[34];
  const float* dec_ff1_w  = (const float*)d_in[35];
  const float* dec_ff1_b  = (const float*)d_in[36];
  const float* dec_ff2_w  = (const float*)d_in[37];
  const float* dec_ff2_b  = (const float*)d_in[38];
  const float* dec_ln1_g  = (const float*)d_in[39];
  const float* dec_ln1_b  = (const float*)d_in[40];
  const float* dec_ln2_g  = (const float*)d_in[41];
  const float* dec_ln2_b  = (const float*)d_in[42];
  const float* dec_ln3_g  = (const float*)d_in[43];
  const float* dec_ln3_b  = (const float*)d_in[44];
  const float* dec_lnf_g  = (const float*)d_in[45];
  const float* dec_lnf_b  = (const float*)d_in[46];

  char* wsp = (char*)d_ws;
  size_t off = 0;
  auto alloc = [&](size_t nbytes) -> char* {
    char* p = wsp + off;
    off += (nbytes + 255) & ~(size_t)255;
    return p;
  };

  __hip_bfloat16* xb     = (__hip_bfloat16*)alloc((size_t)MPAD * KPAD1 * 2);
  __hip_bfloat16* Wb1    = (__hip_bfloat16*)alloc((size_t)4096 * KPAD1 * 2);
  __hip_bfloat16* Wb2    = (__hip_bfloat16*)alloc((size_t)2048 * 4096 * 2);
  __hip_bfloat16* Wb3    = (__hip_bfloat16*)alloc((size_t)512 * 2048 * 2);
  __hip_bfloat16* Wqkvb  = (__hip_bfloat16*)alloc((size_t)2 * 1536 * 512 * 2);
  __hip_bfloat16* Wprojb = (__hip_bfloat16*)alloc((size_t)2 * 512 * 512 * 2);
  __hip_bfloat16* Wff1b  = (__hip_bfloat16*)alloc((size_t)2 * 1024 * 512 * 2);
  __hip_bfloat16* Wff2b  = (__hip_bfloat16*)alloc((size_t)2 * 512 * 1024 * 2);
  __hip_bfloat16* Wkv2b  = (__hip_bfloat16*)alloc((size_t)2048 * 512 * 2);
  int*   nz      = (int*)alloc(ROWS * 4);
  int*   padmask = (int*)alloc(ROWS * 4);
  int*   idx     = (int*)alloc(MPAD * 4);
  int*   pos     = (int*)alloc(ROWS * 4);
  int*   cnt     = (int*)alloc(256);
  float* kvbias  = (float*)alloc(2048 * 4);
  __hip_bfloat16* h1c = (__hip_bfloat16*)alloc((size_t)MPAD * 4096 * 2);
  __hip_bfloat16* h2c = (__hip_bfloat16*)alloc((size_t)MPAD * 2048 * 2);
  float* hf  = (float*)alloc((size_t)ROWS * 512 * 4);
  __hip_bfloat16* hb = (__hip_bfloat16*)alloc((size_t)ROWS * 512 * 2);
  float* qkvbuf = (float*)alloc((size_t)ROWS * 1536 * 4);
  __hip_bfloat16* attnb = (__hip_bfloat16*)alloc((size_t)ROWS * 512 * 2);
  float* pjf  = (float*)alloc((size_t)ROWS * 512 * 4);
  __hip_bfloat16* f1b = (__hip_bfloat16*)alloc((size_t)ROWS * 1024 * 2);
  float* f2f  = (float*)alloc((size_t)ROWS * 512 * 4);
  __hip_bfloat16* memb = (__hip_bfloat16*)alloc((size_t)ROWS * 512 * 2);
  float* kv01 = (float*)alloc((size_t)ROWS * 2048 * 4);
  float* tbuf = (float*)alloc(32 * 512 * 4);
  // transposed fp32 weights (decoder + out1)
  float* WvT[2]  = { (float*)alloc(512 * 512 * 4), (float*)alloc(512 * 512 * 4) };
  float* WpT[2]  = { (float*)alloc(512 * 512 * 4), (float*)alloc(512 * 512 * 4) };
  float* WqT[2]  = { (float*)alloc(512 * 512 * 4), (float*)alloc(512 * 512 * 4) };
  float* WcpT[2] = { (float*)alloc(512 * 512 * 4), (float*)alloc(512 * 512 * 4) };
  float* W1T[2]  = { (float*)alloc(512 * 1024 * 4), (float*)alloc(512 * 1024 * 4) };
  float* W2T[2]  = { (float*)alloc(1024 * 512 * 4), (float*)alloc(1024 * 512 * 4) };
  float* Wo1T    = (float*)alloc((size_t)512 * 2048 * 4);
  // split-K partial buffers (time-shared)
  float* fcP  = (float*)alloc((size_t)4 * MPAD * 4096 * 4);   // 218 MB
  float* encP = (float*)alloc((size_t)2 * ROWS * 1536 * 4);   // aliases

  // phase-4 aliases. Wo3b lives at fcP+48MB: safe ONLY after fc2's reduce
  // (fc1/fc2 partials span up to 109MB); fc3 partials (27MB) and out2/out3
  // partials (<=33MB) stay below the 48MB offset.
  float* outP = fcP;
  __hip_bfloat16* Wo3b = (__hip_bfloat16*)((char*)fcP + ((size_t)48 << 20)); // 124 MB
  __hip_bfloat16* Wo2b = (__hip_bfloat16*)encP;                              // 16.8 MB
  __hip_bfloat16* o1b  = (__hip_bfloat16*)((char*)encP + ((size_t)20 << 20));
  __hip_bfloat16* o2b  = (__hip_bfloat16*)((char*)encP + ((size_t)22 << 20));

  const size_t psF1 = (size_t)MPAD * 4096;
  const size_t psF2 = (size_t)MPAD * 2048;
  const size_t psF3 = (size_t)MPAD * 512;

  // ---- phase 0 ----
  conv_x_kernel<<<ROWS + 1, 256, 0, stream>>>(x, xb, nz);
  compact_kernel<<<1, 256, 0, stream>>>(nz, idx, pos, cnt, padmask,
                                        dec_ca_qkv_b, kvbias);
  {
    CvtArgs a;
    const float* srcs[9] = { enc_qkv_w, enc_proj_w, enc_ff1_w, enc_ff2_w,
                             dec_ca_qkv_w + (size_t)512 * 512,
                             dec_ca_qkv_w + (size_t)(1536 + 512) * 512,
                             fc2_w, fc3_w, out2_w };
    __hip_bfloat16* dsts[9] = { Wqkvb, Wprojb, Wff1b, Wff2b,
                                Wkv2b, Wkv2b + (size_t)1024 * 512,
                                Wb2, Wb3, Wo2b };
    const int counts[9] = { 2*1536*512, 2*512*512, 2*1024*512, 2*512*1024,
                            1024*512, 1024*512, 2048*4096, 512*2048, 4096*2048 };
    int c = 0;
    for (int i = 0; i < 9; ++i) { a.src[i] = srcs[i]; a.dst[i] = dsts[i];
                                  a.cum[i] = c; c += counts[i] >> 11; }
    cvt_multi_kernel<<<c, 256, 0, stream>>>(a);
  }
  cvt_fc1_kernel<<<4096, 256, 0, stream>>>(fc1_w, Wb1);
  {
    TrArgs a;
    const float* srcs[13];
    float* dsts[13];
    int R[13], C[13];
    int n = 0;
    for (int L = 0; L < 2; ++L) {
      srcs[n] = dec_sa_qkv_w + (size_t)L * 1536 * 512 + (size_t)1024 * 512;
      dsts[n] = WvT[L]; R[n] = 512; C[n] = 512; ++n;
      srcs[n] = dec_sa_proj_w + (size_t)L * 512 * 512;
      dsts[n] = WpT[L]; R[n] = 512; C[n] = 512; ++n;
      srcs[n] = dec_ca_qkv_w + (size_t)L * 1536 * 512;
      dsts[n] = WqT[L]; R[n] = 512; C[n] = 512; ++n;
      srcs[n] = dec_ca_proj_w + (size_t)L * 512 * 512;
      dsts[n] = WcpT[L]; R[n] = 512; C[n] = 512; ++n;
      srcs[n] = dec_ff1_w + (size_t)L * 1024 * 512;
      dsts[n] = W1T[L]; R[n] = 1024; C[n] = 512; ++n;
      srcs[n] = dec_ff2_w + (size_t)L * 512 * 1024;
      dsts[n] = W2T[L]; R[n] = 512; C[n] = 1024; ++n;
    }
    srcs[n] = out1_w; dsts[n] = Wo1T; R[n] = 2048; C[n] = 512; ++n;
    int c = 0;
    for (int i = 0; i < 13; ++i) {
      a.src[i] = srcs[i]; a.dst[i] = dsts[i]; a.R[i] = R[i]; a.C[i] = C[i];
      a.cum[i] = c; c += (R[i] >> 6) * (C[i] >> 6);
    }
    transpose_kernel<<<c, 256, 0, stream>>>(a);
  }

  // ---- phase 1: input MLP (split-K) ----
  gemm_bf16<1><<<26 * 32 * 2, 256, 0, stream>>>(xb, Wb1, idx, cnt, fcP,
      KPAD1, 4096, 26, 2, psF1);
  reduce_kernel<1, 0, 1><<<dim3(4, MPAD), 256, 0, stream>>>(fcP, psF1, 2,
      fc1_b, nullptr, h1c, 4096, cnt);
  gemm_bf16<0><<<26 * 16 * 4, 256, 0, stream>>>(h1c, Wb2, nullptr, cnt, fcP,
      4096, 2048, 26, 4, psF2);
  reduce_kernel<1, 0, 1><<<dim3(2, MPAD), 256, 0, stream>>>(fcP, psF2, 4,
      fc2_b, nullptr, h2c, 2048, cnt);
  // out3_w late conversion: fcP beyond 48MB is dead from here on.
  cvt_flat_kernel<<<(FLATIN * 4096) / 2048, 256, 0, stream>>>(out3_w, Wo3b);
  gemm_bf16<0><<<26 * 4 * 4, 256, 0, stream>>>(h2c, Wb3, nullptr, cnt, fcP,
      2048, 512, 26, 4, psF3);
  scatter_pe_reduce<<<ROWS, 256, 0, stream>>>(fcP, psF3, 4, pos, fc3_b, hf, hb);

  // ---- phase 2: encoder ----
  for (int L = 0; L < 2; ++L) {
    gemm_direct<0, 1, 0><<<25 * 12, 256, 0, stream>>>(hb, Wqkvb + (size_t)L * 1536 * 512,
        enc_qkv_b + L * 1536, qkvbuf, nullptr, 512, 1536, 25);
    enc_attn_kernel<<<dim3(128, 25), 256, 0, stream>>>(qkvbuf, padmask, attnb);
    gemm_direct<0, 1, 0><<<25 * 4, 256, 0, stream>>>(attnb, Wprojb + (size_t)L * 512 * 512,
        enc_proj_b + L * 512, pjf, nullptr, 512, 512, 25);
    ln_kernel<<<ROWS, 256, 0, stream>>>(hf, pjf, enc_ln1_g + L * 512, enc_ln1_b + L * 512,
        nullptr, nullptr, 0, hf, hb);
    gemm_direct<1, 0, 1><<<25 * 8, 256, 0, stream>>>(hb, Wff1b + (size_t)L * 1024 * 512,
        enc_ff1_b + L * 1024, nullptr, f1b, 512, 1024, 25);
    gemm_direct<0, 1, 0><<<25 * 4, 256, 0, stream>>>(f1b, Wff2b + (size_t)L * 512 * 1024,
        enc_ff2_b + L * 512, f2f, nullptr, 1024, 512, 25);
    if (L == 0) {
      ln_kernel<<<ROWS, 256, 0, stream>>>(hf, f2f, enc_ln2_g, enc_ln2_b,
          nullptr, nullptr, 0, hf, hb);
    } else {
      ln_kernel<<<ROWS, 256, 0, stream>>>(hf, f2f, enc_ln2_g + 512, enc_ln2_b + 512,
          enc_lnf_g, enc_lnf_b, 1, nullptr, memb);
    }
  }

  // ---- decoder KV (both layers, one GEMM) ----
  gemm_direct<0, 1, 0><<<25 * 16, 256, 0, stream>>>(memb, Wkv2b, kvbias,
      kv01, nullptr, 512, 2048, 25);

  // ---- phase 3: fused decoder layers (+ out1 fused into L1) ----
  for (int L = 0; L < 2; ++L) {
    dec_layer<<<32, 512, 0, stream>>>(
        (L == 0) ? nullptr : tbuf,
        kv01 + (size_t)L * 1024, 2048,
        WvT[L], dec_sa_qkv_b + L * 1536 + 1024,
        WpT[L], dec_sa_proj_b + L * 512,
        dec_ln1_g + L * 512, dec_ln1_b + L * 512,
        WqT[L], dec_ca_qkv_b + L * 1536,
        WcpT[L], dec_ca_proj_b + L * 512,
        dec_ln2_g + L * 512, dec_ln2_b + L * 512,
        W1T[L], dec_ff1_b + L * 1024,
        W2T[L], dec_ff2_b + L * 512,
        dec_ln3_g + L * 512, dec_ln3_b + L * 512,
        dec_lnf_g, dec_lnf_b, (L == 1) ? 1 : 0, tbuf,
        Wo1T, out1_b, o1b);
  }

  // ---- phase 4: output MLP ----
  gemm_bf16<0><<<32 * 4, 256, 0, stream>>>(o1b, Wo2b, nullptr, nullptr, outP,
      2048, 4096, 1, 4, (size_t)128 * 4096);
  reduce_kernel<1, 0, 1><<<dim3(4, 128), 256, 0, stream>>>(outP, (size_t)128 * 4096, 4,
      out2_b, nullptr, o2b, 4096, nullptr);
  gemm_bf16<0><<<125 * 4, 256, 0, stream>>>(o2b, Wo3b, nullptr, nullptr, outP,
      4096, NOUT3, 1, 4, (size_t)128 * NOUT3);
  reduce_pool<<<32, 256, 0, stream>>>(outP, (size_t)128 * NOUT3, out3_b, (float*)d_out);
}

// Round 13
// 1394.621 us; speedup vs baseline: 1.2660x; 1.0244x over previous
//
#include <hip/hip_runtime.h>
#include <hip/hip_bf16.h>

// ---------------------------------------------------------------------------
#define SEQ   100
#define BATCH 32
#define FLATIN 15873
#define KPAD1  16384
#define ROWS   3200
#define MPAD   3328
#define NOUT3  16000

typedef __attribute__((ext_vector_type(8))) short short8;
typedef __attribute__((ext_vector_type(4))) short short4v;
typedef __attribute__((ext_vector_type(4))) float f32x4;

__device__ __forceinline__ void gload_lds16(const void* g, void* l) {
  __builtin_amdgcn_global_load_lds((const __attribute__((address_space(1))) void*)g,
                                   (__attribute__((address_space(3))) void*)l, 16, 0, 0);
}

// bijective XCD chunk swizzle (m204)
__device__ __forceinline__ int xcd_swizzle(int id, int nwg) {
  const int q = nwg >> 3, r = nwg & 7;
  const int x = id & 7, p = id >> 3;
  return (x < r ? x * (q + 1) : r * (q + 1) + (x - r) * q) + p;
}

// ---------------------------------------------------------------------------
// Shared GEMM body: stage 128x64 A/B tiles (both-sides chunk swizzle), MFMA.
#define GEMM_BODY(KBEG, KEND)                                                   \
  const int tid  = threadIdx.x;                                                 \
  const int lane = tid & 63;                                                    \
  const int wid  = tid >> 6;                                                    \
  const int wr = (wid >> 1) << 6;                                               \
  const int wc = (wid & 1) << 6;                                                \
  f32x4 acc[4][4];                                                              \
  _Pragma("unroll") for (int i = 0; i < 4; ++i)                                 \
  _Pragma("unroll") for (int j = 0; j < 4; ++j)                                 \
      acc[i][j] = (f32x4){0.f, 0.f, 0.f, 0.f};                                  \
  const int srow = (wid << 3) + (lane >> 3);                                    \
  const int scs  = lane & 7;                                                    \
  const int gcol = ((scs ^ (srow & 7)) << 3);                                   \
  const __hip_bfloat16* arow[4];                                                \
  const __hip_bfloat16* brow[4];                                                \
  _Pragma("unroll") for (int j = 0; j < 4; ++j) {                               \
    const int row = (j << 5) + srow;                                            \
    const int gr = GATHER ? idx[m0 + row] : (m0 + row);                         \
    arow[j] = A + (size_t)gr * K + gcol;                                        \
    brow[j] = W + (size_t)(n0 + row) * K + gcol;                                \
  }                                                                             \
  for (int k0 = (KBEG); k0 < (KEND); k0 += 64) {                                \
    __syncthreads();                                                            \
    _Pragma("unroll") for (int j = 0; j < 4; ++j) {                             \
      short* la = As + (((j << 2) + wid) << 9);                                 \
      short* lb = Bs + (((j << 2) + wid) << 9);                                 \
      gload_lds16(arow[j] + k0, la);                                            \
      gload_lds16(brow[j] + k0, lb);                                            \
    }                                                                           \
    __syncthreads();                                                            \
    _Pragma("unroll") for (int kk = 0; kk < 2; ++kk) {                          \
      short8 af[4], bfv[4];                                                     \
      _Pragma("unroll") for (int i = 0; i < 4; ++i) {                           \
        const int mr = wr + (i << 4) + (lane & 15);                             \
        const int cg = (kk << 2) + (lane >> 4);                                 \
        af[i]  = *(const short8*)(As + mr * 64 + ((cg ^ (mr & 7)) << 3));       \
        const int nr = wc + (i << 4) + (lane & 15);                             \
        bfv[i] = *(const short8*)(Bs + nr * 64 + ((cg ^ (nr & 7)) << 3));       \
      }                                                                         \
      _Pragma("unroll") for (int i = 0; i < 4; ++i)                             \
      _Pragma("unroll") for (int j = 0; j < 4; ++j)                             \
          acc[i][j] = __builtin_amdgcn_mfma_f32_16x16x32_bf16(af[i], bfv[j],    \
                                                              acc[i][j], 0,0,0);\
    }                                                                           \
  }

// Split-K partial-output GEMM. mt-minor linearization.
template<int GATHER>
__global__ __launch_bounds__(256)
void gemm_bf16(const __hip_bfloat16* __restrict__ A, const __hip_bfloat16* __restrict__ W,
               const int* __restrict__ idx, const int* __restrict__ cnt,
               float* __restrict__ P,
               int K, int ldc, int mtiles, int ksl, size_t pstride)
{
  __shared__ __align__(16) short lds[16384];
  short* As = lds;
  short* Bs = lds + 8192;
  const int wg = xcd_swizzle(blockIdx.x, gridDim.x);
  const int mt = wg % mtiles;
  const int g  = wg / mtiles;
  const int nt = g / ksl;
  const int ks = g % ksl;
  const int m0 = mt << 7;
  const int n0 = nt << 7;
  if (cnt && m0 >= cnt[0]) return;
  const int Klen = K / ksl;
  const int kbeg = ks * Klen;

  GEMM_BODY(kbeg, kbeg + Klen)

  float* Pout = P + (size_t)ks * pstride;
  const int fr = lane & 15, fq = lane >> 4;
#pragma unroll
  for (int j = 0; j < 4; ++j) {
    const int n = n0 + wc + (j << 4) + fr;
#pragma unroll
    for (int i = 0; i < 4; ++i)
#pragma unroll
      for (int r = 0; r < 4; ++r) {
        const int m = m0 + wr + (i << 4) + (fq << 2) + r;
        Pout[(size_t)m * ldc + n] = acc[i][j][r];
      }
  }
}

// Direct GEMM with fused bias/relu epilogue
template<int RELU, int OF32, int OB16>
__global__ __launch_bounds__(256)
void gemm_direct(const __hip_bfloat16* __restrict__ A, const __hip_bfloat16* __restrict__ W,
                 const float* __restrict__ bias, float* __restrict__ Cf,
                 __hip_bfloat16* __restrict__ Cb, int K, int ldc, int mtiles)
{
  __shared__ __align__(16) short lds[16384];
  short* As = lds;
  short* Bs = lds + 8192;
  const int GATHER = 0;
  const int* idx = nullptr;
  const int wg = xcd_swizzle(blockIdx.x, gridDim.x);
  const int m0 = (wg % mtiles) << 7;
  const int n0 = (wg / mtiles) << 7;

  GEMM_BODY(0, K)

  const int fr = lane & 15, fq = lane >> 4;
#pragma unroll
  for (int j = 0; j < 4; ++j) {
    const int n = n0 + wc + (j << 4) + fr;
    const float bb = bias[n];
#pragma unroll
    for (int i = 0; i < 4; ++i)
#pragma unroll
      for (int r = 0; r < 4; ++r) {
        const int m = m0 + wr + (i << 4) + (fq << 2) + r;
        float v = acc[i][j][r] + bb;
        if (RELU) v = fmaxf(v, 0.f);
        if (OF32) Cf[(size_t)m * ldc + n] = v;
        if (OB16) Cb[(size_t)m * ldc + n] = __float2bfloat16(v);
      }
  }
}

// ---------------------------------------------------------------------------
// Split-K GEMM with fp32 B-side: stages W from fp32 global via regs with
// on-the-fly bf16 conversion into the SAME swizzled LDS layout the MFMA
// read path expects (slot (row, c^(row&7)) holds chunk c). B rows clamped
// to wrows-1 (out3_w has FLATIN rows; garbage output cols never read).
__global__ __launch_bounds__(256)
void gemm_w32(const __hip_bfloat16* __restrict__ A, const float* __restrict__ W32,
              float* __restrict__ P, int K, int ldc, int ksl, size_t pstride,
              int wrows)
{
  __shared__ __align__(16) short lds[16384];
  short* As = lds;
  short* Bs = lds + 8192;
  const int wg = xcd_swizzle(blockIdx.x, gridDim.x);
  const int nt = wg / ksl;
  const int ks = wg % ksl;
  const int m0 = 0;
  const int n0 = nt << 7;
  const int Klen = K / ksl;
  const int kbeg = ks * Klen;
  const int kend = kbeg + Klen;

  const int tid  = threadIdx.x;
  const int lane = tid & 63;
  const int wid  = tid >> 6;
  const int wr = (wid >> 1) << 6;
  const int wc = (wid & 1) << 6;

  f32x4 acc[4][4];
#pragma unroll
  for (int i = 0; i < 4; ++i)
#pragma unroll
    for (int j = 0; j < 4; ++j) acc[i][j] = (f32x4){0.f, 0.f, 0.f, 0.f};

  const int srow = (wid << 3) + (lane >> 3);
  const int scs  = lane & 7;
  const int gcol = ((scs ^ (srow & 7)) << 3);

  const __hip_bfloat16* arow[4];
#pragma unroll
  for (int j = 0; j < 4; ++j)
    arow[j] = A + (size_t)(m0 + (j << 5) + srow) * K + gcol;

  // B source rows (clamped) for the 4 slots this thread stages per k-step
  const float* wsrc[4];
  int bslot[4];
#pragma unroll
  for (int i = 0; i < 4; ++i) {
    const int q = (i << 8) + tid;          // 0..1023
    const int row = q >> 3, c = q & 7;     // row 0..127, chunk 0..7
    const int wrow = min(n0 + row, wrows - 1);
    wsrc[i] = W32 + (size_t)wrow * K + (c << 3);
    bslot[i] = row * 64 + ((c ^ (row & 7)) << 3);
  }

  for (int k0 = kbeg; k0 < kend; k0 += 64) {
    __syncthreads();
#pragma unroll
    for (int j = 0; j < 4; ++j)
      gload_lds16(arow[j] + k0, As + (((j << 2) + wid) << 9));
#pragma unroll
    for (int i = 0; i < 4; ++i) {
      const float4 w0 = *(const float4*)(wsrc[i] + k0);
      const float4 w1 = *(const float4*)(wsrc[i] + k0 + 4);
      union { short8 v; __hip_bfloat16 h[8]; } pk;
      pk.h[0] = __float2bfloat16(w0.x); pk.h[1] = __float2bfloat16(w0.y);
      pk.h[2] = __float2bfloat16(w0.z); pk.h[3] = __float2bfloat16(w0.w);
      pk.h[4] = __float2bfloat16(w1.x); pk.h[5] = __float2bfloat16(w1.y);
      pk.h[6] = __float2bfloat16(w1.z); pk.h[7] = __float2bfloat16(w1.w);
      *(short8*)(Bs + bslot[i]) = pk.v;
    }
    __syncthreads();
#pragma unroll
    for (int kk = 0; kk < 2; ++kk) {
      short8 af[4], bfv[4];
#pragma unroll
      for (int i = 0; i < 4; ++i) {
        const int mr = wr + (i << 4) + (lane & 15);
        const int cg = (kk << 2) + (lane >> 4);
        af[i]  = *(const short8*)(As + mr * 64 + ((cg ^ (mr & 7)) << 3));
        const int nr = wc + (i << 4) + (lane & 15);
        bfv[i] = *(const short8*)(Bs + nr * 64 + ((cg ^ (nr & 7)) << 3));
      }
#pragma unroll
      for (int i = 0; i < 4; ++i)
#pragma unroll
        for (int j = 0; j < 4; ++j)
          acc[i][j] = __builtin_amdgcn_mfma_f32_16x16x32_bf16(af[i], bfv[j], acc[i][j], 0, 0, 0);
    }
  }

  float* Pout = P + (size_t)ks * pstride;
  const int fr = lane & 15, fq = lane >> 4;
#pragma unroll
  for (int j = 0; j < 4; ++j) {
    const int n = n0 + wc + (j << 4) + fr;
#pragma unroll
    for (int i = 0; i < 4; ++i)
#pragma unroll
      for (int r = 0; r < 4; ++r) {
        const int m = m0 + wr + (i << 4) + (fq << 2) + r;
        Pout[(size_t)m * ldc + n] = acc[i][j][r];
      }
  }
}

// ---------------------------------------------------------------------------
// Split-K reduce: C = sum_ks P[ks] + bias [, relu]
template<int RELU, int OF32, int OB16>
__global__ __launch_bounds__(256)
void reduce_kernel(const float* __restrict__ P, size_t pstride, int ksl,
                   const float* __restrict__ bias, float* __restrict__ Cf,
                   __hip_bfloat16* __restrict__ Cb, int N,
                   const int* __restrict__ cnt)
{
  const int row = blockIdx.y;
  if (cnt) { const int cp = (cnt[0] + 127) & ~127; if (row >= cp) return; }
  const int n = (blockIdx.x * 256 + threadIdx.x) * 4;
  if (n >= N) return;
  const size_t o = (size_t)row * N + n;
  const float4 b4 = *(const float4*)(bias + n);
  float4 s = *(const float4*)(P + o);
  for (int k = 1; k < ksl; ++k) {
    const float4 p = *(const float4*)(P + (size_t)k * pstride + o);
    s.x += p.x; s.y += p.y; s.z += p.z; s.w += p.w;
  }
  s.x += b4.x; s.y += b4.y; s.z += b4.z; s.w += b4.w;
  if (RELU) {
    s.x = fmaxf(s.x, 0.f); s.y = fmaxf(s.y, 0.f);
    s.z = fmaxf(s.z, 0.f); s.w = fmaxf(s.w, 0.f);
  }
  if (OF32) *(float4*)(Cf + o) = s;
  if (OB16) {
    union { short4v v; __hip_bfloat16 h[4]; } u;
    u.h[0] = __float2bfloat16(s.x);
    u.h[1] = __float2bfloat16(s.y);
    u.h[2] = __float2bfloat16(s.z);
    u.h[3] = __float2bfloat16(s.w);
    *(short4v*)(Cb + o) = u.v;
  }
}

// ---------------------------------------------------------------------------
// x -> xb bf16 single pass (convert + any-check together; always write)
__global__ __launch_bounds__(256)
void conv_x_kernel(const float* __restrict__ x, __hip_bfloat16* __restrict__ xb,
                   int* __restrict__ nz)
{
  __shared__ int sred[4];
  const int m = blockIdx.x;               // 0..ROWS
  const int t = threadIdx.x;
  __hip_bfloat16* dst = xb + (size_t)m * KPAD1;
  if (m == ROWS) {
    const __hip_bfloat162 z2 = {__float2bfloat16(0.f), __float2bfloat16(0.f)};
    for (int c = t; c < (KPAD1 >> 1); c += 256) *(__hip_bfloat162*)(dst + 2 * c) = z2;
    return;
  }
  const float* src = x + (size_t)m * FLATIN;
  int any = 0;
  for (int c = t; c < (KPAD1 >> 1); c += 256) {
    const int c0 = 2 * c;
    const float v0 = (c0 < FLATIN) ? src[c0] : 0.f;
    const float v1 = (c0 + 1 < FLATIN) ? src[c0 + 1] : 0.f;
    any |= (v0 != 0.f) | (v1 != 0.f);
    __hip_bfloat162 pr;
    pr.x = __float2bfloat16(v0);
    pr.y = __float2bfloat16(v1);
    *(__hip_bfloat162*)(dst + c0) = pr;
  }
  any = __any(any) ? 1 : 0;
  if ((t & 63) == 0) sred[t >> 6] = any;
  __syncthreads();
  if (t == 0) nz[m] = sred[0] | sred[1] | sred[2] | sred[3];
}

// Compaction + padding mask + decoder-KV bias concat (single block)
__global__ __launch_bounds__(256)
void compact_kernel(const int* __restrict__ nz, int* __restrict__ idx,
                    int* __restrict__ pos, int* __restrict__ cnt,
                    int* __restrict__ pad,
                    const float* __restrict__ dkvb, float* __restrict__ kvbias)
{
  __shared__ int wsum[4];
  __shared__ int total;
  const int t = threadIdx.x;
  int loc[13];
  int c = 0;
#pragma unroll
  for (int i = 0; i < 13; ++i) {
    const int m = t * 13 + i;
    loc[i] = (m < ROWS) ? nz[m] : 0;
    c += loc[i];
  }
  int v = c;
#pragma unroll
  for (int o = 1; o < 64; o <<= 1) {
    const int u = __shfl_up(v, o);
    if ((t & 63) >= o) v += u;
  }
  if ((t & 63) == 63) wsum[t >> 6] = v;
  __syncthreads();
  int wbase = 0;
  for (int w = 0; w < (t >> 6); ++w) wbase += wsum[w];
  int p = wbase + v - c;
#pragma unroll
  for (int i = 0; i < 13; ++i) {
    const int m = t * 13 + i;
    if (m < ROWS) {
      if (loc[i]) { idx[p] = m; pos[m] = p; ++p; }
      else pos[m] = -1;
    }
  }
  if (t == 255) total = p;
  __syncthreads();
  const int count = total;
  if (t == 0) cnt[0] = count + 1;
  for (int i = count + t; i < MPAD; i += 256) idx[i] = ROWS;
  for (int m = t; m < ROWS; m += 256) if (pos[m] < 0) pos[m] = count;
  if (t < 32) {
    int any = 0;
    for (int s = 99; s >= 0; --s) {
      any |= nz[t * 100 + s];
      pad[t * 100 + s] = (s > 0 && !any) ? 1 : 0;
    }
  }
#pragma unroll
  for (int i = t; i < 2048; i += 256) {
    const int L = i >> 10, j = i & 1023;
    kvbias[i] = dkvb[L * 1536 + 512 + j];
  }
}

// fc1 weight fp32 -> bf16 with column pad; one block per row, 8 elems/thread
__global__ __launch_bounds__(256)
void cvt_fc1_kernel(const float* __restrict__ in, __hip_bfloat16* __restrict__ out)
{
  const int r = blockIdx.x;               // 4096 rows
  const float* src = in + (size_t)r * FLATIN;
  __hip_bfloat16* dst = out + (size_t)r * KPAD1;
#pragma unroll
  for (int u = 0; u < KPAD1 / 2048; ++u) {
    const int c0 = u * 2048 + threadIdx.x * 8;
    union { short8 v; __hip_bfloat16 h[8]; } pk;
    if (c0 + 8 <= FLATIN) {
      const float4 a = *(const float4*)(src + c0);
      const float4 b = *(const float4*)(src + c0 + 4);
      pk.h[0] = __float2bfloat16(a.x); pk.h[1] = __float2bfloat16(a.y);
      pk.h[2] = __float2bfloat16(a.z); pk.h[3] = __float2bfloat16(a.w);
      pk.h[4] = __float2bfloat16(b.x); pk.h[5] = __float2bfloat16(b.y);
      pk.h[6] = __float2bfloat16(b.z); pk.h[7] = __float2bfloat16(b.w);
    } else {
#pragma unroll
      for (int i = 0; i < 8; ++i)
        pk.h[i] = __float2bfloat16((c0 + i < FLATIN) ? src[c0 + i] : 0.f);
    }
    *(short8*)(dst + c0) = pk.v;
  }
}

// Multi-segment flat fp32->bf16 (counts multiples of 2048)
struct CvtArgs {
  const float* src[8];
  __hip_bfloat16* dst[8];
  int cum[8];
};
__global__ __launch_bounds__(256)
void cvt_multi_kernel(CvtArgs a)
{
  const int bid = blockIdx.x;
  int seg = 0;
#pragma unroll
  for (int i = 1; i < 8; ++i) if (bid >= a.cum[i]) seg = i;
  const size_t e0 = ((size_t)(bid - a.cum[seg]) << 11) + (threadIdx.x << 3);
  const float4 v0 = *(const float4*)(a.src[seg] + e0);
  const float4 v1 = *(const float4*)(a.src[seg] + e0 + 4);
  union { short4v v; __hip_bfloat16 h[4]; } u0, u1;
  u0.h[0] = __float2bfloat16(v0.x); u0.h[1] = __float2bfloat16(v0.y);
  u0.h[2] = __float2bfloat16(v0.z); u0.h[3] = __float2bfloat16(v0.w);
  u1.h[0] = __float2bfloat16(v1.x); u1.h[1] = __float2bfloat16(v1.y);
  u1.h[2] = __float2bfloat16(v1.z); u1.h[3] = __float2bfloat16(v1.w);
  *(short4v*)(a.dst[seg] + e0) = u0.v;
  *(short4v*)(a.dst[seg] + e0 + 4) = u1.v;
}

// Multi-segment tiled fp32 transpose: dst[C][R] = src[R][C]^T ; 64x64 tiles.
struct TrArgs {
  const float* src[13];
  float* dst[13];
  int R[13], C[13], cum[13];
};
__global__ __launch_bounds__(256)
void transpose_kernel(TrArgs a)
{
  __shared__ float tbuf[64][65];
  const int bid = blockIdx.x;
  int seg = 0;
#pragma unroll
  for (int i = 1; i < 13; ++i) if (bid >= a.cum[i]) seg = i;
  const int local = bid - a.cum[seg];
  const int R = a.R[seg], C = a.C[seg];
  const int tilesC = C >> 6;
  const int r0 = (local / tilesC) << 6;
  const int c0 = (local % tilesC) << 6;
  const int tx = threadIdx.x & 63, ty = threadIdx.x >> 6;
  const float* s = a.src[seg];
  float* d = a.dst[seg];
#pragma unroll
  for (int i = 0; i < 16; ++i) {
    const int rr = (ty << 4) + i;
    tbuf[rr][tx] = s[(size_t)(r0 + rr) * C + c0 + tx];
  }
  __syncthreads();
#pragma unroll
  for (int i = 0; i < 16; ++i) {
    const int cc = (ty << 4) + i;
    d[(size_t)(c0 + cc) * R + r0 + tx] = tbuf[tx][cc];
  }
}

// fc3 reduce + bias + relu + scatter + inline PE
__global__ __launch_bounds__(256)
void scatter_pe_reduce(const float* __restrict__ P, size_t pstride, int ksl,
                       const int* __restrict__ pos, const float* __restrict__ bias,
                       float* __restrict__ hf, __hip_bfloat16* __restrict__ hb)
{
  const int m = blockIdx.x;
  const int s = m % 100, b = m / 100;
  const int src = pos[m];
  const int t = threadIdx.x;
  const size_t sb = (size_t)src * 512;
  const size_t db = (size_t)(s * 32 + b) * 512;
#pragma unroll
  for (int u = 0; u < 2; ++u) {
    const int d = t + u * 256;
    float v = bias[d];
    for (int k = 0; k < ksl; ++k) v += P[(size_t)k * pstride + sb + d];
    const float div = expf((float)(2 * (d >> 1)) * (-9.210340371976184f / 512.f));
    const float arg = (float)s * div;
    const float pe = (d & 1) ? cosf(arg) : sinf(arg);
    v = fmaxf(v, 0.f) + pe;
    hf[db + d] = v;
    hb[db + d] = __float2bfloat16(v);
  }
}

// ---------------------------------------------------------------------------
// LayerNorm over D=512 (+ optional second, final LN fused)
__global__ __launch_bounds__(256)
void ln_kernel(const float* __restrict__ x, const float* __restrict__ res,
               const float* __restrict__ g, const float* __restrict__ bta,
               const float* __restrict__ gf, const float* __restrict__ bf_,
               int dofinal, float* __restrict__ y, __hip_bfloat16* __restrict__ yb)
{
  __shared__ float rs[4], rss[4];
  const int row = blockIdx.x;
  const int t = threadIdx.x;
  const size_t base = (size_t)row * 512;
  float v0 = x[base + t];
  float v1 = x[base + t + 256];
  if (res) { v0 += res[base + t]; v1 += res[base + t + 256]; }
  float o0, o1;
#pragma unroll
  for (int pass = 0; pass < 2; ++pass) {
    float s = v0 + v1, ss = v0 * v0 + v1 * v1;
#pragma unroll
    for (int o = 32; o > 0; o >>= 1) { s += __shfl_xor(s, o); ss += __shfl_xor(ss, o); }
    if ((t & 63) == 0) { rs[t >> 6] = s; rss[t >> 6] = ss; }
    __syncthreads();
    s = rs[0] + rs[1] + rs[2] + rs[3];
    ss = rss[0] + rss[1] + rss[2] + rss[3];
    __syncthreads();
    const float mean = s * (1.f / 512.f);
    const float var = ss * (1.f / 512.f) - mean * mean;
    const float inv = rsqrtf(var + 1e-5f);
    const float* gg = (pass == 0) ? g : gf;
    const float* bb = (pass == 0) ? bta : bf_;
    o0 = (v0 - mean) * inv * gg[t] + bb[t];
    o1 = (v1 - mean) * inv * gg[t + 256] + bb[t + 256];
    if (pass == 1 || !dofinal) break;
    v0 = o0; v1 = o1;
  }
  if (y) {
    y[base + t] = o0;
    y[base + t + 256] = o1;
  }
  if (yb) {
    yb[base + t] = __float2bfloat16(o0);
    yb[base + t + 256] = __float2bfloat16(o1);
  }
}

// ---------------------------------------------------------------------------
// Encoder self-attention. grid (128 bh, 25 qg): 4 q's per block.
__global__ __launch_bounds__(256)
void enc_attn_kernel(const float* __restrict__ qkv, const int* __restrict__ pad,
                     __hip_bfloat16* __restrict__ ob)
{
  __shared__ float Ks[100][129];
  __shared__ float Qs[128];
  __shared__ float Ps[100];
  __shared__ float red[4];
  const int bh = blockIdx.x;
  const int b = bh >> 2, h = bh & 3;
  const int q0 = blockIdx.y * 4;
  const int t = threadIdx.x;
  for (int i = t; i < 12800; i += 256) {
    const int s = i >> 7, d = i & 127;
    Ks[s][d] = qkv[(size_t)(s * 32 + b) * 1536 + 512 + h * 128 + d];
  }
  const int masked = (t < 100) ? pad[b * 100 + t] : 0;
  const float scale = 0.08838834764831845f;
  for (int qi = 0; qi < 4; ++qi) {
    const int q = q0 + qi;
    __syncthreads();
    if (t < 128) Qs[t] = qkv[(size_t)(q * 32 + b) * 1536 + h * 128 + t];
    __syncthreads();
    float sc = -3e38f;
    if (t < 100) {
      const float* kr = &Ks[t][0];
      float a = 0.f;
#pragma unroll 16
      for (int d = 0; d < 128; ++d) a += Qs[d] * kr[d];
      sc = masked ? -1e9f : (a * scale);
    }
    float mx = sc;
#pragma unroll
    for (int o = 32; o > 0; o >>= 1) mx = fmaxf(mx, __shfl_xor(mx, o));
    if ((t & 63) == 0) red[t >> 6] = mx;
    __syncthreads();
    mx = fmaxf(fmaxf(red[0], red[1]), fmaxf(red[2], red[3]));
    const float e = (t < 100) ? expf(sc - mx) : 0.f;
    float sm = e;
#pragma unroll
    for (int o = 32; o > 0; o >>= 1) sm += __shfl_xor(sm, o);
    __syncthreads();
    if ((t & 63) == 0) red[t >> 6] = sm;
    __syncthreads();
    sm = red[0] + red[1] + red[2] + red[3];
    if (t < 100) Ps[t] = e;
    __syncthreads();
    if (t < 128) {
      float a = 0.f;
      const float* vb = qkv + 1024 + h * 128 + t;
      for (int k = 0; k < 100; ++k) a += Ps[k] * vb[(size_t)(k * 32 + b) * 1536];
      ob[(size_t)(q * 32 + b) * 512 + h * 128 + t] = __float2bfloat16(a / sm);
    }
  }
}

// ---------------------------------------------------------------------------
// Fused decoder layer: transposed-weight coalesced GEMVs. 512 thr, grid 32.
template<int N, int K, int RELU>
__device__ __forceinline__ void gemvT(int tid, const float* S,
                                      const float* __restrict__ WT,
                                      const float* __restrict__ bias,
                                      float* out, float* part)
{
  constexpr int NQ = N / 4;
  constexpr int G = 512 / NQ;
  constexpr int KP = K / G;
  const int p = tid % NQ;
  const int g = tid / NQ;
  const float4* wp = (const float4*)WT;
  float ax = 0.f, ay = 0.f, az = 0.f, aw = 0.f;
  const int kend = g * KP + KP;
#pragma unroll 8
  for (int k = g * KP; k < kend; ++k) {
    const float s = S[k];
    const float4 w = wp[(size_t)k * NQ + p];
    ax += s * w.x; ay += s * w.y; az += s * w.z; aw += s * w.w;
  }
  float4 a4 = {ax, ay, az, aw};
  *(float4*)(part + g * N + 4 * p) = a4;
  __syncthreads();
#pragma unroll
  for (int n = tid; n < N; n += 512) {
    float v = bias[n];
#pragma unroll
    for (int q = 0; q < G; ++q) v += part[q * N + n];
    if (RELU) v = fmaxf(v, 0.f);
    out[n] = v;
  }
  __syncthreads();
}

#define BLOCK_LN512(V, G, B, O)                                                 \
  {                                                                             \
    float s_ = (V), ss_ = (V) * (V);                                            \
    _Pragma("unroll")                                                           \
    for (int o_ = 32; o_ > 0; o_ >>= 1) {                                       \
      s_ += __shfl_xor(s_, o_); ss_ += __shfl_xor(ss_, o_);                     \
    }                                                                           \
    if ((tid & 63) == 0) { red[tid >> 6] = s_; red2[tid >> 6] = ss_; }          \
    __syncthreads();                                                            \
    s_ = 0.f; ss_ = 0.f;                                                        \
    _Pragma("unroll")                                                           \
    for (int w_ = 0; w_ < 8; ++w_) { s_ += red[w_]; ss_ += red2[w_]; }          \
    const float mean_ = s_ * (1.f / 512.f);                                     \
    const float inv_ = rsqrtf(ss_ * (1.f / 512.f) - mean_ * mean_ + 1e-5f);     \
    O = ((V) - mean_) * inv_ * (G)[tid] + (B)[tid];                             \
    __syncthreads();                                                            \
  }

__global__ __launch_bounds__(512)
void dec_layer(const float* __restrict__ tin,          // nullptr => ones
               const float* __restrict__ kvb,          // K at +0, V at +512
               int kvstride,
               const float* __restrict__ WvT, const float* __restrict__ bv,
               const float* __restrict__ WpT, const float* __restrict__ bp,
               const float* __restrict__ g1, const float* __restrict__ b1,
               const float* __restrict__ WqT, const float* __restrict__ bq,
               const float* __restrict__ WcpT, const float* __restrict__ bcp,
               const float* __restrict__ g2, const float* __restrict__ b2,
               const float* __restrict__ W1T, const float* __restrict__ b1f,
               const float* __restrict__ W2T, const float* __restrict__ b2f,
               const float* __restrict__ g3, const float* __restrict__ b3,
               const float* __restrict__ gf, const float* __restrict__ bf_,
               int dofinal, float* __restrict__ tout,
               const float* __restrict__ Wo1T, const float* __restrict__ ob1,
               __hip_bfloat16* __restrict__ o1b)
{
  __shared__ float Ts[512], Bs[512], Cs[512], F1[1024], part[2048];
  __shared__ float Ps[4][104];
  __shared__ float red[8], red2[8];
  const int r = blockIdx.x, tid = threadIdx.x;
  Ts[tid] = tin ? tin[r * 512 + tid] : 1.0f;
  __syncthreads();

  // self-attn (Sq=1: softmax over one key == 1 -> out = V(t))
  gemvT<512, 512, 0>(tid, Ts, WvT, bv, Bs, part);
  gemvT<512, 512, 0>(tid, Bs, WpT, bp, Cs, part);
  {
    const float rr = Cs[tid] + Ts[tid];
    float o;
    BLOCK_LN512(rr, g1, b1, o)
    Ts[tid] = o;                          // t1
  }
  __syncthreads();

  // cross-attn Q
  gemvT<512, 512, 0>(tid, Ts, WqT, bq, Bs, part);

  // cross-attention: wave h<4 handles head h; 100 keys, 2 per lane
  if (tid < 256) {
    const int h = tid >> 6, lane = tid & 63;
    const float scale = 0.08838834764831845f;
    const float* Qh = Bs + h * 128;
    float s0, s1 = -3e38f;
    {
      const float* kr = kvb + (size_t)(lane * 32 + r) * kvstride + h * 128;
      float a = 0.f;
#pragma unroll 16
      for (int d = 0; d < 128; ++d) a += Qh[d] * kr[d];
      s0 = a * scale;
    }
    if (lane + 64 < 100) {
      const float* kr = kvb + (size_t)((lane + 64) * 32 + r) * kvstride + h * 128;
      float a = 0.f;
#pragma unroll 16
      for (int d = 0; d < 128; ++d) a += Qh[d] * kr[d];
      s1 = a * scale;
    }
    float mx = fmaxf(s0, s1);
#pragma unroll
    for (int o = 32; o > 0; o >>= 1) mx = fmaxf(mx, __shfl_xor(mx, o));
    const float e0 = expf(s0 - mx);
    const float e1 = (lane + 64 < 100) ? expf(s1 - mx) : 0.f;
    float sm = e0 + e1;
#pragma unroll
    for (int o = 32; o > 0; o >>= 1) sm += __shfl_xor(sm, o);
    Ps[h][lane] = e0 / sm;
    if (lane + 64 < 100) Ps[h][lane + 64] = e1 / sm;
  }
  __syncthreads();
  if (tid < 256) {
    const int h = tid >> 6, lane = tid & 63;
#pragma unroll
    for (int u = 0; u < 2; ++u) {
      const int d = lane + u * 64;
      const float* vb = kvb + 512 + h * 128 + d;
      float a = 0.f;
      for (int k = 0; k < 100; ++k) a += Ps[h][k] * vb[(size_t)(k * 32 + r) * kvstride];
      Bs[h * 128 + d] = a;                // cav
    }
  }
  __syncthreads();

  // ca proj + residual + LN2
  gemvT<512, 512, 0>(tid, Bs, WcpT, bcp, Cs, part);
  {
    const float rr = Cs[tid] + Ts[tid];
    float o;
    BLOCK_LN512(rr, g2, b2, o)
    Ts[tid] = o;                          // t2
  }
  __syncthreads();

  // FF
  gemvT<1024, 512, 1>(tid, Ts, W1T, b1f, F1, part);
  gemvT<512, 1024, 0>(tid, F1, W2T, b2f, Cs, part);
  {
    const float rr = Cs[tid] + Ts[tid];
    float o;
    BLOCK_LN512(rr, g3, b3, o)
    if (dofinal) {
      float f;
      BLOCK_LN512(o, gf, bf_, f)
      o = f;
    }
    tout[r * 512 + tid] = o;
    if (dofinal) {
      Ts[tid] = o;
      __syncthreads();
      // fused out1: row r of C(32,2048) = relu(t @ Wo1T + b); 4 outputs/thread
      const float4* wp = (const float4*)Wo1T;   // [512][512 quads]
      float ax = 0.f, ay = 0.f, az = 0.f, aw = 0.f;
#pragma unroll 8
      for (int k = 0; k < 512; ++k) {
        const float s = Ts[k];
        const float4 w = wp[(size_t)k * 512 + tid];
        ax += s * w.x; ay += s * w.y; az += s * w.z; aw += s * w.w;
      }
      union { short4v v; __hip_bfloat16 h[4]; } u;
      u.h[0] = __float2bfloat16(fmaxf(ax + ob1[4 * tid], 0.f));
      u.h[1] = __float2bfloat16(fmaxf(ay + ob1[4 * tid + 1], 0.f));
      u.h[2] = __float2bfloat16(fmaxf(az + ob1[4 * tid + 2], 0.f));
      u.h[3] = __float2bfloat16(fmaxf(aw + ob1[4 * tid + 3], 0.f));
      *(short4v*)(o1b + (size_t)r * 2048 + 4 * tid) = u.v;
      const short4v z = {0, 0, 0, 0};
#pragma unroll
      for (int rr = r + 32; rr < 128; rr += 32)
        *(short4v*)(o1b + (size_t)rr * 2048 + 4 * tid) = z;
    }
  }
}

// ---------------------------------------------------------------------------
// out3 split-K reduce (+bias(+guard)+relu) fused with adaptive pool. grid 32.
__global__ __launch_bounds__(256)
void reduce_pool(const float* __restrict__ P, size_t pstride,
                 const float* __restrict__ bias, float* __restrict__ out)
{
  __shared__ float row[NOUT3];
  const int b = blockIdx.x, t = threadIdx.x;
  for (int n = t * 4; n < NOUT3; n += 1024) {
    const size_t o = (size_t)b * NOUT3 + n;
    float4 s = *(const float4*)(P + o);
#pragma unroll
    for (int k = 1; k < 4; ++k) {
      const float4 p = *(const float4*)(P + (size_t)k * pstride + o);
      s.x += p.x; s.y += p.y; s.z += p.z; s.w += p.w;
    }
    row[n]     = fmaxf(s.x + ((n     < FLATIN) ? bias[n]     : 0.f), 0.f);
    row[n + 1] = fmaxf(s.y + ((n + 1 < FLATIN) ? bias[n + 1] : 0.f), 0.f);
    row[n + 2] = fmaxf(s.z + ((n + 2 < FLATIN) ? bias[n + 2] : 0.f), 0.f);
    row[n + 3] = fmaxf(s.w + ((n + 3 < FLATIN) ? bias[n + 3] : 0.f), 0.f);
  }
  __syncthreads();
  for (int i = t; i < 135 * 103; i += 256) {
    const int j = i % 103, r = i / 103;
    const int rs = (r * 143) / 135, re = ((r + 1) * 143 + 134) / 135;
    const int cs = (j * 111) / 103, ce = ((j + 1) * 111 + 102) / 103;
    float s = 0.f;
    for (int rr = rs; rr < re; ++rr)
      for (int cc = cs; cc < ce; ++cc)
        s += row[rr * 111 + cc];
    out[(size_t)b * (135 * 103) + i] = s / (float)((re - rs) * (ce - cs));
  }
}

// ---------------------------------------------------------------------------
extern "C" void kernel_launch(void* const* d_in, const int* in_sizes, int n_in,
                              void* d_out, int out_size, void* d_ws, size_t ws_size,
                              hipStream_t stream)
{
  (void)in_sizes; (void)n_in; (void)out_size; (void)ws_size;

  const float* x          = (const float*)d_in[0];
  const float* fc1_w      = (const float*)d_in[1];
  const float* fc1_b      = (const float*)d_in[2];
  const float* fc2_w      = (const float*)d_in[3];
  const float* fc2_b      = (const float*)d_in[4];
  const float* fc3_w      = (const float*)d_in[5];
  const float* fc3_b      = (const float*)d_in[6];
  const float* out1_w     = (const float*)d_in[7];
  const float* out1_b     = (const float*)d_in[8];
  const float* out2_w     = (const float*)d_in[9];
  const float* out2_b     = (const float*)d_in[10];
  const float* out3_w     = (const float*)d_in[11];
  const float* out3_b     = (const float*)d_in[12];
  const float* enc_qkv_w  = (const float*)d_in[13];
  const float* enc_qkv_b  = (const float*)d_in[14];
  const float* enc_proj_w = (const float*)d_in[15];
  const float* enc_proj_b = (const float*)d_in[16];
  const float* enc_ff1_w  = (const float*)d_in[17];
  const float* enc_ff1_b  = (const float*)d_in[18];
  const float* enc_ff2_w  = (const float*)d_in[19];
  const float* enc_ff2_b  = (const float*)d_in[20];
  const float* enc_ln1_g  = (const float*)d_in[21];
  const float* enc_ln1_b  = (const float*)d_in[22];
  const float* enc_ln2_g  = (const float*)d_in[23];
  const float* enc_ln2_b  = (const float*)d_in[24];
  const float* enc_lnf_g  = (const float*)d_in[25];
  const float* enc_lnf_b  = (const float*)d_in[26];
  const float* dec_sa_qkv_w  = (const float*)d_in[27];
  const float* dec_sa_qkv_b  = (const float*)d_in[28];
  const float* dec_sa_proj_w = (const float*)d_in[29];
  const float* dec_sa_proj_b = (const float*)d_in[30];
  const float* dec_ca_qkv_w  = (const float*)d_in[31];
  const float* dec_ca_qkv_b  = (const float*)d_in[32];
  const float* dec_ca_proj_w = (const float*)d_in[33];
  const float* dec_ca_proj_b = (const float*)d_in[34];
  const float* dec_ff1_w  = (const float*)d_in[35];
  const float* dec_ff1_b  = (const float*)d_in[36];
  const float* dec_ff2_w  = (const float*)d_in[37];
  const float* dec_ff2_b  = (const float*)d_in[38];
  const float* dec_ln1_g  = (const float*)d_in[39];
  const float* dec_ln1_b  = (const float*)d_in[40];
  const float* dec_ln2_g  = (const float*)d_in[41];
  const float* dec_ln2_b  = (const float*)d_in[42];
  const float* dec_ln3_g  = (const float*)d_in[43];
  const float* dec_ln3_b  = (const float*)d_in[44];
  const float* dec_lnf_g  = (const float*)d_in[45];
  const float* dec_lnf_b  = (const float*)d_in[46];

  char* wsp = (char*)d_ws;
  size_t off = 0;
  auto alloc = [&](size_t nbytes) -> char* {
    char* p = wsp + off;
    off += (nbytes + 255) & ~(size_t)255;
    return p;
  };

  __hip_bfloat16* xb     = (__hip_bfloat16*)alloc((size_t)MPAD * KPAD1 * 2);
  __hip_bfloat16* Wb1    = (__hip_bfloat16*)alloc((size_t)4096 * KPAD1 * 2);
  __hip_bfloat16* Wb2    = (__hip_bfloat16*)alloc((size_t)2048 * 4096 * 2);
  __hip_bfloat16* Wb3    = (__hip_bfloat16*)alloc((size_t)512 * 2048 * 2);
  __hip_bfloat16* Wqkvb  = (__hip_bfloat16*)alloc((size_t)2 * 1536 * 512 * 2);
  __hip_bfloat16* Wprojb = (__hip_bfloat16*)alloc((size_t)2 * 512 * 512 * 2);
  __hip_bfloat16* Wff1b  = (__hip_bfloat16*)alloc((size_t)2 * 1024 * 512 * 2);
  __hip_bfloat16* Wff2b  = (__hip_bfloat16*)alloc((size_t)2 * 512 * 1024 * 2);
  __hip_bfloat16* Wkv2b  = (__hip_bfloat16*)alloc((size_t)2048 * 512 * 2);
  int*   nz      = (int*)alloc(ROWS * 4);
  int*   padmask = (int*)alloc(ROWS * 4);
  int*   idx     = (int*)alloc(MPAD * 4);
  int*   pos     = (int*)alloc(ROWS * 4);
  int*   cnt     = (int*)alloc(256);
  float* kvbias  = (float*)alloc(2048 * 4);
  __hip_bfloat16* h1c = (__hip_bfloat16*)alloc((size_t)MPAD * 4096 * 2);
  __hip_bfloat16* h2c = (__hip_bfloat16*)alloc((size_t)MPAD * 2048 * 2);
  float* hf  = (float*)alloc((size_t)ROWS * 512 * 4);
  __hip_bfloat16* hb = (__hip_bfloat16*)alloc((size_t)ROWS * 512 * 2);
  float* qkvbuf = (float*)alloc((size_t)ROWS * 1536 * 4);
  __hip_bfloat16* attnb = (__hip_bfloat16*)alloc((size_t)ROWS * 512 * 2);
  float* pjf  = (float*)alloc((size_t)ROWS * 512 * 4);
  __hip_bfloat16* f1b = (__hip_bfloat16*)alloc((size_t)ROWS * 1024 * 2);
  float* f2f  = (float*)alloc((size_t)ROWS * 512 * 4);
  __hip_bfloat16* memb = (__hip_bfloat16*)alloc((size_t)ROWS * 512 * 2);
  float* kv01 = (float*)alloc((size_t)ROWS * 2048 * 4);
  float* tbuf = (float*)alloc(32 * 512 * 4);
  // transposed fp32 weights (decoder + out1)
  float* WvT[2]  = { (float*)alloc(512 * 512 * 4), (float*)alloc(512 * 512 * 4) };
  float* WpT[2]  = { (float*)alloc(512 * 512 * 4), (float*)alloc(512 * 512 * 4) };
  float* WqT[2]  = { (float*)alloc(512 * 512 * 4), (float*)alloc(512 * 512 * 4) };
  float* WcpT[2] = { (float*)alloc(512 * 512 * 4), (float*)alloc(512 * 512 * 4) };
  float* W1T[2]  = { (float*)alloc(512 * 1024 * 4), (float*)alloc(512 * 1024 * 4) };
  float* W2T[2]  = { (float*)alloc(1024 * 512 * 4), (float*)alloc(1024 * 512 * 4) };
  float* Wo1T    = (float*)alloc((size_t)512 * 2048 * 4);
  // split-K partial buffers (time-shared)
  float* fcP  = (float*)alloc((size_t)4 * MPAD * 4096 * 4);   // 218 MB
  float* encP = (float*)alloc((size_t)2 * ROWS * 1536 * 4);   // aliases

  // phase-4 aliases
  float* outP = fcP;                                           // <=33 MB
  __hip_bfloat16* o1b  = (__hip_bfloat16*)((char*)encP + ((size_t)20 << 20));
  __hip_bfloat16* o2b  = (__hip_bfloat16*)((char*)encP + ((size_t)22 << 20));

  const size_t psF1 = (size_t)MPAD * 4096;
  const size_t psF2 = (size_t)MPAD * 2048;
  const size_t psF3 = (size_t)MPAD * 512;

  // ---- phase 0 ----
  conv_x_kernel<<<ROWS + 1, 256, 0, stream>>>(x, xb, nz);
  compact_kernel<<<1, 256, 0, stream>>>(nz, idx, pos, cnt, padmask,
                                        dec_ca_qkv_b, kvbias);
  {
    CvtArgs a;
    const float* srcs[8] = { enc_qkv_w, enc_proj_w, enc_ff1_w, enc_ff2_w,
                             dec_ca_qkv_w + (size_t)512 * 512,
                             dec_ca_qkv_w + (size_t)(1536 + 512) * 512,
                             fc2_w, fc3_w };
    __hip_bfloat16* dsts[8] = { Wqkvb, Wprojb, Wff1b, Wff2b,
                                Wkv2b, Wkv2b + (size_t)1024 * 512,
                                Wb2, Wb3 };
    const int counts[8] = { 2*1536*512, 2*512*512, 2*1024*512, 2*512*1024,
                            1024*512, 1024*512, 2048*4096, 512*2048 };
    int c = 0;
    for (int i = 0; i < 8; ++i) { a.src[i] = srcs[i]; a.dst[i] = dsts[i];
                                  a.cum[i] = c; c += counts[i] >> 11; }
    cvt_multi_kernel<<<c, 256, 0, stream>>>(a);
  }
  cvt_fc1_kernel<<<4096, 256, 0, stream>>>(fc1_w, Wb1);
  {
    TrArgs a;
    const float* srcs[13];
    float* dsts[13];
    int R[13], C[13];
    int n = 0;
    for (int L = 0; L < 2; ++L) {
      srcs[n] = dec_sa_qkv_w + (size_t)L * 1536 * 512 + (size_t)1024 * 512;
      dsts[n] = WvT[L]; R[n] = 512; C[n] = 512; ++n;
      srcs[n] = dec_sa_proj_w + (size_t)L * 512 * 512;
      dsts[n] = WpT[L]; R[n] = 512; C[n] = 512; ++n;
      srcs[n] = dec_ca_qkv_w + (size_t)L * 1536 * 512;
      dsts[n] = WqT[L]; R[n] = 512; C[n] = 512; ++n;
      srcs[n] = dec_ca_proj_w + (size_t)L * 512 * 512;
      dsts[n] = WcpT[L]; R[n] = 512; C[n] = 512; ++n;
      srcs[n] = dec_ff1_w + (size_t)L * 1024 * 512;
      dsts[n] = W1T[L]; R[n] = 1024; C[n] = 512; ++n;
      srcs[n] = dec_ff2_w + (size_t)L * 512 * 1024;
      dsts[n] = W2T[L]; R[n] = 512; C[n] = 1024; ++n;
    }
    srcs[n] = out1_w; dsts[n] = Wo1T; R[n] = 2048; C[n] = 512; ++n;
    int c = 0;
    for (int i = 0; i < 13; ++i) {
      a.src[i] = srcs[i]; a.dst[i] = dsts[i]; a.R[i] = R[i]; a.C[i] = C[i];
      a.cum[i] = c; c += (R[i] >> 6) * (C[i] >> 6);
    }
    transpose_kernel<<<c, 256, 0, stream>>>(a);
  }

  // ---- phase 1: input MLP (split-K) ----
  gemm_bf16<1><<<26 * 32 * 2, 256, 0, stream>>>(xb, Wb1, idx, cnt, fcP,
      KPAD1, 4096, 26, 2, psF1);
  reduce_kernel<1, 0, 1><<<dim3(4, MPAD), 256, 0, stream>>>(fcP, psF1, 2,
      fc1_b, nullptr, h1c, 4096, cnt);
  gemm_bf16<0><<<26 * 16 * 4, 256, 0, stream>>>(h1c, Wb2, nullptr, cnt, fcP,
      4096, 2048, 26, 4, psF2);
  reduce_kernel<1, 0, 1><<<dim3(2, MPAD), 256, 0, stream>>>(fcP, psF2, 4,
      fc2_b, nullptr, h2c, 2048, cnt);
  gemm_bf16<0><<<26 * 4 * 4, 256, 0, stream>>>(h2c, Wb3, nullptr, cnt, fcP,
      2048, 512, 26, 4, psF3);
  scatter_pe_reduce<<<ROWS, 256, 0, stream>>>(fcP, psF3, 4, pos, fc3_b, hf, hb);

  // ---- phase 2: encoder ----
  for (int L = 0; L < 2; ++L) {
    gemm_direct<0, 1, 0><<<25 * 12, 256, 0, stream>>>(hb, Wqkvb + (size_t)L * 1536 * 512,
        enc_qkv_b + L * 1536, qkvbuf, nullptr, 512, 1536, 25);
    enc_attn_kernel<<<dim3(128, 25), 256, 0, stream>>>(qkvbuf, padmask, attnb);
    gemm_direct<0, 1, 0><<<25 * 4, 256, 0, stream>>>(attnb, Wprojb + (size_t)L * 512 * 512,
        enc_proj_b + L * 512, pjf, nullptr, 512, 512, 25);
    ln_kernel<<<ROWS, 256, 0, stream>>>(hf, pjf, enc_ln1_g + L * 512, enc_ln1_b + L * 512,
        nullptr, nullptr, 0, hf, hb);
    gemm_direct<1, 0, 1><<<25 * 8, 256, 0, stream>>>(hb, Wff1b + (size_t)L * 1024 * 512,
        enc_ff1_b + L * 1024, nullptr, f1b, 512, 1024, 25);
    gemm_direct<0, 1, 0><<<25 * 4, 256, 0, stream>>>(f1b, Wff2b + (size_t)L * 512 * 1024,
        enc_ff2_b + L * 512, f2f, nullptr, 1024, 512, 25);
    if (L == 0) {
      ln_kernel<<<ROWS, 256, 0, stream>>>(hf, f2f, enc_ln2_g, enc_ln2_b,
          nullptr, nullptr, 0, hf, hb);
    } else {
      ln_kernel<<<ROWS, 256, 0, stream>>>(hf, f2f, enc_ln2_g + 512, enc_ln2_b + 512,
          enc_lnf_g, enc_lnf_b, 1, nullptr, memb);
    }
  }

  // ---- decoder KV (both layers, one GEMM) ----
  gemm_direct<0, 1, 0><<<25 * 16, 256, 0, stream>>>(memb, Wkv2b, kvbias,
      kv01, nullptr, 512, 2048, 25);

  // ---- phase 3: fused decoder layers (+ out1 fused into L1) ----
  for (int L = 0; L < 2; ++L) {
    dec_layer<<<32, 512, 0, stream>>>(
        (L == 0) ? nullptr : tbuf,
        kv01 + (size_t)L * 1024, 2048,
        WvT[L], dec_sa_qkv_b + L * 1536 + 1024,
        WpT[L], dec_sa_proj_b + L * 512,
        dec_ln1_g + L * 512, dec_ln1_b + L * 512,
        WqT[L], dec_ca_qkv_b + L * 1536,
        WcpT[L], dec_ca_proj_b + L * 512,
        dec_ln2_g + L * 512, dec_ln2_b + L * 512,
        W1T[L], dec_ff1_b + L * 1024,
        W2T[L], dec_ff2_b + L * 512,
        dec_ln3_g + L * 512, dec_ln3_b + L * 512,
        dec_lnf_g, dec_lnf_b, (L == 1) ? 1 : 0, tbuf,
        Wo1T, out1_b, o1b);
  }

  // ---- phase 4: output MLP (fp32-weight GEMMs, conversion fused) ----
  gemm_w32<<<32 * 4, 256, 0, stream>>>(o1b, out2_w, outP,
      2048, 4096, 4, (size_t)128 * 4096, 4096);
  reduce_kernel<1, 0, 1><<<dim3(4, 128), 256, 0, stream>>>(outP, (size_t)128 * 4096, 4,
      out2_b, nullptr, o2b, 4096, nullptr);
  gemm_w32<<<125 * 4, 256, 0, stream>>>(o2b, out3_w, outP,
      4096, NOUT3, 4, (size_t)128 * NOUT3, FLATIN);
  reduce_pool<<<32, 256, 0, stream>>>(outP, (size_t)128 * NOUT3, out3_b, (float*)d_out);
}

// Round 15
// 1388.925 us; speedup vs baseline: 1.2712x; 1.0041x over previous
//
#include <hip/hip_runtime.h>
#include <hip/hip_bf16.h>

// ---------------------------------------------------------------------------
#define SEQ   100
#define BATCH 32
#define FLATIN 15873
#define KPAD1  16384
#define ROWS   3200
#define MPAD   3328
#define NOUT3  16000

typedef __attribute__((ext_vector_type(8))) short short8;
typedef __attribute__((ext_vector_type(4))) short short4v;
typedef __attribute__((ext_vector_type(4))) float f32x4;
typedef __hip_bfloat16 bf16;

__device__ __forceinline__ void gload_lds16(const void* g, void* l) {
  __builtin_amdgcn_global_load_lds((const __attribute__((address_space(1))) void*)g,
                                   (__attribute__((address_space(3))) void*)l, 16, 0, 0);
}

// bijective XCD chunk swizzle (m204)
__device__ __forceinline__ int xcd_swizzle(int id, int nwg) {
  const int q = nwg >> 3, r = nwg & 7;
  const int x = id & 7, p = id >> 3;
  return (x < r ? x * (q + 1) : r * (q + 1) + (x - r) * q) + p;
}

// ---------------------------------------------------------------------------
// Shared GEMM body: stage 128x64 A/B tiles (both-sides chunk swizzle), MFMA.
#define GEMM_BODY(KBEG, KEND)                                                   \
  const int tid  = threadIdx.x;                                                 \
  const int lane = tid & 63;                                                    \
  const int wid  = tid >> 6;                                                    \
  const int wr = (wid >> 1) << 6;                                               \
  const int wc = (wid & 1) << 6;                                                \
  f32x4 acc[4][4];                                                              \
  _Pragma("unroll") for (int i = 0; i < 4; ++i)                                 \
  _Pragma("unroll") for (int j = 0; j < 4; ++j)                                 \
      acc[i][j] = (f32x4){0.f, 0.f, 0.f, 0.f};                                  \
  const int srow = (wid << 3) + (lane >> 3);                                    \
  const int scs  = lane & 7;                                                    \
  const int gcol = ((scs ^ (srow & 7)) << 3);                                   \
  const bf16* arow[4];                                                          \
  const bf16* brow[4];                                                          \
  _Pragma("unroll") for (int j = 0; j < 4; ++j) {                               \
    const int row = (j << 5) + srow;                                            \
    const int gr = GATHER ? idx[m0 + row] : (m0 + row);                         \
    arow[j] = A + (size_t)gr * K + gcol;                                        \
    brow[j] = W + (size_t)(n0 + row) * K + gcol;                                \
  }                                                                             \
  for (int k0 = (KBEG); k0 < (KEND); k0 += 64) {                                \
    __syncthreads();                                                            \
    _Pragma("unroll") for (int j = 0; j < 4; ++j) {                             \
      short* la = As + (((j << 2) + wid) << 9);                                 \
      short* lb = Bs + (((j << 2) + wid) << 9);                                 \
      gload_lds16(arow[j] + k0, la);                                            \
      gload_lds16(brow[j] + k0, lb);                                            \
    }                                                                           \
    __syncthreads();                                                            \
    _Pragma("unroll") for (int kk = 0; kk < 2; ++kk) {                          \
      short8 af[4], bfv[4];                                                     \
      _Pragma("unroll") for (int i = 0; i < 4; ++i) {                           \
        const int mr = wr + (i << 4) + (lane & 15);                             \
        const int cg = (kk << 2) + (lane >> 4);                                 \
        af[i]  = *(const short8*)(As + mr * 64 + ((cg ^ (mr & 7)) << 3));       \
        const int nr = wc + (i << 4) + (lane & 15);                             \
        bfv[i] = *(const short8*)(Bs + nr * 64 + ((cg ^ (nr & 7)) << 3));       \
      }                                                                         \
      _Pragma("unroll") for (int i = 0; i < 4; ++i)                             \
      _Pragma("unroll") for (int j = 0; j < 4; ++j)                             \
          acc[i][j] = __builtin_amdgcn_mfma_f32_16x16x32_bf16(af[i], bfv[j],    \
                                                              acc[i][j], 0,0,0);\
    }                                                                           \
  }

// Split-K partial-output GEMM. mt-minor linearization.
template<int GATHER>
__global__ __launch_bounds__(256)
void gemm_bf16(const bf16* __restrict__ A, const bf16* __restrict__ W,
               const int* __restrict__ idx, const int* __restrict__ cnt,
               float* __restrict__ P,
               int K, int ldc, int mtiles, int ksl, size_t pstride)
{
  __shared__ __align__(16) short lds[16384];
  short* As = lds;
  short* Bs = lds + 8192;
  const int wg = xcd_swizzle(blockIdx.x, gridDim.x);
  const int mt = wg % mtiles;
  const int g  = wg / mtiles;
  const int nt = g / ksl;
  const int ks = g % ksl;
  const int m0 = mt << 7;
  const int n0 = nt << 7;
  if (cnt && m0 >= cnt[0]) return;
  const int Klen = K / ksl;
  const int kbeg = ks * Klen;

  GEMM_BODY(kbeg, kbeg + Klen)

  float* Pout = P + (size_t)ks * pstride;
  const int fr = lane & 15, fq = lane >> 4;
#pragma unroll
  for (int j = 0; j < 4; ++j) {
    const int n = n0 + wc + (j << 4) + fr;
#pragma unroll
    for (int i = 0; i < 4; ++i)
#pragma unroll
      for (int r = 0; r < 4; ++r) {
        const int m = m0 + wr + (i << 4) + (fq << 2) + r;
        Pout[(size_t)m * ldc + n] = acc[i][j][r];
      }
  }
}

// Direct GEMM with fused bias/relu epilogue
template<int RELU, int OF32, int OB16>
__global__ __launch_bounds__(256)
void gemm_direct(const bf16* __restrict__ A, const bf16* __restrict__ W,
                 const float* __restrict__ bias, float* __restrict__ Cf,
                 bf16* __restrict__ Cb, int K, int ldc, int mtiles)
{
  __shared__ __align__(16) short lds[16384];
  short* As = lds;
  short* Bs = lds + 8192;
  const int GATHER = 0;
  const int* idx = nullptr;
  const int wg = xcd_swizzle(blockIdx.x, gridDim.x);
  const int m0 = (wg % mtiles) << 7;
  const int n0 = (wg / mtiles) << 7;

  GEMM_BODY(0, K)

  const int fr = lane & 15, fq = lane >> 4;
#pragma unroll
  for (int j = 0; j < 4; ++j) {
    const int n = n0 + wc + (j << 4) + fr;
    const float bb = bias[n];
#pragma unroll
    for (int i = 0; i < 4; ++i)
#pragma unroll
      for (int r = 0; r < 4; ++r) {
        const int m = m0 + wr + (i << 4) + (fq << 2) + r;
        float v = acc[i][j][r] + bb;
        if (RELU) v = fmaxf(v, 0.f);
        if (OF32) Cf[(size_t)m * ldc + n] = v;
        if (OB16) Cb[(size_t)m * ldc + n] = __float2bfloat16(v);
      }
  }
}

// ---------------------------------------------------------------------------
// Split-K GEMM with fp32 B-side (conversion fused into staging; rule #21:
// inverse-swizzled write + swizzled read). B rows clamped to wrows-1.
__global__ __launch_bounds__(256)
void gemm_w32(const bf16* __restrict__ A, const float* __restrict__ W32,
              float* __restrict__ P, int K, int ldc, int ksl, size_t pstride,
              int wrows)
{
  __shared__ __align__(16) short lds[16384];
  short* As = lds;
  short* Bs = lds + 8192;
  const int wg = xcd_swizzle(blockIdx.x, gridDim.x);
  const int nt = wg / ksl;
  const int ks = wg % ksl;
  const int m0 = 0;
  const int n0 = nt << 7;
  const int Klen = K / ksl;
  const int kbeg = ks * Klen;
  const int kend = kbeg + Klen;

  const int tid  = threadIdx.x;
  const int lane = tid & 63;
  const int wid  = tid >> 6;
  const int wr = (wid >> 1) << 6;
  const int wc = (wid & 1) << 6;

  f32x4 acc[4][4];
#pragma unroll
  for (int i = 0; i < 4; ++i)
#pragma unroll
    for (int j = 0; j < 4; ++j) acc[i][j] = (f32x4){0.f, 0.f, 0.f, 0.f};

  const int srow = (wid << 3) + (lane >> 3);
  const int scs  = lane & 7;
  const int gcol = ((scs ^ (srow & 7)) << 3);

  const bf16* arow[4];
#pragma unroll
  for (int j = 0; j < 4; ++j)
    arow[j] = A + (size_t)(m0 + (j << 5) + srow) * K + gcol;

  const float* wsrc[4];
  int bslot[4];
#pragma unroll
  for (int i = 0; i < 4; ++i) {
    const int q = (i << 8) + tid;
    const int row = q >> 3, c = q & 7;
    const int wrow = min(n0 + row, wrows - 1);
    wsrc[i] = W32 + (size_t)wrow * K + (c << 3);
    bslot[i] = row * 64 + ((c ^ (row & 7)) << 3);
  }

  for (int k0 = kbeg; k0 < kend; k0 += 64) {
    __syncthreads();
#pragma unroll
    for (int j = 0; j < 4; ++j)
      gload_lds16(arow[j] + k0, As + (((j << 2) + wid) << 9));
#pragma unroll
    for (int i = 0; i < 4; ++i) {
      const float4 w0 = *(const float4*)(wsrc[i] + k0);
      const float4 w1 = *(const float4*)(wsrc[i] + k0 + 4);
      union { short8 v; bf16 h[8]; } pk;
      pk.h[0] = __float2bfloat16(w0.x); pk.h[1] = __float2bfloat16(w0.y);
      pk.h[2] = __float2bfloat16(w0.z); pk.h[3] = __float2bfloat16(w0.w);
      pk.h[4] = __float2bfloat16(w1.x); pk.h[5] = __float2bfloat16(w1.y);
      pk.h[6] = __float2bfloat16(w1.z); pk.h[7] = __float2bfloat16(w1.w);
      *(short8*)(Bs + bslot[i]) = pk.v;
    }
    __syncthreads();
#pragma unroll
    for (int kk = 0; kk < 2; ++kk) {
      short8 af[4], bfv[4];
#pragma unroll
      for (int i = 0; i < 4; ++i) {
        const int mr = wr + (i << 4) + (lane & 15);
        const int cg = (kk << 2) + (lane >> 4);
        af[i]  = *(const short8*)(As + mr * 64 + ((cg ^ (mr & 7)) << 3));
        const int nr = wc + (i << 4) + (lane & 15);
        bfv[i] = *(const short8*)(Bs + nr * 64 + ((cg ^ (nr & 7)) << 3));
      }
#pragma unroll
      for (int i = 0; i < 4; ++i)
#pragma unroll
        for (int j = 0; j < 4; ++j)
          acc[i][j] = __builtin_amdgcn_mfma_f32_16x16x32_bf16(af[i], bfv[j], acc[i][j], 0, 0, 0);
    }
  }

  float* Pout = P + (size_t)ks * pstride;
  const int fr = lane & 15, fq = lane >> 4;
#pragma unroll
  for (int j = 0; j < 4; ++j) {
    const int n = n0 + wc + (j << 4) + fr;
#pragma unroll
    for (int i = 0; i < 4; ++i)
#pragma unroll
      for (int r = 0; r < 4; ++r) {
        const int m = m0 + wr + (i << 4) + (fq << 2) + r;
        Pout[(size_t)m * ldc + n] = acc[i][j][r];
      }
  }
}

// ---------------------------------------------------------------------------
// Split-K reduce: C = sum_ks P[ks] + bias [, relu]
template<int RELU, int OF32, int OB16>
__global__ __launch_bounds__(256)
void reduce_kernel(const float* __restrict__ P, size_t pstride, int ksl,
                   const float* __restrict__ bias, float* __restrict__ Cf,
                   bf16* __restrict__ Cb, int N, const int* __restrict__ cnt)
{
  const int row = blockIdx.y;
  if (cnt) { const int cp = (cnt[0] + 127) & ~127; if (row >= cp) return; }
  const int n = (blockIdx.x * 256 + threadIdx.x) * 4;
  if (n >= N) return;
  const size_t o = (size_t)row * N + n;
  const float4 b4 = *(const float4*)(bias + n);
  float4 s = *(const float4*)(P + o);
  for (int k = 1; k < ksl; ++k) {
    const float4 p = *(const float4*)(P + (size_t)k * pstride + o);
    s.x += p.x; s.y += p.y; s.z += p.z; s.w += p.w;
  }
  s.x += b4.x; s.y += b4.y; s.z += b4.z; s.w += b4.w;
  if (RELU) {
    s.x = fmaxf(s.x, 0.f); s.y = fmaxf(s.y, 0.f);
    s.z = fmaxf(s.z, 0.f); s.w = fmaxf(s.w, 0.f);
  }
  if (OF32) *(float4*)(Cf + o) = s;
  if (OB16) {
    union { short4v v; bf16 h[4]; } u;
    u.h[0] = __float2bfloat16(s.x);
    u.h[1] = __float2bfloat16(s.y);
    u.h[2] = __float2bfloat16(s.z);
    u.h[3] = __float2bfloat16(s.w);
    *(short4v*)(Cb + o) = u.v;
  }
}

// ---------------------------------------------------------------------------
// x -> xb bf16 single pass (convert + any-check together; always write)
__global__ __launch_bounds__(256)
void conv_x_kernel(const float* __restrict__ x, bf16* __restrict__ xb,
                   int* __restrict__ nz)
{
  __shared__ int sred[4];
  const int m = blockIdx.x;               // 0..ROWS
  const int t = threadIdx.x;
  bf16* dst = xb + (size_t)m * KPAD1;
  if (m == ROWS) {
    const __hip_bfloat162 z2 = {__float2bfloat16(0.f), __float2bfloat16(0.f)};
    for (int c = t; c < (KPAD1 >> 1); c += 256) *(__hip_bfloat162*)(dst + 2 * c) = z2;
    return;
  }
  const float* src = x + (size_t)m * FLATIN;
  int any = 0;
  for (int c = t; c < (KPAD1 >> 1); c += 256) {
    const int c0 = 2 * c;
    const float v0 = (c0 < FLATIN) ? src[c0] : 0.f;
    const float v1 = (c0 + 1 < FLATIN) ? src[c0 + 1] : 0.f;
    any |= (v0 != 0.f) | (v1 != 0.f);
    __hip_bfloat162 pr;
    pr.x = __float2bfloat16(v0);
    pr.y = __float2bfloat16(v1);
    *(__hip_bfloat162*)(dst + c0) = pr;
  }
  any = __any(any) ? 1 : 0;
  if ((t & 63) == 0) sred[t >> 6] = any;
  __syncthreads();
  if (t == 0) nz[m] = sred[0] | sred[1] | sred[2] | sred[3];
}

// Compaction + padding mask + decoder-KV bias concat (single block)
__global__ __launch_bounds__(256)
void compact_kernel(const int* __restrict__ nz, int* __restrict__ idx,
                    int* __restrict__ pos, int* __restrict__ cnt,
                    int* __restrict__ pad,
                    const float* __restrict__ dkvb, float* __restrict__ kvbias)
{
  __shared__ int wsum[4];
  __shared__ int total;
  const int t = threadIdx.x;
  int loc[13];
  int c = 0;
#pragma unroll
  for (int i = 0; i < 13; ++i) {
    const int m = t * 13 + i;
    loc[i] = (m < ROWS) ? nz[m] : 0;
    c += loc[i];
  }
  int v = c;
#pragma unroll
  for (int o = 1; o < 64; o <<= 1) {
    const int u = __shfl_up(v, o);
    if ((t & 63) >= o) v += u;
  }
  if ((t & 63) == 63) wsum[t >> 6] = v;
  __syncthreads();
  int wbase = 0;
  for (int w = 0; w < (t >> 6); ++w) wbase += wsum[w];
  int p = wbase + v - c;
#pragma unroll
  for (int i = 0; i < 13; ++i) {
    const int m = t * 13 + i;
    if (m < ROWS) {
      if (loc[i]) { idx[p] = m; pos[m] = p; ++p; }
      else pos[m] = -1;
    }
  }
  if (t == 255) total = p;
  __syncthreads();
  const int count = total;
  if (t == 0) cnt[0] = count + 1;
  for (int i = count + t; i < MPAD; i += 256) idx[i] = ROWS;
  for (int m = t; m < ROWS; m += 256) if (pos[m] < 0) pos[m] = count;
  if (t < 32) {
    int any = 0;
    for (int s = 99; s >= 0; --s) {
      any |= nz[t * 100 + s];
      pad[t * 100 + s] = (s > 0 && !any) ? 1 : 0;
    }
  }
#pragma unroll
  for (int i = t; i < 2048; i += 256) {
    const int L = i >> 10, j = i & 1023;
    kvbias[i] = dkvb[L * 1536 + 512 + j];
  }
}

// ---------------------------------------------------------------------------
// Merged prep kernel: multi-cvt | fc1 padded cvt | multi transpose.
// Independent work units -> blockIdx-partitioned, no inter-phase sync.
struct CvtArgs {
  const float* src[8];
  bf16* dst[8];
  int cum[8];
};
struct TrArgs {
  const float* src[13];
  float* dst[13];
  int R[13], C[13], cum[13];
};
struct PrepArgs {
  CvtArgs cv;
  TrArgs tr;
  const float* fc1w;
  bf16* wb1;
  int nCvt, nFc1;       // block counts of first two partitions
};
__global__ __launch_bounds__(256)
void prep_kernel(PrepArgs a)
{
  __shared__ float tbuf[64][65];
  const int bid0 = blockIdx.x;
  if (bid0 < a.nCvt) {
    const int bid = bid0;
    int seg = 0;
#pragma unroll
    for (int i = 1; i < 8; ++i) if (bid >= a.cv.cum[i]) seg = i;
    const size_t e0 = ((size_t)(bid - a.cv.cum[seg]) << 11) + (threadIdx.x << 3);
    const float4 v0 = *(const float4*)(a.cv.src[seg] + e0);
    const float4 v1 = *(const float4*)(a.cv.src[seg] + e0 + 4);
    union { short8 v; bf16 h[8]; } pk;
    pk.h[0] = __float2bfloat16(v0.x); pk.h[1] = __float2bfloat16(v0.y);
    pk.h[2] = __float2bfloat16(v0.z); pk.h[3] = __float2bfloat16(v0.w);
    pk.h[4] = __float2bfloat16(v1.x); pk.h[5] = __float2bfloat16(v1.y);
    pk.h[6] = __float2bfloat16(v1.z); pk.h[7] = __float2bfloat16(v1.w);
    *(short8*)(a.cv.dst[seg] + e0) = pk.v;
  } else if (bid0 < a.nCvt + a.nFc1) {
    const int r = bid0 - a.nCvt;          // 0..4095
    const float* src = a.fc1w + (size_t)r * FLATIN;
    bf16* dst = a.wb1 + (size_t)r * KPAD1;
#pragma unroll
    for (int u = 0; u < KPAD1 / 2048; ++u) {
      const int c0 = u * 2048 + threadIdx.x * 8;
      union { short8 v; bf16 h[8]; } pk;
      if (c0 + 8 <= FLATIN) {
        const float4 p = *(const float4*)(src + c0);
        const float4 q = *(const float4*)(src + c0 + 4);
        pk.h[0] = __float2bfloat16(p.x); pk.h[1] = __float2bfloat16(p.y);
        pk.h[2] = __float2bfloat16(p.z); pk.h[3] = __float2bfloat16(p.w);
        pk.h[4] = __float2bfloat16(q.x); pk.h[5] = __float2bfloat16(q.y);
        pk.h[6] = __float2bfloat16(q.z); pk.h[7] = __float2bfloat16(q.w);
      } else {
#pragma unroll
        for (int i = 0; i < 8; ++i)
          pk.h[i] = __float2bfloat16((c0 + i < FLATIN) ? src[c0 + i] : 0.f);
      }
      *(short8*)(dst + c0) = pk.v;
    }
  } else {
    const int bid = bid0 - a.nCvt - a.nFc1;
    int seg = 0;
#pragma unroll
    for (int i = 1; i < 13; ++i) if (bid >= a.tr.cum[i]) seg = i;
    const int local = bid - a.tr.cum[seg];
    const int R = a.tr.R[seg], C = a.tr.C[seg];
    const int tilesC = C >> 6;
    const int r0 = (local / tilesC) << 6;
    const int c0 = (local % tilesC) << 6;
    const int tx = threadIdx.x & 63, ty = threadIdx.x >> 6;
    const float* s = a.tr.src[seg];
    float* d = a.tr.dst[seg];
#pragma unroll
    for (int i = 0; i < 16; ++i) {
      const int rr = (ty << 4) + i;
      tbuf[rr][tx] = s[(size_t)(r0 + rr) * C + c0 + tx];
    }
    __syncthreads();
#pragma unroll
    for (int i = 0; i < 16; ++i) {
      const int cc = (ty << 4) + i;
      d[(size_t)(c0 + cc) * R + r0 + tx] = tbuf[tx][cc];
    }
  }
}

// fc3 reduce + bias + relu + scatter + inline PE
__global__ __launch_bounds__(256)
void scatter_pe_reduce(const float* __restrict__ P, size_t pstride, int ksl,
                       const int* __restrict__ pos, const float* __restrict__ bias,
                       float* __restrict__ hf, bf16* __restrict__ hb)
{
  const int m = blockIdx.x;
  const int s = m % 100, b = m / 100;
  const int src = pos[m];
  const int t = threadIdx.x;
  const size_t sb = (size_t)src * 512;
  const size_t db = (size_t)(s * 32 + b) * 512;
#pragma unroll
  for (int u = 0; u < 2; ++u) {
    const int d = t + u * 256;
    float v = bias[d];
    for (int k = 0; k < ksl; ++k) v += P[(size_t)k * pstride + sb + d];
    const float div = expf((float)(2 * (d >> 1)) * (-9.210340371976184f / 512.f));
    const float arg = (float)s * div;
    const float pe = (d & 1) ? cosf(arg) : sinf(arg);
    v = fmaxf(v, 0.f) + pe;
    hf[db + d] = v;
    hb[db + d] = __float2bfloat16(v);
  }
}

// ---------------------------------------------------------------------------
// LayerNorm over D=512 (+ optional second, final LN fused)
__global__ __launch_bounds__(256)
void ln_kernel(const float* __restrict__ x, const float* __restrict__ res,
               const float* __restrict__ g, const float* __restrict__ bta,
               const float* __restrict__ gf, const float* __restrict__ bf_,
               int dofinal, float* __restrict__ y, bf16* __restrict__ yb)
{
  __shared__ float rs[4], rss[4];
  const int row = blockIdx.x;
  const int t = threadIdx.x;
  const size_t base = (size_t)row * 512;
  float v0 = x[base + t];
  float v1 = x[base + t + 256];
  if (res) { v0 += res[base + t]; v1 += res[base + t + 256]; }
  float o0, o1;
#pragma unroll
  for (int pass = 0; pass < 2; ++pass) {
    float s = v0 + v1, ss = v0 * v0 + v1 * v1;
#pragma unroll
    for (int o = 32; o > 0; o >>= 1) { s += __shfl_xor(s, o); ss += __shfl_xor(ss, o); }
    if ((t & 63) == 0) { rs[t >> 6] = s; rss[t >> 6] = ss; }
    __syncthreads();
    s = rs[0] + rs[1] + rs[2] + rs[3];
    ss = rss[0] + rss[1] + rss[2] + rss[3];
    __syncthreads();
    const float mean = s * (1.f / 512.f);
    const float var = ss * (1.f / 512.f) - mean * mean;
    const float inv = rsqrtf(var + 1e-5f);
    const float* gg = (pass == 0) ? g : gf;
    const float* bb = (pass == 0) ? bta : bf_;
    o0 = (v0 - mean) * inv * gg[t] + bb[t];
    o1 = (v1 - mean) * inv * gg[t + 256] + bb[t + 256];
    if (pass == 1 || !dofinal) break;
    v0 = o0; v1 = o1;
  }
  if (y) {
    y[base + t] = o0;
    y[base + t + 256] = o1;
  }
  if (yb) {
    yb[base + t] = __float2bfloat16(o0);
    yb[base + t + 256] = __float2bfloat16(o1);
  }
}

// ---------------------------------------------------------------------------
// Encoder self-attention. grid (128 bh, 25 qg): 4 q's per block.
__global__ __launch_bounds__(256)
void enc_attn_kernel(const float* __restrict__ qkv, const int* __restrict__ pad,
                     bf16* __restrict__ ob)
{
  __shared__ float Ks[100][129];
  __shared__ float Qs[128];
  __shared__ float Ps[100];
  __shared__ float red[4];
  const int bh = blockIdx.x;
  const int b = bh >> 2, h = bh & 3;
  const int q0 = blockIdx.y * 4;
  const int t = threadIdx.x;
  for (int i = t; i < 12800; i += 256) {
    const int s = i >> 7, d = i & 127;
    Ks[s][d] = qkv[(size_t)(s * 32 + b) * 1536 + 512 + h * 128 + d];
  }
  const int masked = (t < 100) ? pad[b * 100 + t] : 0;
  const float scale = 0.08838834764831845f;
  for (int qi = 0; qi < 4; ++qi) {
    const int q = q0 + qi;
    __syncthreads();
    if (t < 128) Qs[t] = qkv[(size_t)(q * 32 + b) * 1536 + h * 128 + t];
    __syncthreads();
    float sc = -3e38f;
    if (t < 100) {
      const float* kr = &Ks[t][0];
      float a = 0.f;
#pragma unroll 16
      for (int d = 0; d < 128; ++d) a += Qs[d] * kr[d];
      sc = masked ? -1e9f : (a * scale);
    }
    float mx = sc;
#pragma unroll
    for (int o = 32; o > 0; o >>= 1) mx = fmaxf(mx, __shfl_xor(mx, o));
    if ((t & 63) == 0) red[t >> 6] = mx;
    __syncthreads();
    mx = fmaxf(fmaxf(red[0], red[1]), fmaxf(red[2], red[3]));
    const float e = (t < 100) ? expf(sc - mx) : 0.f;
    float sm = e;
#pragma unroll
    for (int o = 32; o > 0; o >>= 1) sm += __shfl_xor(sm, o);
    __syncthreads();
    if ((t & 63) == 0) red[t >> 6] = sm;
    __syncthreads();
    sm = red[0] + red[1] + red[2] + red[3];
    if (t < 100) Ps[t] = e;
    __syncthreads();
    if (t < 128) {
      float a = 0.f;
      const float* vb = qkv + 1024 + h * 128 + t;
      for (int k = 0; k < 100; ++k) a += Ps[k] * vb[(size_t)(k * 32 + b) * 1536];
      ob[(size_t)(q * 32 + b) * 512 + h * 128 + t] = __float2bfloat16(a / sm);
    }
  }
}

// ---------------------------------------------------------------------------
// Fused decoder layer: transposed-weight coalesced GEMVs. 512 thr, grid 32.
template<int N, int K, int RELU>
__device__ __forceinline__ void gemvT(int tid, const float* S,
                                      const float* __restrict__ WT,
                                      const float* __restrict__ bias,
                                      float* out, float* part)
{
  constexpr int NQ = N / 4;
  constexpr int G = 512 / NQ;
  constexpr int KP = K / G;
  const int p = tid % NQ;
  const int g = tid / NQ;
  const float4* wp = (const float4*)WT;
  float ax = 0.f, ay = 0.f, az = 0.f, aw = 0.f;
  const int kend = g * KP + KP;
#pragma unroll 8
  for (int k = g * KP; k < kend; ++k) {
    const float s = S[k];
    const float4 w = wp[(size_t)k * NQ + p];
    ax += s * w.x; ay += s * w.y; az += s * w.z; aw += s * w.w;
  }
  float4 a4 = {ax, ay, az, aw};
  *(float4*)(part + g * N + 4 * p) = a4;
  __syncthreads();
#pragma unroll
  for (int n = tid; n < N; n += 512) {
    float v = bias[n];
#pragma unroll
    for (int q = 0; q < G; ++q) v += part[q * N + n];
    if (RELU) v = fmaxf(v, 0.f);
    out[n] = v;
  }
  __syncthreads();
}

#define BLOCK_LN512(V, G, B, O)                                                 \
  {                                                                             \
    float s_ = (V), ss_ = (V) * (V);                                            \
    _Pragma("unroll")                                                           \
    for (int o_ = 32; o_ > 0; o_ >>= 1) {                                       \
      s_ += __shfl_xor(s_, o_); ss_ += __shfl_xor(ss_, o_);                     \
    }                                                                           \
    if ((tid & 63) == 0) { red[tid >> 6] = s_; red2[tid >> 6] = ss_; }          \
    __syncthreads();                                                            \
    s_ = 0.f; ss_ = 0.f;                                                        \
    _Pragma("unroll")                                                           \
    for (int w_ = 0; w_ < 8; ++w_) { s_ += red[w_]; ss_ += red2[w_]; }          \
    const float mean_ = s_ * (1.f / 512.f);                                     \
    const float inv_ = rsqrtf(ss_ * (1.f / 512.f) - mean_ * mean_ + 1e-5f);     \
    O = ((V) - mean_) * inv_ * (G)[tid] + (B)[tid];                             \
    __syncthreads();                                                            \
  }

__global__ __launch_bounds__(512)
void dec_layer(const float* __restrict__ tin,          // nullptr => ones
               const float* __restrict__ kvb, int kvstride,
               const float* __restrict__ WvT, const float* __restrict__ bv,
               const float* __restrict__ WpT, const float* __restrict__ bp,
               const float* __restrict__ g1, const float* __restrict__ b1,
               const float* __restrict__ WqT, const float* __restrict__ bq,
               const float* __restrict__ WcpT, const float* __restrict__ bcp,
               const float* __restrict__ g2, const float* __restrict__ b2,
               const float* __restrict__ W1T, const float* __restrict__ b1f,
               const float* __restrict__ W2T, const float* __restrict__ b2f,
               const float* __restrict__ g3, const float* __restrict__ b3,
               const float* __restrict__ gf, const float* __restrict__ bf_,
               int dofinal, float* __restrict__ tout,
               const float* __restrict__ Wo1T, const float* __restrict__ ob1,
               bf16* __restrict__ o1b)
{
  __shared__ float Ts[512], Bs[512], Cs[512], F1[1024], part[2048];
  __shared__ float Ps[4][104];
  __shared__ float red[8], red2[8];
  const int r = blockIdx.x, tid = threadIdx.x;
  Ts[tid] = tin ? tin[r * 512 + tid] : 1.0f;
  __syncthreads();

  gemvT<512, 512, 0>(tid, Ts, WvT, bv, Bs, part);
  gemvT<512, 512, 0>(tid, Bs, WpT, bp, Cs, part);
  {
    const float rr = Cs[tid] + Ts[tid];
    float o;
    BLOCK_LN512(rr, g1, b1, o)
    Ts[tid] = o;
  }
  __syncthreads();

  gemvT<512, 512, 0>(tid, Ts, WqT, bq, Bs, part);

  if (tid < 256) {
    const int h = tid >> 6, lane = tid & 63;
    const float scale = 0.08838834764831845f;
    const float* Qh = Bs + h * 128;
    float s0, s1 = -3e38f;
    {
      const float* kr = kvb + (size_t)(lane * 32 + r) * kvstride + h * 128;
      float a = 0.f;
#pragma unroll 16
      for (int d = 0; d < 128; ++d) a += Qh[d] * kr[d];
      s0 = a * scale;
    }
    if (lane + 64 < 100) {
      const float* kr = kvb + (size_t)((lane + 64) * 32 + r) * kvstride + h * 128;
      float a = 0.f;
#pragma unroll 16
      for (int d = 0; d < 128; ++d) a += Qh[d] * kr[d];
      s1 = a * scale;
    }
    float mx = fmaxf(s0, s1);
#pragma unroll
    for (int o = 32; o > 0; o >>= 1) mx = fmaxf(mx, __shfl_xor(mx, o));
    const float e0 = expf(s0 - mx);
    const float e1 = (lane + 64 < 100) ? expf(s1 - mx) : 0.f;
    float sm = e0 + e1;
#pragma unroll
    for (int o = 32; o > 0; o >>= 1) sm += __shfl_xor(sm, o);
    Ps[h][lane] = e0 / sm;
    if (lane + 64 < 100) Ps[h][lane + 64] = e1 / sm;
  }
  __syncthreads();
  if (tid < 256) {
    const int h = tid >> 6, lane = tid & 63;
#pragma unroll
    for (int u = 0; u < 2; ++u) {
      const int d = lane + u * 64;
      const float* vb = kvb + 512 + h * 128 + d;
      float a = 0.f;
      for (int k = 0; k < 100; ++k) a += Ps[h][k] * vb[(size_t)(k * 32 + r) * kvstride];
      Bs[h * 128 + d] = a;
    }
  }
  __syncthreads();

  gemvT<512, 512, 0>(tid, Bs, WcpT, bcp, Cs, part);
  {
    const float rr = Cs[tid] + Ts[tid];
    float o;
    BLOCK_LN512(rr, g2, b2, o)
    Ts[tid] = o;
  }
  __syncthreads();

  gemvT<1024, 512, 1>(tid, Ts, W1T, b1f, F1, part);
  gemvT<512, 1024, 0>(tid, F1, W2T, b2f, Cs, part);
  {
    const float rr = Cs[tid] + Ts[tid];
    float o;
    BLOCK_LN512(rr, g3, b3, o)
    if (dofinal) {
      float f;
      BLOCK_LN512(o, gf, bf_, f)
      o = f;
    }
    tout[r * 512 + tid] = o;
    if (dofinal) {
      Ts[tid] = o;
      __syncthreads();
      const float4* wp = (const float4*)Wo1T;
      float ax = 0.f, ay = 0.f, az = 0.f, aw = 0.f;
#pragma unroll 8
      for (int k = 0; k < 512; ++k) {
        const float s = Ts[k];
        const float4 w = wp[(size_t)k * 512 + tid];
        ax += s * w.x; ay += s * w.y; az += s * w.z; aw += s * w.w;
      }
      union { short4v v; bf16 h[4]; } u;
      u.h[0] = __float2bfloat16(fmaxf(ax + ob1[4 * tid], 0.f));
      u.h[1] = __float2bfloat16(fmaxf(ay + ob1[4 * tid + 1], 0.f));
      u.h[2] = __float2bfloat16(fmaxf(az + ob1[4 * tid + 2], 0.f));
      u.h[3] = __float2bfloat16(fmaxf(aw + ob1[4 * tid + 3], 0.f));
      *(short4v*)(o1b + (size_t)r * 2048 + 4 * tid) = u.v;
      const short4v z = {0, 0, 0, 0};
#pragma unroll
      for (int rr = r + 32; rr < 128; rr += 32)
        *(short4v*)(o1b + (size_t)rr * 2048 + 4 * tid) = z;
    }
  }
}

// ---------------------------------------------------------------------------
// out3 split-K reduce (+bias(+guard)+relu) fused with adaptive pool. grid 32.
__global__ __launch_bounds__(256)
void reduce_pool(const float* __restrict__ P, size_t pstride,
                 const float* __restrict__ bias, float* __restrict__ out)
{
  __shared__ float row[NOUT3];
  const int b = blockIdx.x, t = threadIdx.x;
  for (int n = t * 4; n < NOUT3; n += 1024) {
    const size_t o = (size_t)b * NOUT3 + n;
    float4 s = *(const float4*)(P + o);
#pragma unroll
    for (int k = 1; k < 4; ++k) {
      const float4 p = *(const float4*)(P + (size_t)k * pstride + o);
      s.x += p.x; s.y += p.y; s.z += p.z; s.w += p.w;
    }
    row[n]     = fmaxf(s.x + ((n     < FLATIN) ? bias[n]     : 0.f), 0.f);
    row[n + 1] = fmaxf(s.y + ((n + 1 < FLATIN) ? bias[n + 1] : 0.f), 0.f);
    row[n + 2] = fmaxf(s.z + ((n + 2 < FLATIN) ? bias[n + 2] : 0.f), 0.f);
    row[n + 3] = fmaxf(s.w + ((n + 3 < FLATIN) ? bias[n + 3] : 0.f), 0.f);
  }
  __syncthreads();
  for (int i = t; i < 135 * 103; i += 256) {
    const int j = i % 103, r = i / 103;
    const int rs = (r * 143) / 135, re = ((r + 1) * 143 + 134) / 135;
    const int cs = (j * 111) / 103, ce = ((j + 1) * 111 + 102) / 103;
    float s = 0.f;
    for (int rr = rs; rr < re; ++rr)
      for (int cc = cs; cc < ce; ++cc)
        s += row[rr * 111 + cc];
    out[(size_t)b * (135 * 103) + i] = s / (float)((re - rs) * (ce - cs));
  }
}

// ---------------------------------------------------------------------------
extern "C" void kernel_launch(void* const* d_in, const int* in_sizes, int n_in,
                              void* d_out, int out_size, void* d_ws, size_t ws_size,
                              hipStream_t stream)
{
  (void)in_sizes; (void)n_in; (void)out_size; (void)ws_size;

  const float* x          = (const float*)d_in[0];
  const float* fc1_w      = (const float*)d_in[1];
  const float* fc1_b      = (const float*)d_in[2];
  const float* fc2_w      = (const float*)d_in[3];
  const float* fc2_b      = (const float*)d_in[4];
  const float* fc3_w      = (const float*)d_in[5];
  const float* fc3_b      = (const float*)d_in[6];
  const float* out1_w     = (const float*)d_in[7];
  const float* out1_b     = (const float*)d_in[8];
  const float* out2_w     = (const float*)d_in[9];
  const float* out2_b     = (const float*)d_in[10];
  const float* out3_w     = (const float*)d_in[11];
  const float* out3_b     = (const float*)d_in[12];
  const float* enc_qkv_w  = (const float*)d_in[13];
  const float* enc_qkv_b  = (const float*)d_in[14];
  const float* enc_proj_w = (const float*)d_in[15];
  const float* enc_proj_b = (const float*)d_in[16];
  const float* enc_ff1_w  = (const float*)d_in[17];
  const float* enc_ff1_b  = (const float*)d_in[18];
  const float* enc_ff2_w  = (const float*)d_in[19];
  const float* enc_ff2_b  = (const float*)d_in[20];
  const float* enc_ln1_g  = (const float*)d_in[21];
  const float* enc_ln1_b  = (const float*)d_in[22];
  const float* enc_ln2_g  = (const float*)d_in[23];
  const float* enc_ln2_b  = (const float*)d_in[24];
  const float* enc_lnf_g  = (const float*)d_in[25];
  const float* enc_lnf_b  = (const float*)d_in[26];
  const float* dec_sa_qkv_w  = (const float*)d_in[27];
  const float* dec_sa_qkv_b  = (const float*)d_in[28];
  const float* dec_sa_proj_w = (const float*)d_in[29];
  const float* dec_sa_proj_b = (const float*)d_in[30];
  const float* dec_ca_qkv_w  = (const float*)d_in[31];
  const float* dec_ca_qkv_b  = (const float*)d_in[32];
  const float* dec_ca_proj_w = (const float*)d_in[33];
  const float* dec_ca_proj_b = (const float*)d_in[34];
  const float* dec_ff1_w  = (const float*)d_in[35];
  const float* dec_ff1_b  = (const float*)d_in[36];
  const float* dec_ff2_w  = (const float*)d_in[37];
  const float* dec_ff2_b  = (const float*)d_in[38];
  const float* dec_ln1_g  = (const float*)d_in[39];
  const float* dec_ln1_b  = (const float*)d_in[40];
  const float* dec_ln2_g  = (const float*)d_in[41];
  const float* dec_ln2_b  = (const float*)d_in[42];
  const float* dec_ln3_g  = (const float*)d_in[43];
  const float* dec_ln3_b  = (const float*)d_in[44];
  const float* dec_lnf_g  = (const float*)d_in[45];
  const float* dec_lnf_b  = (const float*)d_in[46];

  char* wsp = (char*)d_ws;
  size_t off = 0;
  auto alloc = [&](size_t nbytes) -> char* {
    char* p = wsp + off;
    off += (nbytes + 255) & ~(size_t)255;
    return p;
  };

  bf16* xb     = (bf16*)alloc((size_t)MPAD * KPAD1 * 2);
  bf16* Wb1    = (bf16*)alloc((size_t)4096 * KPAD1 * 2);
  bf16* Wb2    = (bf16*)alloc((size_t)2048 * 4096 * 2);
  bf16* Wb3    = (bf16*)alloc((size_t)512 * 2048 * 2);
  bf16* Wqkvb  = (bf16*)alloc((size_t)2 * 1536 * 512 * 2);
  bf16* Wprojb = (bf16*)alloc((size_t)2 * 512 * 512 * 2);
  bf16* Wff1b  = (bf16*)alloc((size_t)2 * 1024 * 512 * 2);
  bf16* Wff2b  = (bf16*)alloc((size_t)2 * 512 * 1024 * 2);
  bf16* Wkv2b  = (bf16*)alloc((size_t)2048 * 512 * 2);
  int*   nz      = (int*)alloc(ROWS * 4);
  int*   padmask = (int*)alloc(ROWS * 4);
  int*   idx     = (int*)alloc(MPAD * 4);
  int*   pos     = (int*)alloc(ROWS * 4);
  int*   cnt     = (int*)alloc(256);
  float* kvbias  = (float*)alloc(2048 * 4);
  bf16* h1c = (bf16*)alloc((size_t)MPAD * 4096 * 2);
  bf16* h2c = (bf16*)alloc((size_t)MPAD * 2048 * 2);
  float* hf  = (float*)alloc((size_t)ROWS * 512 * 4);
  bf16* hb = (bf16*)alloc((size_t)ROWS * 512 * 2);
  float* qkvbuf = (float*)alloc((size_t)ROWS * 1536 * 4);
  bf16* attnb = (bf16*)alloc((size_t)ROWS * 512 * 2);
  float* pjf  = (float*)alloc((size_t)ROWS * 512 * 4);
  bf16* f1b = (bf16*)alloc((size_t)ROWS * 1024 * 2);
  float* f2f  = (float*)alloc((size_t)ROWS * 512 * 4);
  bf16* memb = (bf16*)alloc((size_t)ROWS * 512 * 2);
  float* kv01 = (float*)alloc((size_t)ROWS * 2048 * 4);
  float* tbuf = (float*)alloc(32 * 512 * 4);
  float* WvT[2]  = { (float*)alloc(512 * 512 * 4), (float*)alloc(512 * 512 * 4) };
  float* WpT[2]  = { (float*)alloc(512 * 512 * 4), (float*)alloc(512 * 512 * 4) };
  float* WqT[2]  = { (float*)alloc(512 * 512 * 4), (float*)alloc(512 * 512 * 4) };
  float* WcpT[2] = { (float*)alloc(512 * 512 * 4), (float*)alloc(512 * 512 * 4) };
  float* W1T[2]  = { (float*)alloc(512 * 1024 * 4), (float*)alloc(512 * 1024 * 4) };
  float* W2T[2]  = { (float*)alloc(1024 * 512 * 4), (float*)alloc(1024 * 512 * 4) };
  float* Wo1T    = (float*)alloc((size_t)512 * 2048 * 4);
  float* fcP  = (float*)alloc((size_t)4 * MPAD * 4096 * 4);   // 218 MB
  float* encP = (float*)alloc((size_t)2 * ROWS * 1536 * 4);   // aliases

  float* outP = fcP;                                           // <=33 MB
  bf16* o1b  = (bf16*)((char*)encP + ((size_t)20 << 20));
  bf16* o2b  = (bf16*)((char*)encP + ((size_t)22 << 20));

  const size_t psF1 = (size_t)MPAD * 4096;
  const size_t psF2 = (size_t)MPAD * 2048;
  const size_t psF3 = (size_t)MPAD * 512;

  // ---- phase 0 ----
  conv_x_kernel<<<ROWS + 1, 256, 0, stream>>>(x, xb, nz);
  compact_kernel<<<1, 256, 0, stream>>>(nz, idx, pos, cnt, padmask,
                                        dec_ca_qkv_b, kvbias);
  {
    PrepArgs pa;
    const float* srcs[8] = { enc_qkv_w, enc_proj_w, enc_ff1_w, enc_ff2_w,
                             dec_ca_qkv_w + (size_t)512 * 512,
                             dec_ca_qkv_w + (size_t)(1536 + 512) * 512,
                             fc2_w, fc3_w };
    bf16* dsts[8] = { Wqkvb, Wprojb, Wff1b, Wff2b,
                      Wkv2b, Wkv2b + (size_t)1024 * 512, Wb2, Wb3 };
    const int counts[8] = { 2*1536*512, 2*512*512, 2*1024*512, 2*512*1024,
                            1024*512, 1024*512, 2048*4096, 512*2048 };
    int c = 0;
    for (int i = 0; i < 8; ++i) { pa.cv.src[i] = srcs[i]; pa.cv.dst[i] = dsts[i];
                                  pa.cv.cum[i] = c; c += counts[i] >> 11; }
    pa.nCvt = c;
    pa.fc1w = fc1_w; pa.wb1 = Wb1; pa.nFc1 = 4096;
    const float* tsr[13];
    float* tds[13];
    int R[13], C[13];
    int n = 0;
    for (int L = 0; L < 2; ++L) {
      tsr[n] = dec_sa_qkv_w + (size_t)L * 1536 * 512 + (size_t)1024 * 512;
      tds[n] = WvT[L]; R[n] = 512; C[n] = 512; ++n;
      tsr[n] = dec_sa_proj_w + (size_t)L * 512 * 512;
      tds[n] = WpT[L]; R[n] = 512; C[n] = 512; ++n;
      tsr[n] = dec_ca_qkv_w + (size_t)L * 1536 * 512;
      tds[n] = WqT[L]; R[n] = 512; C[n] = 512; ++n;
      tsr[n] = dec_ca_proj_w + (size_t)L * 512 * 512;
      tds[n] = WcpT[L]; R[n] = 512; C[n] = 512; ++n;
      tsr[n] = dec_ff1_w + (size_t)L * 1024 * 512;
      tds[n] = W1T[L]; R[n] = 1024; C[n] = 512; ++n;
      tsr[n] = dec_ff2_w + (size_t)L * 512 * 1024;
      tds[n] = W2T[L]; R[n] = 512; C[n] = 1024; ++n;
    }
    tsr[n] = out1_w; tds[n] = Wo1T; R[n] = 2048; C[n] = 512; ++n;
    int tc = 0;
    for (int i = 0; i < 13; ++i) {
      pa.tr.src[i] = tsr[i]; pa.tr.dst[i] = tds[i];
      pa.tr.R[i] = R[i]; pa.tr.C[i] = C[i];
      pa.tr.cum[i] = tc; tc += (R[i] >> 6) * (C[i] >> 6);
    }
    prep_kernel<<<pa.nCvt + pa.nFc1 + tc, 256, 0, stream>>>(pa);
  }

  // ---- phase 1: input MLP (split-K) ----
  gemm_bf16<1><<<26 * 32 * 2, 256, 0, stream>>>(xb, Wb1, idx, cnt, fcP,
      KPAD1, 4096, 26, 2, psF1);
  reduce_kernel<1, 0, 1><<<dim3(4, MPAD), 256, 0, stream>>>(fcP, psF1, 2,
      fc1_b, nullptr, h1c, 4096, cnt);
  gemm_bf16<0><<<26 * 16 * 4, 256, 0, stream>>>(h1c, Wb2, nullptr, cnt, fcP,
      4096, 2048, 26, 4, psF2);
  reduce_kernel<1, 0, 1><<<dim3(2, MPAD), 256, 0, stream>>>(fcP, psF2, 4,
      fc2_b, nullptr, h2c, 2048, cnt);
  gemm_bf16<0><<<26 * 4 * 4, 256, 0, stream>>>(h2c, Wb3, nullptr, cnt, fcP,
      2048, 512, 26, 4, psF3);
  scatter_pe_reduce<<<ROWS, 256, 0, stream>>>(fcP, psF3, 4, pos, fc3_b, hf, hb);

  // ---- phase 2: encoder ----
  for (int L = 0; L < 2; ++L) {
    gemm_direct<0, 1, 0><<<25 * 12, 256, 0, stream>>>(hb, Wqkvb + (size_t)L * 1536 * 512,
        enc_qkv_b + L * 1536, qkvbuf, nullptr, 512, 1536, 25);
    enc_attn_kernel<<<dim3(128, 25), 256, 0, stream>>>(qkvbuf, padmask, attnb);
    gemm_direct<0, 1, 0><<<25 * 4, 256, 0, stream>>>(attnb, Wprojb + (size_t)L * 512 * 512,
        enc_proj_b + L * 512, pjf, nullptr, 512, 512, 25);
    ln_kernel<<<ROWS, 256, 0, stream>>>(hf, pjf, enc_ln1_g + L * 512, enc_ln1_b + L * 512,
        nullptr, nullptr, 0, hf, hb);
    gemm_direct<1, 0, 1><<<25 * 8, 256, 0, stream>>>(hb, Wff1b + (size_t)L * 1024 * 512,
        enc_ff1_b + L * 1024, nullptr, f1b, 512, 1024, 25);
    gemm_direct<0, 1, 0><<<25 * 4, 256, 0, stream>>>(f1b, Wff2b + (size_t)L * 512 * 1024,
        enc_ff2_b + L * 512, f2f, nullptr, 1024, 512, 25);
    if (L == 0) {
      ln_kernel<<<ROWS, 256, 0, stream>>>(hf, f2f, enc_ln2_g, enc_ln2_b,
          nullptr, nullptr, 0, hf, hb);
    } else {
      ln_kernel<<<ROWS, 256, 0, stream>>>(hf, f2f, enc_ln2_g + 512, enc_ln2_b + 512,
          enc_lnf_g, enc_lnf_b, 1, nullptr, memb);
    }
  }

  // ---- decoder KV (both layers, one GEMM) ----
  gemm_direct<0, 1, 0><<<25 * 16, 256, 0, stream>>>(memb, Wkv2b, kvbias,
      kv01, nullptr, 512, 2048, 25);

  // ---- phase 3: fused decoder layers (+ out1 fused into L1) ----
  for (int L = 0; L < 2; ++L) {
    dec_layer<<<32, 512, 0, stream>>>(
        (L == 0) ? nullptr : tbuf,
        kv01 + (size_t)L * 1024, 2048,
        WvT[L], dec_sa_qkv_b + L * 1536 + 1024,
        WpT[L], dec_sa_proj_b + L * 512,
        dec_ln1_g + L * 512, dec_ln1_b + L * 512,
        WqT[L], dec_ca_qkv_b + L * 1536,
        WcpT[L], dec_ca_proj_b + L * 512,
        dec_ln2_g + L * 512, dec_ln2_b + L * 512,
        W1T[L], dec_ff1_b + L * 1024,
        W2T[L], dec_ff2_b + L * 512,
        dec_ln3_g + L * 512, dec_ln3_b + L * 512,
        dec_lnf_g, dec_lnf_b, (L == 1) ? 1 : 0, tbuf,
        Wo1T, out1_b, o1b);
  }

  // ---- phase 4: output MLP (fp32-weight GEMMs, conversion fused) ----
  gemm_w32<<<32 * 4, 256, 0, stream>>>(o1b, out2_w, outP,
      2048, 4096, 4, (size_t)128 * 4096, 4096);
  reduce_kernel<1, 0, 1><<<dim3(4, 128), 256, 0, stream>>>(outP, (size_t)128 * 4096, 4,
      out2_b, nullptr, o2b, 4096, nullptr);
  gemm_w32<<<125 * 4, 256, 0, stream>>>(o2b, out3_w, outP,
      4096, NOUT3, 4, (size_t)128 * NOUT3, FLATIN);
  reduce_pool<<<32, 256, 0, stream>>>(outP, (size_t)128 * NOUT3, out3_b, (float*)d_out);
}